// Round 1
// baseline (1650.024 us; speedup 1.0000x reference)
//
#include <hip/hip_runtime.h>
#include <hip/hip_bf16.h>

#define DEV __device__ __forceinline__

DEV float fastrcp(float x) { return __builtin_amdgcn_rcpf(x); }
DEV float sigm(float x)    { return fastrcp(1.f + __expf(-x)); }
DEV float tanh_(float x)   { return 1.f - 2.f * fastrcp(__expf(2.f * x) + 1.f); }

DEV unsigned short f2bf(float f) {           // fp32 -> bf16, round-nearest-even
  unsigned u = __float_as_uint(f);
  u += 0x7fffu + ((u >> 16) & 1u);
  return (unsigned short)(u >> 16);
}
DEV float bf2f(unsigned short h) { return __uint_as_float(((unsigned)h) << 16); }

struct P {
  const float *spec;
  const float *fw_ih1,*fw_hh1,*fb1,*fw_ih2,*fw_hh2,*fb2,*fw_ih3,*fw_hh3,*fb3,*fw_ih4,*fw_hh4,*fb4;
  const float *bw_ih1,*bw_hh1,*bb1,*bw_ih2,*bw_hh2,*bb2,*bw_ih3,*bw_hh3,*bb3,*bw_ih4,*bw_hh4,*bb4;
  const float *ft12h,*ft12c,*ft23h,*ft23c,*ft34h,*bt43h,*bt43c,*bt32h,*bt32c,*bt21h,*bt21c;
  float *out;
};

template<int NG,int NJ>
DEV void init_acc(float (&acc)[NG][NJ], const float* __restrict__ bias,
                  const int (&gb)[NG], int j0) {
  #pragma unroll
  for (int g = 0; g < NG; ++g)
    #pragma unroll
    for (int jj = 0; jj < NJ; ++jj)
      acc[g][jj] = bias[gb[g] + j0 + jj];
}

// x-part: x from swizzled bf16-pair LDS (spec), weights via wave-uniform scalar loads
template<int NG,int NJ,int K>
DEV void dot_x(float (&acc)[NG][NJ], const float* __restrict__ W, const int (&gb)[NG],
               int j0, int k2off, const unsigned* xs, int b) {
  static_assert(K % 4 == 0, "");
  for (int kc = 0; kc < K / 4; ++kc) {
    int k2 = k2off + 2 * kc;
    unsigned v0 = xs[(k2    ) * 64 + (b ^ (k2    ))];
    unsigned v1 = xs[(k2 + 1) * 64 + (b ^ (k2 + 1))];
    float x0 = __uint_as_float(v0 << 16);
    float x1 = __uint_as_float(v0 & 0xffff0000u);
    float x2 = __uint_as_float(v1 << 16);
    float x3 = __uint_as_float(v1 & 0xffff0000u);
    #pragma unroll
    for (int g = 0; g < NG; ++g) {
      #pragma unroll
      for (int jj = 0; jj < NJ; ++jj) {
        const float* wr = W + (size_t)(gb[g] + j0 + jj) * K + 4 * kc;
        acc[g][jj] = fmaf(wr[0], x0, fmaf(wr[1], x1, fmaf(wr[2], x2, fmaf(wr[3], x3, acc[g][jj]))));
      }
    }
  }
}

// h-part: state from bf16 [feat][64] LDS buffer
template<int NG,int NJ,int K>
DEV void dot_h(float (&acc)[NG][NJ], const float* __restrict__ W, const int (&gb)[NG],
               int j0, int fbase, const unsigned short* Bb, int b) {
  static_assert(K % 4 == 0, "");
  for (int kc = 0; kc < K / 4; ++kc) {
    float xv[4];
    #pragma unroll
    for (int q = 0; q < 4; ++q)
      xv[q] = bf2f(Bb[(fbase + 4 * kc + q) * 64 + b]);
    #pragma unroll
    for (int g = 0; g < NG; ++g) {
      #pragma unroll
      for (int jj = 0; jj < NJ; ++jj) {
        const float* wr = W + (size_t)(gb[g] + j0 + jj) * K + 4 * kc;
        acc[g][jj] = fmaf(wr[0], xv[0], fmaf(wr[1], xv[1], fmaf(wr[2], xv[2], fmaf(wr[3], xv[3], acc[g][jj]))));
      }
    }
  }
}

// conv1d(k=3, pad=1, stride S) + softmax over one row of length L, per-lane serial.
template<int L,int S>
DEV void trans_row(const float* A, int fin, const float* __restrict__ tw,
                   unsigned short* Bout, int fout, int b) {
  constexpr int O = (S == 2) ? L / 2 : L;
  float w0 = tw[0], w1 = tw[1], w2 = tw[2];
  const float* in = A + fin * 64 + b;
  float y[O];
  float m = -3.0e38f;
  #pragma unroll
  for (int o = 0; o < O; ++o) {
    int c = S * o;
    float v = w1 * in[c * 64];
    if (c >= 1)    v += w0 * in[(c - 1) * 64];
    if (c + 1 < L) v += w2 * in[(c + 1) * 64];
    y[o] = v;
    m = fmaxf(m, v);
  }
  float s = 0.f;
  #pragma unroll
  for (int o = 0; o < O; ++o) { float e = __expf(y[o] - m); y[o] = e; s += e; }
  float inv = fastrcp(s);
  unsigned short* op = Bout + fout * 64 + b;
  #pragma unroll
  for (int o = 0; o < O; ++o) op[o * 64] = f2bf(y[o] * inv);
}

__global__ __launch_bounds__(512, 4) void dsgsf_kernel(P p) {
  __shared__ unsigned        xs[64 * 64];   // spec as bf16 pairs, [k2][b], XOR-swizzled (16 KB)
  __shared__ float           Ah[64 * 64];   // lstm h state, [feat][b] fp32 (16 KB)
  __shared__ float           Ac[64 * 64];   // lstm c state (16 KB)
  __shared__ unsigned short  Bh[64 * 64];   // trans h out, bf16 (8 KB)
  __shared__ unsigned short  Bc[64 * 64];   // trans c out, bf16 (8 KB)   total = 64 KB exactly

  const int t  = threadIdx.x;
  const int b  = t & 63;                                    // lane = batch element in tile
  const int wu = __builtin_amdgcn_readfirstlane(t >> 6);    // wave id, forced SGPR-uniform
  const long long b0 = (long long)blockIdx.x * 64;

  // ---- stage spec -> LDS bf16 pairs, coalesced global, conflict-free LDS ----
  {
    const float* sp = p.spec + b0 * 128;
    #pragma unroll
    for (int i = 0; i < 8; ++i) {
      int idx = i * 512 + t;                 // pair index 0..4095
      int k2 = idx & 63, bb = idx >> 6;
      float2 v = *(const float2*)(sp + bb * 128 + 2 * k2);
      xs[k2 * 64 + (bb ^ k2)] = (unsigned)f2bf(v.x) | ((unsigned)f2bf(v.y) << 16);
    }
  }
  __syncthreads();

  // ================= forward =================
  { // F1: lstm0(spec) -> h1,c1 [64]
    const int gb[3] = {0, 128, 192};         // i, g, o rows of fw_ih1
    int j0 = wu * 8;
    float acc[3][8];
    init_acc<3,8>(acc, p.fb1, gb, j0);
    dot_x<3,8,128>(acc, p.fw_ih1, gb, j0, 0, xs, b);
    #pragma unroll
    for (int jj = 0; jj < 8; ++jj) {
      float c = sigm(acc[0][jj]) * tanh_(acc[1][jj]);
      float h = sigm(acc[2][jj]) * tanh_(c);
      int j = j0 + jj;
      Ah[j * 64 + b] = h; Ac[j * 64 + b] = c;
    }
  }
  __syncthreads();
  if (wu == 0)      trans_row<64,2>(Ah, 0, p.ft12h, Bh, 0, b);
  else if (wu == 1) trans_row<64,2>(Ac, 0, p.ft12c, Bc, 0, b);
  __syncthreads();
  { // F2: 2 steps, dh=32, state hb/cb broadcast
    const int gb[4] = {0, 32, 64, 96};
    int ts = wu & 1, j0 = (wu >> 1) * 8;
    float acc[4][8];
    init_acc<4,8>(acc, p.fb2, gb, j0);
    dot_x<4,8,64>(acc, p.fw_ih2, gb, j0, ts * 32, xs, b);
    dot_h<4,8,32>(acc, p.fw_hh2, gb, j0, 0, Bh, b);
    #pragma unroll
    for (int jj = 0; jj < 8; ++jj) {
      int j = j0 + jj;
      float cb = bf2f(Bc[j * 64 + b]);
      float c = sigm(acc[1][jj]) * cb + sigm(acc[0][jj]) * tanh_(acc[2][jj]);
      float h = sigm(acc[3][jj]) * tanh_(c);
      Ah[(ts * 32 + j) * 64 + b] = h; Ac[(ts * 32 + j) * 64 + b] = c;
    }
  }
  __syncthreads();
  if (wu < 2)      trans_row<32,2>(Ah, wu * 32, p.ft23h, Bh, wu * 16, b);
  else if (wu < 4) trans_row<32,2>(Ac, (wu - 2) * 32, p.ft23c, Bc, (wu - 2) * 16, b);
  __syncthreads();
  { // F3: 4 steps, dh=16, state hb2[s>>1]
    const int gb[4] = {0, 16, 32, 48};
    int s = wu & 3, j0 = (wu >> 2) * 8;
    float acc[4][8];
    init_acc<4,8>(acc, p.fb3, gb, j0);
    dot_x<4,8,32>(acc, p.fw_ih3, gb, j0, s * 16, xs, b);
    dot_h<4,8,16>(acc, p.fw_hh3, gb, j0, (s >> 1) * 16, Bh, b);
    #pragma unroll
    for (int jj = 0; jj < 8; ++jj) {
      int j = j0 + jj;
      float cb = bf2f(Bc[((s >> 1) * 16 + j) * 64 + b]);
      float c = sigm(acc[1][jj]) * cb + sigm(acc[0][jj]) * tanh_(acc[2][jj]);
      float h = sigm(acc[3][jj]) * tanh_(c);
      Ah[(s * 16 + j) * 64 + b] = h; Ac[(s * 16 + j) * 64 + b] = c;
    }
  }
  __syncthreads();
  if (wu < 4) trans_row<16,2>(Ah, wu * 16, p.ft34h, Bh, wu * 8, b);
  else        trans_row<16,2>(Ac, (wu - 4) * 16, p.ft34h, Bc, (wu - 4) * 8, b); // ref bug: ft34h reused for c
  __syncthreads();
  { // F4: 8 steps, dh=8 -> out_fwd
    const int gb[4] = {0, 8, 16, 24};
    int u = wu;
    float acc[4][8];
    init_acc<4,8>(acc, p.fb4, gb, 0);
    dot_x<4,8,16>(acc, p.fw_ih4, gb, 0, u * 8, xs, b);
    dot_h<4,8,8>(acc, p.fw_hh4, gb, 0, (u >> 1) * 8, Bh, b);
    float* op = p.out + (b0 + b) * 128 + u * 8;
    #pragma unroll
    for (int jj = 0; jj < 8; ++jj) {
      float cb = bf2f(Bc[((u >> 1) * 8 + jj) * 64 + b]);
      float c = sigm(acc[1][jj]) * cb + sigm(acc[0][jj]) * tanh_(acc[2][jj]);
      float h = sigm(acc[3][jj]) * tanh_(c);
      op[jj] = h;
    }
  }
  // ================= backward =================
  { // B4: lstm0(x4) (writes A; nothing reads A in this barrier interval)
    const int gb[3] = {0, 16, 24};
    int u = wu;
    float acc[3][8];
    init_acc<3,8>(acc, p.bb4, gb, 0);
    dot_x<3,8,16>(acc, p.bw_ih4, gb, 0, u * 8, xs, b);
    #pragma unroll
    for (int jj = 0; jj < 8; ++jj) {
      float c = sigm(acc[0][jj]) * tanh_(acc[1][jj]);
      float h = sigm(acc[2][jj]) * tanh_(c);
      Ah[(u * 8 + jj) * 64 + b] = h; Ac[(u * 8 + jj) * 64 + b] = c;
    }
  }
  __syncthreads();
  if (wu < 4) trans_row<16,1>(Ah, wu * 16, p.bt43h, Bh, wu * 16, b);
  else        trans_row<16,1>(Ac, (wu - 4) * 16, p.bt43c, Bc, (wu - 4) * 16, b);
  __syncthreads();
  { // B3: 4 steps, dh=16, state hb4[s]
    const int gb[4] = {0, 16, 32, 48};
    int s = wu & 3, j0 = (wu >> 2) * 8;
    float acc[4][8];
    init_acc<4,8>(acc, p.bb3, gb, j0);
    dot_x<4,8,32>(acc, p.bw_ih3, gb, j0, s * 16, xs, b);
    dot_h<4,8,16>(acc, p.bw_hh3, gb, j0, s * 16, Bh, b);
    #pragma unroll
    for (int jj = 0; jj < 8; ++jj) {
      int j = j0 + jj;
      float cb = bf2f(Bc[(s * 16 + j) * 64 + b]);
      float c = sigm(acc[1][jj]) * cb + sigm(acc[0][jj]) * tanh_(acc[2][jj]);
      float h = sigm(acc[3][jj]) * tanh_(c);
      Ah[(s * 16 + j) * 64 + b] = h; Ac[(s * 16 + j) * 64 + b] = c;
    }
  }
  __syncthreads();
  if (wu < 2)      trans_row<32,1>(Ah, wu * 32, p.bt32h, Bh, wu * 32, b);
  else if (wu < 4) trans_row<32,1>(Ac, (wu - 2) * 32, p.bt32c, Bc, (wu - 2) * 32, b);
  __syncthreads();
  { // B2: 2 steps, dh=32, state hb3b[t]
    const int gb[4] = {0, 32, 64, 96};
    int ts = wu & 1, j0 = (wu >> 1) * 8;
    float acc[4][8];
    init_acc<4,8>(acc, p.bb2, gb, j0);
    dot_x<4,8,64>(acc, p.bw_ih2, gb, j0, ts * 32, xs, b);
    dot_h<4,8,32>(acc, p.bw_hh2, gb, j0, ts * 32, Bh, b);
    #pragma unroll
    for (int jj = 0; jj < 8; ++jj) {
      int j = j0 + jj;
      float cb = bf2f(Bc[(ts * 32 + j) * 64 + b]);
      float c = sigm(acc[1][jj]) * cb + sigm(acc[0][jj]) * tanh_(acc[2][jj]);
      float h = sigm(acc[3][jj]) * tanh_(c);
      Ah[(ts * 32 + j) * 64 + b] = h; Ac[(ts * 32 + j) * 64 + b] = c;
    }
  }
  __syncthreads();
  if (wu == 0)      trans_row<64,1>(Ah, 0, p.bt21h, Bh, 0, b);
  else if (wu == 1) trans_row<64,1>(Ac, 0, p.bt21c, Bc, 0, b);
  __syncthreads();
  { // B1: only c1b needed -> gates i,f,g
    const int gb[3] = {0, 64, 128};
    int j0 = wu * 8;
    float acc[3][8];
    init_acc<3,8>(acc, p.bb1, gb, j0);
    dot_x<3,8,128>(acc, p.bw_ih1, gb, j0, 0, xs, b);
    dot_h<3,8,64>(acc, p.bw_hh1, gb, j0, 0, Bh, b);
    float* op = p.out + (b0 + b) * 128 + 64 + j0;
    #pragma unroll
    for (int jj = 0; jj < 8; ++jj) {
      float cb = bf2f(Bc[(j0 + jj) * 64 + b]);
      float c = sigm(acc[1][jj]) * cb + sigm(acc[0][jj]) * tanh_(acc[2][jj]);
      op[jj] = c;
    }
  }
}

extern "C" void kernel_launch(void* const* d_in, const int* in_sizes, int n_in,
                              void* d_out, int out_size, void* d_ws, size_t ws_size,
                              hipStream_t stream) {
  P p;
  p.spec   = (const float*)d_in[0];
  p.fw_ih1 = (const float*)d_in[1];  p.fw_hh1 = (const float*)d_in[2];  p.fb1 = (const float*)d_in[3];
  p.fw_ih2 = (const float*)d_in[4];  p.fw_hh2 = (const float*)d_in[5];  p.fb2 = (const float*)d_in[6];
  p.fw_ih3 = (const float*)d_in[7];  p.fw_hh3 = (const float*)d_in[8];  p.fb3 = (const float*)d_in[9];
  p.fw_ih4 = (const float*)d_in[10]; p.fw_hh4 = (const float*)d_in[11]; p.fb4 = (const float*)d_in[12];
  p.bw_ih1 = (const float*)d_in[13]; p.bw_hh1 = (const float*)d_in[14]; p.bb1 = (const float*)d_in[15];
  p.bw_ih2 = (const float*)d_in[16]; p.bw_hh2 = (const float*)d_in[17]; p.bb2 = (const float*)d_in[18];
  p.bw_ih3 = (const float*)d_in[19]; p.bw_hh3 = (const float*)d_in[20]; p.bb3 = (const float*)d_in[21];
  p.bw_ih4 = (const float*)d_in[22]; p.bw_hh4 = (const float*)d_in[23]; p.bb4 = (const float*)d_in[24];
  p.ft12h = (const float*)d_in[25]; p.ft12c = (const float*)d_in[26];
  p.ft23h = (const float*)d_in[27]; p.ft23c = (const float*)d_in[28];
  p.ft34h = (const float*)d_in[29];
  p.bt43h = (const float*)d_in[30]; p.bt43c = (const float*)d_in[31];
  p.bt32h = (const float*)d_in[32]; p.bt32c = (const float*)d_in[33];
  p.bt21h = (const float*)d_in[34]; p.bt21c = (const float*)d_in[35];
  p.out = (float*)d_out;

  int Bn = in_sizes[0] / 128;            // 131072
  dim3 grid(Bn / 64), block(512);        // 64-element batch tile per block
  hipLaunchKernelGGL(dsgsf_kernel, grid, block, 0, stream, p);
}

// Round 2
// 225.593 us; speedup vs baseline: 7.3142x; 7.3142x over previous
//
#include <hip/hip_runtime.h>

typedef __attribute__((ext_vector_type(4))) float f32x4;
typedef __attribute__((ext_vector_type(8))) short short8;

#define DEV __device__ __forceinline__

DEV float fastrcp(float x){ return __builtin_amdgcn_rcpf(x); }
DEV float sigm(float x){ return fastrcp(1.f + __expf(-x)); }
DEV float tanh_(float x){ return 1.f - 2.f*fastrcp(__expf(2.f*x)+1.f); }
DEV unsigned short f2bf(float f){ unsigned u=__float_as_uint(f); u += 0x7fffu + ((u>>16)&1u); return (unsigned short)(u>>16); }
DEV float bf2f(unsigned short h){ return __uint_as_float(((unsigned)h)<<16); }
DEV unsigned pack2(float a, float b){ return (unsigned)f2bf(a) | ((unsigned)f2bf(b)<<16); }

// bank swizzle for [feat][64batch] bf16 arrays: 2-way-free for both
// per-lane-batch scans (trans) and C-fragment-pattern stores/loads.
DEV int gmask(int f){ return ((f&1)<<5) | (f&2) | ((f&4)<<2); }
DEV void stBF(char* A, int f, int b, float v){ *(unsigned short*)(A + (((f<<6) + (b ^ gmask(f)))<<1)) = f2bf(v); }
DEV float ldBF(const char* A, int f, int b){ return bf2f(*(const unsigned short*)(A + (((f<<6) + (b ^ gmask(f)))<<1))); }

DEV short8 frag(const char* p){ return *(const short8*)p; }
DEV f32x4 MF(short8 a, short8 b, f32x4 c){ return __builtin_amdgcn_mfma_f32_16x16x32_bf16(a,b,c,0,0,0); }

DEV void gload(const char* g, char* lds){
  __builtin_amdgcn_global_load_lds((const __attribute__((address_space(1))) unsigned*)g,
                                   (__attribute__((address_space(3))) unsigned*)lds, 16, 0, 0);
}

struct P {
  const float *spec;
  const float *fw_ih1,*fw_hh1,*fb1,*fw_ih2,*fw_hh2,*fb2,*fw_ih3,*fw_hh3,*fb3,*fw_ih4,*fw_hh4,*fb4;
  const float *bw_ih1,*bw_hh1,*bb1,*bw_ih2,*bw_hh2,*bb2,*bw_ih3,*bw_hh3,*bb3,*bw_ih4,*bw_hh4,*bb4;
  const float *ft12h,*ft12c,*ft23h,*ft23c,*ft34h,*bt43h,*bt43c,*bt32h,*bt32c,*bt21h,*bt21c;
  float *out;
};

// weight-fragment blob offsets (KB). slot = 1KB = one 16(row)x32(k) bf16 B-fragment.
#define OF1 0
#define OF2 48
#define OF3 72
#define OF4 80
#define OB4 84
#define OB3 86
#define OB2 94
#define OB1 118
#define BLOBB (190*1024)

// ---------------- prep: pack weights into bf16 B-fragments -----------------
__global__ __launch_bounds__(256) void dsgsf_prep(P p, char* blob){
  int s = blockIdx.x;
  const float* wih = nullptr; const float* whh = nullptr;
  int H=0, NG=0, Kx=0, KXT=0, Kh=0, KT=0, NT=0, off=0, o0=0,o1=1,o2=2,o3=3;
  switch(s){
    case 0: wih=p.fw_ih1;               H=64;NG=3;Kx=128;KXT=4;Kh=0; KT=4;NT=12;off=OF1;o1=2;o2=3; break;
    case 1: wih=p.fw_ih2; whh=p.fw_hh2; H=32;NG=4;Kx=64; KXT=2;Kh=32;KT=3;NT=8; off=OF2; break;
    case 2: wih=p.fw_ih3; whh=p.fw_hh3; H=16;NG=4;Kx=32; KXT=1;Kh=16;KT=2;NT=4; off=OF3; break;
    case 3: wih=p.fw_ih4; whh=p.fw_hh4; H=8; NG=4;Kx=16; KXT=1;Kh=8; KT=2;NT=2; off=OF4; break;
    case 4: wih=p.bw_ih4;               H=8; NG=3;Kx=16; KXT=1;Kh=0; KT=1;NT=2; off=OB4;o1=2;o2=3; break;
    case 5: wih=p.bw_ih3; whh=p.bw_hh3; H=16;NG=4;Kx=32; KXT=1;Kh=16;KT=2;NT=4; off=OB3; break;
    case 6: wih=p.bw_ih2; whh=p.bw_hh2; H=32;NG=4;Kx=64; KXT=2;Kh=32;KT=3;NT=8; off=OB2; break;
    default:wih=p.bw_ih1; whh=p.bw_hh1; H=64;NG=3;Kx=128;KXT=4;Kh=64;KT=6;NT=12;off=OB1; break;
  }
  int total = KT*NT*64;
  for (int n = threadIdx.x; n < total; n += 256){
    int kt = n/(NT*64); int rem = n - kt*NT*64; int nt = rem>>6; int lx = rem&63;
    int R = nt*16 + (lx&15);
    int gi = R / H; int feat = R - gi*H;
    int og = (gi==0)? o0 : (gi==1)? o1 : (gi==2)? o2 : o3;
    int src = og*H + feat;
    int k0 = kt*32 + ((lx>>4)<<3);
    unsigned dw[4];
    #pragma unroll
    for (int q=0;q<4;++q){
      float a=0.f, b=0.f;
      int ka = k0+2*q, kb = ka+1;
      if (gi < NG){
        if (ka < Kx) a = wih[(size_t)src*Kx + ka];
        else { int kh = ka - KXT*32; if (kh>=0 && kh<Kh) a = whh[(size_t)src*Kh + kh]; }
        if (kb < Kx) b = wih[(size_t)src*Kx + kb];
        else { int kh = kb - KXT*32; if (kh>=0 && kh<Kh) b = whh[(size_t)src*Kh + kh]; }
      }
      dw[q] = pack2(a,b);
    }
    *(uint4*)(blob + (size_t)off*1024 + (size_t)(kt*NT + nt)*1024 + lx*16) =
        make_uint4(dw[0],dw[1],dw[2],dw[3]);
  }
}

// ---------------- generic GEMM stage driver -----------------
// acc[mtI][g] over 2 m-tiles (mtp*2+mtI) and NG gate-tiles at feat-slice nf.
template<int NG, int NFT, int KT, int NT, class AF>
DEV void gemm_run(f32x4 (&acc)[2][NG], const char* bstage, char* WB,
                  int nf, int mtp, int wu, int l, AF afrag){
  constexpr int NPC = (NT > 8) ? 2 : 1;   // pieces per kt (WB is 8KB)
  constexpr int PS  = NT / NPC;
  for (int kt = 0; kt < KT; ++kt){
    short8 a0 = afrag(kt, mtp*2);
    short8 a1 = afrag(kt, mtp*2+1);
    for (int pc = 0; pc < NPC; ++pc){
      __syncthreads();                    // WB free (prev compute done)
      if (wu < PS)
        gload(bstage + (size_t)(kt*NT + pc*PS + wu)*1024 + l*16, WB + wu*1024 + l*16);
      __syncthreads();                    // WB staged (vmcnt drained at barrier)
      #pragma unroll
      for (int g = 0; g < NG; ++g){
        int slot = g*NFT + nf;
        if (slot >= pc*PS && slot < (pc+1)*PS){
          short8 bf = frag(WB + (slot - pc*PS)*1024 + l*16);
          acc[0][g] = MF(a0, bf, acc[0][g]);
          acc[1][g] = MF(a1, bf, acc[1][g]);
        }
      }
    }
  }
}

template<int NG>
DEV void binit(f32x4 (&acc)[2][NG], const float* bias, int H, int feat,
               int o0, int o1, int o2, int o3){
  int og[4] = {o0,o1,o2,o3};
  #pragma unroll
  for (int g=0; g<NG; ++g){
    float bv = bias[og[g]*H + feat];
    f32x4 v = {bv,bv,bv,bv};
    acc[0][g]=v; acc[1][g]=v;
  }
}

// full-LSTM pointwise on C fragments (gates i,f,g,o)
DEV void pw4(const f32x4 (&acc)[2][4], char* AH, char* AC, const char* BC,
             int arow, int cbrow, int mtp, int l){
  #pragma unroll
  for (int mtI=0;mtI<2;++mtI){
    #pragma unroll
    for (int r=0;r<4;++r){
      int batch = (mtp*2+mtI)*16 + ((l>>4)<<2) + r;
      float cb = ldBF(BC, cbrow, batch);
      float c = sigm(acc[mtI][1][r])*cb + sigm(acc[mtI][0][r])*tanh_(acc[mtI][2][r]);
      float h = sigm(acc[mtI][3][r])*tanh_(c);
      stBF(AH, arow, batch, h);
      stBF(AC, arow, batch, c);
    }
  }
}

// ---------------- trans: conv(k3,pad1,stride S)+softmax, streaming 2-pass ----
// h-variant: writes output directly in A-fragment layout into TF arena.
template<int L, int S, int SZ>
DEV void trans_h(const char* Ain, int row0, const float* tw, char* TFb, int subBase, int b){
  constexpr int O = (S==2)? L/2 : L;
  float w0=tw[0], w1=tw[1], w2=tw[2];
  float s=0.f;
  #pragma unroll
  for (int o=0;o<O;++o){
    int c=S*o;
    float v = w1*ldBF(Ain,row0+c,b);
    if (c>=1)   v += w0*ldBF(Ain,row0+c-1,b);
    if (c+1<L)  v += w2*ldBF(Ain,row0+c+1,b);
    float e=__expf(v); s+=e;
    int fl=o&31; int slot=(subBase+(o>>5))*4+(b>>4);
    *(unsigned short*)(TFb + slot*SZ + ((b&15)+16*(fl>>3))*16 + (fl&7)*2) = f2bf(e);
  }
  float inv=fastrcp(s);
  #pragma unroll
  for (int o=0;o<O;++o){
    int fl=o&31; int slot=(subBase+(o>>5))*4+(b>>4);
    unsigned short* q = (unsigned short*)(TFb + slot*SZ + ((b&15)+16*(fl>>3))*16 + (fl&7)*2);
    *q = f2bf(bf2f(*q)*inv);
  }
}
// c-variant: writes [feat][batch] bf16 (read pointwise as cb)
template<int L, int S>
DEV void trans_c(const char* Ain, int row0, const float* tw, char* BCb, int orow0, int b){
  constexpr int O = (S==2)? L/2 : L;
  float w0=tw[0], w1=tw[1], w2=tw[2];
  float s=0.f;
  #pragma unroll
  for (int o=0;o<O;++o){
    int c=S*o;
    float v = w1*ldBF(Ain,row0+c,b);
    if (c>=1)   v += w0*ldBF(Ain,row0+c-1,b);
    if (c+1<L)  v += w2*ldBF(Ain,row0+c+1,b);
    float e=__expf(v); s+=e;
    stBF(BCb, orow0+o, b, e);
  }
  float inv=fastrcp(s);
  #pragma unroll
  for (int o=0;o<O;++o) stBF(BCb, orow0+o, b, ldBF(BCb,orow0+o,b)*inv);
}

// ---------------- main kernel -----------------
__global__ __launch_bounds__(512, 4) void dsgsf_main(P p, const char* blob){
  __shared__ __align__(16) char SM[65536];
  char* XP  = SM;            // 16KB: spec A-frags, full 32-k chunks [kc*4+mt]
  char* XPH = SM + 16384;    //  8KB: spec A-frags, odd 16-k chunks (half slots)
  char* WB  = SM + 24576;    //  8KB: weight B-frag staging
  char* AH  = SM + 32768;    //  8KB: h state  [feat][batch] bf16 swizzled
  char* AC  = SM + 40960;    //  8KB: c state
  char* BC  = SM + 49152;    //  8KB: trans-c outputs (cb)
  char* TF  = SM + 57344;    //  8KB: trans-h outputs as A-frags (arena, reused)

  const int tid = threadIdx.x;
  const int l   = tid & 63;
  const int wu  = __builtin_amdgcn_readfirstlane(tid >> 6);
  const int mtp = wu & 1, z = wu >> 1;
  const long b0 = (long)blockIdx.x * 64;

  auto xfrag16 = [&](int c16, int mt)->short8 {
    return ((c16&1)==0) ? frag(XP  + (size_t)(((c16>>1)<<2)+mt)*1024 + l*16)
                        : frag(XPH + (size_t)(((c16>>1)<<2)+mt)*512  + (l&31)*16);
  };

  // ---- stage spec into A-fragment layout ----
  #pragma unroll
  for (int it=0; it<2; ++it){
    int n = it*512 + tid; int slot = n>>6, lx = n&63;
    int kc = slot>>2, mt = slot&3;
    const float* sp = p.spec + (b0 + mt*16 + (lx&15))*128 + kc*32 + ((lx>>4)<<3);
    float4 v0 = *(const float4*)sp; float4 v1 = *(const float4*)(sp+4);
    unsigned* dst = (unsigned*)(XP + (size_t)slot*1024 + lx*16);
    dst[0]=pack2(v0.x,v0.y); dst[1]=pack2(v0.z,v0.w);
    dst[2]=pack2(v1.x,v1.y); dst[3]=pack2(v1.z,v1.w);
  }
  { // odd 16-chunks (for F4/B4 odd steps), half slots
    int slot = tid>>5, lx = tid&31;
    int c16 = ((slot>>2)<<1)+1, mt = slot&3;
    const float* sp = p.spec + (b0 + mt*16 + (lx&15))*128 + c16*16 + ((lx>>4)<<3);
    float4 v0 = *(const float4*)sp; float4 v1 = *(const float4*)(sp+4);
    unsigned* dst = (unsigned*)(XPH + (size_t)slot*512 + lx*16);
    dst[0]=pack2(v0.x,v0.y); dst[1]=pack2(v0.z,v0.w);
    dst[2]=pack2(v1.x,v1.y); dst[3]=pack2(v1.z,v1.w);
  }
  __syncthreads();

  // ================= F1: lstm0(spec), gates i,g,o =================
  {
    f32x4 acc[2][3];
    int feat = z*16 + (l&15);
    binit<3>(acc, p.fb1, 64, feat, 0,2,3,0);
    auto af = [&](int kt, int mt){ return frag(XP + (size_t)((kt<<2)+mt)*1024 + l*16); };
    gemm_run<3,4,4,12>(acc, blob + (size_t)OF1*1024, WB, z, mtp, wu, l, af);
    #pragma unroll
    for (int mtI=0;mtI<2;++mtI)
      #pragma unroll
      for (int r=0;r<4;++r){
        int batch = (mtp*2+mtI)*16 + ((l>>4)<<2) + r;
        float c = sigm(acc[mtI][0][r])*tanh_(acc[mtI][1][r]);
        float h = sigm(acc[mtI][2][r])*tanh_(c);
        stBF(AH, feat, batch, h); stBF(AC, feat, batch, c);
      }
  }
  __syncthreads();
  if (wu==0)      trans_h<64,2,1024>(AH, 0, p.ft12h, TF, 0, l);
  else if (wu==1) trans_c<64,2>(AC, 0, p.ft12c, BC, 0, l);

  // ================= F2 =================
  {
    f32x4 acc[2][4];
    int step = z>>1, nf = z&1;
    int feat = nf*16 + (l&15);
    binit<4>(acc, p.fb2, 32, feat, 0,1,2,3);
    auto af = [&](int kt, int mt){
      return (kt<2) ? frag(XP + (size_t)(((2*step+kt)<<2)+mt)*1024 + l*16)
                    : frag(TF + (size_t)mt*1024 + l*16); };
    gemm_run<4,2,3,8>(acc, blob + (size_t)OF2*1024, WB, nf, mtp, wu, l, af);
    pw4(acc, AH, AC, BC, step*32+feat, feat, mtp, l);
  }
  __syncthreads();
  if (wu<2)      trans_h<32,2,512>(AH, wu*32, p.ft23h, TF, wu, l);
  else if (wu<4) trans_c<32,2>(AC, (wu-2)*32, p.ft23c, BC, (wu-2)*16, l);

  // ================= F3 =================
  {
    f32x4 acc[2][4];
    int s = z, feat = l&15;
    binit<4>(acc, p.fb3, 16, feat, 0,1,2,3);
    auto af = [&](int kt, int mt){
      return (kt==0) ? frag(XP + (size_t)((s<<2)+mt)*1024 + l*16)
                     : frag(TF + (size_t)(((s>>1)<<2)+mt)*512 + (l&31)*16); };
    gemm_run<4,1,2,4>(acc, blob + (size_t)OF3*1024, WB, 0, mtp, wu, l, af);
    pw4(acc, AH, AC, BC, s*16+feat, (s>>1)*16+feat, mtp, l);
  }
  __syncthreads();
  if (wu<4) trans_h<16,2,256>(AH, wu*16, p.ft34h, TF, wu, l);
  else      trans_c<16,2>(AC, (wu-4)*16, p.ft34h, BC, (wu-4)*8, l);  // ref bug: ft34h for c

  // ================= F4 (H=8): rows [i8,f8,g8,o8] =================
  {
    f32x4 a4[2][2][2]; // [uu][mtI][tile]
    float bv0 = p.fb4[l&15], bv1 = p.fb4[16+(l&15)];
    #pragma unroll
    for (int uu=0;uu<2;++uu)
      #pragma unroll
      for (int mtI=0;mtI<2;++mtI){ a4[uu][mtI][0]=f32x4{bv0,bv0,bv0,bv0}; a4[uu][mtI][1]=f32x4{bv1,bv1,bv1,bv1}; }
    for (int kt=0;kt<2;++kt){
      __syncthreads();
      if (wu<2) gload(blob + (size_t)(OF4 + kt*2 + wu)*1024 + l*16, WB + wu*1024 + l*16);
      __syncthreads();
      #pragma unroll
      for (int uu=0;uu<2;++uu){
        int u = z*2+uu;
        #pragma unroll
        for (int mtI=0;mtI<2;++mtI){
          int mt = mtp*2+mtI;
          short8 a = (kt==0) ? xfrag16(u,mt)
                             : frag(TF + (size_t)(((u>>1)<<2)+mt)*256 + (l&15)*16);
          a4[uu][mtI][0] = MF(a, frag(WB + l*16),        a4[uu][mtI][0]);
          a4[uu][mtI][1] = MF(a, frag(WB + 1024 + l*16), a4[uu][mtI][1]);
        }
      }
    }
    #pragma unroll
    for (int uu=0;uu<2;++uu)
      #pragma unroll
      for (int mtI=0;mtI<2;++mtI)
        #pragma unroll
        for (int r=0;r<4;++r){
          float iv = a4[uu][mtI][0][r], gv = a4[uu][mtI][1][r];
          float xf = __shfl_xor(iv,8), xo = __shfl_xor(gv,8);
          if ((l&15)<8){
            int q = l&15, u = z*2+uu;
            int batch = (mtp*2+mtI)*16 + ((l>>4)<<2) + r;
            float cb = ldBF(BC, (u>>1)*8+q, batch);
            float c = sigm(xf)*cb + sigm(iv)*tanh_(gv);
            float h = sigm(xo)*tanh_(c);
            p.out[(size_t)(b0+batch)*128 + u*8 + q] = h;
          }
        }
  }

  // ================= B4: lstm0(x4), rows [i8,g8,o8,pad8] =================
  {
    f32x4 a4[2][2][2];
    float bv0 = ((l&15)<8) ? p.bb4[l&15] : p.bb4[(l&15)+8];   // i | g
    float bv1 = ((l&15)<8) ? p.bb4[24+(l&15)] : 0.f;          // o | pad
    #pragma unroll
    for (int uu=0;uu<2;++uu)
      #pragma unroll
      for (int mtI=0;mtI<2;++mtI){ a4[uu][mtI][0]=f32x4{bv0,bv0,bv0,bv0}; a4[uu][mtI][1]=f32x4{bv1,bv1,bv1,bv1}; }
    __syncthreads();
    if (wu<2) gload(blob + (size_t)(OB4 + wu)*1024 + l*16, WB + wu*1024 + l*16);
    __syncthreads();
    #pragma unroll
    for (int uu=0;uu<2;++uu){
      int u = z*2+uu;
      #pragma unroll
      for (int mtI=0;mtI<2;++mtI){
        int mt = mtp*2+mtI;
        short8 a = xfrag16(u,mt);
        a4[uu][mtI][0] = MF(a, frag(WB + l*16),        a4[uu][mtI][0]);
        a4[uu][mtI][1] = MF(a, frag(WB + 1024 + l*16), a4[uu][mtI][1]);
      }
    }
    #pragma unroll
    for (int uu=0;uu<2;++uu)
      #pragma unroll
      for (int mtI=0;mtI<2;++mtI)
        #pragma unroll
        for (int r=0;r<4;++r){
          float iv = a4[uu][mtI][0][r], ov = a4[uu][mtI][1][r];
          float gv = __shfl_xor(iv,8);
          if ((l&15)<8){
            int q = l&15, u = z*2+uu;
            int batch = (mtp*2+mtI)*16 + ((l>>4)<<2) + r;
            float c = sigm(iv)*tanh_(gv);
            float h = sigm(ov)*tanh_(c);
            stBF(AH, u*8+q, batch, h); stBF(AC, u*8+q, batch, c);
          }
        }
  }
  __syncthreads();
  if (wu<4) trans_h<16,1,512>(AH, wu*16, p.bt43h, TF, wu, l);
  else      trans_c<16,1>(AC, (wu-4)*16, p.bt43c, BC, (wu-4)*16, l);

  // ================= B3 =================
  {
    f32x4 acc[2][4];
    int s = z, feat = l&15;
    binit<4>(acc, p.bb3, 16, feat, 0,1,2,3);
    auto af = [&](int kt, int mt){
      return (kt==0) ? frag(XP + (size_t)((s<<2)+mt)*1024 + l*16)
                     : frag(TF + (size_t)((s<<2)+mt)*512 + (l&31)*16); };
    gemm_run<4,1,2,4>(acc, blob + (size_t)OB3*1024, WB, 0, mtp, wu, l, af);
    pw4(acc, AH, AC, BC, s*16+feat, s*16+feat, mtp, l);
  }
  __syncthreads();
  if (wu<2)      trans_h<32,1,1024>(AH, wu*32, p.bt32h, TF, wu, l);
  else if (wu<4) trans_c<32,1>(AC, (wu-2)*32, p.bt32c, BC, (wu-2)*32, l);

  // ================= B2 =================
  {
    f32x4 acc[2][4];
    int t2 = z>>1, nf = z&1;
    int feat = nf*16 + (l&15);
    binit<4>(acc, p.bb2, 32, feat, 0,1,2,3);
    auto af = [&](int kt, int mt){
      return (kt<2) ? frag(XP + (size_t)(((2*t2+kt)<<2)+mt)*1024 + l*16)
                    : frag(TF + (size_t)((t2<<2)+mt)*1024 + l*16); };
    gemm_run<4,2,3,8>(acc, blob + (size_t)OB2*1024, WB, nf, mtp, wu, l, af);
    pw4(acc, AH, AC, BC, t2*32+feat, t2*32+feat, mtp, l);
  }
  __syncthreads();
  if (wu==0)      trans_h<64,1,1024>(AH, 0, p.bt21h, TF, 0, l);
  else if (wu==1) trans_c<64,1>(AC, 0, p.bt21c, BC, 0, l);

  // ================= B1: gates i,f,g -> c only =================
  {
    f32x4 acc[2][3];
    int feat = z*16 + (l&15);
    binit<3>(acc, p.bb1, 64, feat, 0,1,2,0);
    auto af = [&](int kt, int mt){
      return (kt<4) ? frag(XP + (size_t)((kt<<2)+mt)*1024 + l*16)
                    : frag(TF + (size_t)(((kt-4)<<2)+mt)*1024 + l*16); };
    gemm_run<3,4,6,12>(acc, blob + (size_t)OB1*1024, WB, z, mtp, wu, l, af);
    #pragma unroll
    for (int mtI=0;mtI<2;++mtI)
      #pragma unroll
      for (int r=0;r<4;++r){
        int batch = (mtp*2+mtI)*16 + ((l>>4)<<2) + r;
        float cb = ldBF(BC, feat, batch);
        float c = sigm(acc[mtI][1][r])*cb + sigm(acc[mtI][0][r])*tanh_(acc[mtI][2][r]);
        p.out[(size_t)(b0+batch)*128 + 64 + feat] = c;
      }
  }
}

extern "C" void kernel_launch(void* const* d_in, const int* in_sizes, int n_in,
                              void* d_out, int out_size, void* d_ws, size_t ws_size,
                              hipStream_t stream) {
  if (ws_size < (size_t)BLOBB) return;  // need 190KB scratch for weight fragments
  P p;
  p.spec   = (const float*)d_in[0];
  p.fw_ih1 = (const float*)d_in[1];  p.fw_hh1 = (const float*)d_in[2];  p.fb1 = (const float*)d_in[3];
  p.fw_ih2 = (const float*)d_in[4];  p.fw_hh2 = (const float*)d_in[5];  p.fb2 = (const float*)d_in[6];
  p.fw_ih3 = (const float*)d_in[7];  p.fw_hh3 = (const float*)d_in[8];  p.fb3 = (const float*)d_in[9];
  p.fw_ih4 = (const float*)d_in[10]; p.fw_hh4 = (const float*)d_in[11]; p.fb4 = (const float*)d_in[12];
  p.bw_ih1 = (const float*)d_in[13]; p.bw_hh1 = (const float*)d_in[14]; p.bb1 = (const float*)d_in[15];
  p.bw_ih2 = (const float*)d_in[16]; p.bw_hh2 = (const float*)d_in[17]; p.bb2 = (const float*)d_in[18];
  p.bw_ih3 = (const float*)d_in[19]; p.bw_hh3 = (const float*)d_in[20]; p.bb3 = (const float*)d_in[21];
  p.bw_ih4 = (const float*)d_in[22]; p.bw_hh4 = (const float*)d_in[23]; p.bb4 = (const float*)d_in[24];
  p.ft12h = (const float*)d_in[25]; p.ft12c = (const float*)d_in[26];
  p.ft23h = (const float*)d_in[27]; p.ft23c = (const float*)d_in[28];
  p.ft34h = (const float*)d_in[29];
  p.bt43h = (const float*)d_in[30]; p.bt43c = (const float*)d_in[31];
  p.bt32h = (const float*)d_in[32]; p.bt32c = (const float*)d_in[33];
  p.bt21h = (const float*)d_in[34]; p.bt21c = (const float*)d_in[35];
  p.out = (float*)d_out;

  char* blob = (char*)d_ws;
  hipLaunchKernelGGL(dsgsf_prep, dim3(8), dim3(256), 0, stream, p, blob);
  int Bn = in_sizes[0] / 128;
  hipLaunchKernelGGL(dsgsf_main, dim3(Bn/64), dim3(512), 0, stream, p, (const char*)blob);
}

// Round 3
// 216.120 us; speedup vs baseline: 7.6348x; 1.0438x over previous
//
#include <hip/hip_runtime.h>

typedef __attribute__((ext_vector_type(4))) float f32x4;
typedef __attribute__((ext_vector_type(8))) short short8;

#define DEV __device__ __forceinline__

DEV float fastrcp(float x){ return __builtin_amdgcn_rcpf(x); }
DEV float sigm(float x){ return fastrcp(1.f + __expf(-x)); }
DEV float tanh_(float x){ return 1.f - 2.f*fastrcp(__expf(2.f*x)+1.f); }
DEV unsigned short f2bf(float f){ unsigned u=__float_as_uint(f); u += 0x7fffu + ((u>>16)&1u); return (unsigned short)(u>>16); }
DEV float bf2f(unsigned short h){ return __uint_as_float(((unsigned)h)<<16); }
DEV unsigned pack2(float a, float b){ return (unsigned)f2bf(a) | ((unsigned)f2bf(b)<<16); }

// bank swizzle for [feat][64batch] bf16 arrays (2-way-free on all hot patterns)
DEV int gmask(int f){ return ((f&1)<<5) | (f&2) | ((f&4)<<2); }
DEV void stBF(char* A, int f, int b, float v){ *(unsigned short*)(A + (((f<<6) + (b ^ gmask(f)))<<1)) = f2bf(v); }
DEV float ldBF(const char* A, int f, int b){ return bf2f(*(const unsigned short*)(A + (((f<<6) + (b ^ gmask(f)))<<1))); }

DEV short8 frag(const char* p){ return *(const short8*)p; }
DEV short8 gfrag(const char* p){ return *(const short8*)p; }   // global B-frag -> VGPR
DEV f32x4 MF(short8 a, short8 b, f32x4 c){ return __builtin_amdgcn_mfma_f32_16x16x32_bf16(a,b,c,0,0,0); }

struct P {
  const float *spec;
  const float *fw_ih1,*fw_hh1,*fb1,*fw_ih2,*fw_hh2,*fb2,*fw_ih3,*fw_hh3,*fb3,*fw_ih4,*fw_hh4,*fb4;
  const float *bw_ih1,*bw_hh1,*bb1,*bw_ih2,*bw_hh2,*bb2,*bw_ih3,*bw_hh3,*bb3,*bw_ih4,*bw_hh4,*bb4;
  const float *ft12h,*ft12c,*ft23h,*ft23c,*ft34h,*bt43h,*bt43c,*bt32h,*bt32c,*bt21h,*bt21c;
  float *out;
};

// blob offsets in KB; slot = 1KB = one 16(row)x32(k) bf16 B-fragment
#define OF1 0
#define OF2 48
#define OF3 72
#define OF4 80
#define OB4 86
#define OB3 90
#define OB2 98
#define OB1 122
#define BLOBB (194*1024)

// ---------------- prep: pack weights into bf16 B-fragments -----------------
__global__ __launch_bounds__(256) void dsgsf_prep(P p, char* blob){
  int s = blockIdx.x;
  if (s == 3 || s == 4){            // F4 / B4: parity-packed (full 32-k spec chunks)
    bool isF = (s == 3);
    const float* wih = isF ? p.fw_ih4 : p.bw_ih4;
    const float* whh = p.fw_hh4;
    int nslot = isF ? 6 : 4;
    int off   = isF ? OF4 : OB4;
    for (int n = threadIdx.x; n < nslot*64; n += 256){
      int st = n>>6, lx = n&63;
      int R = lx&15, half = R>>3, feat = R&7;
      int k0 = ((lx>>4)<<3);
      unsigned dw[4];
      #pragma unroll
      for (int q=0;q<4;++q){
        float a=0.f, bv=0.f;
        int ka=k0+2*q, kb=ka+1;
        if (isF){
          if (st < 4){
            int pp = st>>1, t = st&1;
            int gi = t*2 + half;                 // t0:[i,f] t1:[g,o]
            int src = gi*8 + feat, base = pp*16;
            if (ka>=base && ka<base+16) a  = wih[src*16 + (ka-base)];
            if (kb>=base && kb<base+16) bv = wih[src*16 + (kb-base)];
          } else {
            int t = st-4; int gi = t*2 + half; int src = gi*8 + feat;
            if (ka<8) a  = whh[src*8+ka];
            if (kb<8) bv = whh[src*8+kb];
          }
        } else {
          int pp = st>>1, t = st&1;
          int gi = (t==0) ? (half? 2:0) : (half? -1:3);   // t0:[i,g] t1:[o,pad]
          if (gi >= 0){
            int src = gi*8 + feat, base = pp*16;
            if (ka>=base && ka<base+16) a  = wih[src*16 + (ka-base)];
            if (kb>=base && kb<base+16) bv = wih[src*16 + (kb-base)];
          }
        }
        dw[q] = pack2(a,bv);
      }
      *(uint4*)(blob + (size_t)(off+st)*1024 + lx*16) = make_uint4(dw[0],dw[1],dw[2],dw[3]);
    }
    return;
  }
  const float* wih=nullptr; const float* whh=nullptr;
  int H=0,NG=0,Kx=0,KXT=0,Kh=0,KT=0,NT=0,off=0,o0=0,o1=1,o2=2,o3=3;
  switch(s){
    case 0: wih=p.fw_ih1;               H=64;NG=3;Kx=128;KXT=4;Kh=0; KT=4;NT=12;off=OF1;o1=2;o2=3; break;
    case 1: wih=p.fw_ih2; whh=p.fw_hh2; H=32;NG=4;Kx=64; KXT=2;Kh=32;KT=3;NT=8; off=OF2; break;
    case 2: wih=p.fw_ih3; whh=p.fw_hh3; H=16;NG=4;Kx=32; KXT=1;Kh=16;KT=2;NT=4; off=OF3; break;
    case 5: wih=p.bw_ih3; whh=p.bw_hh3; H=16;NG=4;Kx=32; KXT=1;Kh=16;KT=2;NT=4; off=OB3; break;
    case 6: wih=p.bw_ih2; whh=p.bw_hh2; H=32;NG=4;Kx=64; KXT=2;Kh=32;KT=3;NT=8; off=OB2; break;
    default:wih=p.bw_ih1; whh=p.bw_hh1; H=64;NG=3;Kx=128;KXT=4;Kh=64;KT=6;NT=12;off=OB1; break;
  }
  int total = KT*NT*64;
  for (int n = threadIdx.x; n < total; n += 256){
    int kt = n/(NT*64); int rem = n - kt*NT*64; int nt = rem>>6; int lx = rem&63;
    int R = nt*16 + (lx&15);
    int gi = R / H; int feat = R - gi*H;
    int og = (gi==0)? o0 : (gi==1)? o1 : (gi==2)? o2 : o3;
    int src = og*H + feat;
    int k0 = kt*32 + ((lx>>4)<<3);
    unsigned dw[4];
    #pragma unroll
    for (int q=0;q<4;++q){
      float a=0.f, b=0.f;
      int ka=k0+2*q, kb=ka+1;
      if (gi < NG){
        if (ka < Kx) a = wih[(size_t)src*Kx + ka];
        else { int kh = ka - KXT*32; if (kh>=0 && kh<Kh) a = whh[(size_t)src*Kh + kh]; }
        if (kb < Kx) b = wih[(size_t)src*Kx + kb];
        else { int kh = kb - KXT*32; if (kh>=0 && kh<Kh) b = whh[(size_t)src*Kh + kh]; }
      }
      dw[q] = pack2(a,b);
    }
    *(uint4*)(blob + (size_t)off*1024 + (size_t)(kt*NT + nt)*1024 + lx*16) =
        make_uint4(dw[0],dw[1],dw[2],dw[3]);
  }
}

// ---------------- GEMM: B-fragments direct global->VGPR, no barriers ----------
template<int NG,int NFT,int KT, class AF>
DEV void gemm_reg(f32x4 (&acc)[2][NG], const char* bstage, int nf, int mtp, int l, AF af){
  constexpr int NT = NG*NFT;
  #pragma unroll
  for (int kt=0; kt<KT; ++kt){
    short8 a0 = af(kt, mtp*2);
    short8 a1 = af(kt, mtp*2+1);
    #pragma unroll
    for (int g=0; g<NG; ++g){
      short8 bf = gfrag(bstage + (size_t)(kt*NT + g*NFT + nf)*1024 + l*16);
      acc[0][g] = MF(a0, bf, acc[0][g]);
      acc[1][g] = MF(a1, bf, acc[1][g]);
    }
  }
}

template<int NG>
DEV void binit(f32x4 (&acc)[2][NG], const float* bias, int H, int feat,
               int o0, int o1, int o2, int o3){
  int og[4] = {o0,o1,o2,o3};
  #pragma unroll
  for (int g=0; g<NG; ++g){
    float bv = bias[og[g]*H + feat];
    f32x4 v = {bv,bv,bv,bv};
    acc[0][g]=v; acc[1][g]=v;
  }
}

DEV void pw4(const f32x4 (&acc)[2][4], char* AH, char* AC, const char* BC,
             int arow, int cbrow, int mtp, int l){
  #pragma unroll
  for (int mtI=0;mtI<2;++mtI){
    #pragma unroll
    for (int r=0;r<4;++r){
      int batch = (mtp*2+mtI)*16 + ((l>>4)<<2) + r;
      float cb = ldBF(BC, cbrow, batch);
      float c = sigm(acc[mtI][1][r])*cb + sigm(acc[mtI][0][r])*tanh_(acc[mtI][2][r]);
      float h = sigm(acc[mtI][3][r])*tanh_(c);
      stBF(AH, arow, batch, h);
      stBF(AC, arow, batch, c);
    }
  }
}

// ---- trans: conv(k3,pad1,stride S)+exp for NO outputs, kept in registers ----
template<int L,int S,int NO>
DEV void convE(const char* Ain, int row0, const float* tw, int o0, int b,
               float (&y)[NO], float& s){
  float w0=tw[0], w1=tw[1], w2=tw[2];
  s = 0.f;
  #pragma unroll
  for (int j=0;j<NO;++j){
    int o=o0+j, c=S*o;
    float v = w1*ldBF(Ain,row0+c,b);
    if (c>=1)   v += w0*ldBF(Ain,row0+c-1,b);
    if (c+1<L)  v += w2*ldBF(Ain,row0+c+1,b);
    y[j] = __expf(v); s += y[j];
  }
}
// normalized write, A-fragment layout (one 16B store per 8 outputs)
template<int SZ,int NO>
DEV void wrTF(char* TFb, int subBase, int o0, int b, const float (&y)[NO], float inv){
  #pragma unroll
  for (int g8=0; g8<NO/8; ++g8){
    int oo = o0 + g8*8, fl = oo&31;
    char* base = TFb + (size_t)((subBase+(oo>>5))*4+(b>>4))*SZ + ((b&15)+16*(fl>>3))*16;
    unsigned d0=pack2(y[g8*8+0]*inv,y[g8*8+1]*inv), d1=pack2(y[g8*8+2]*inv,y[g8*8+3]*inv);
    unsigned d2=pack2(y[g8*8+4]*inv,y[g8*8+5]*inv), d3=pack2(y[g8*8+6]*inv,y[g8*8+7]*inv);
    *(uint4*)base = make_uint4(d0,d1,d2,d3);
  }
}
template<int NO>
DEV void wrBC(char* BCb, int row0, int b, const float (&y)[NO], float inv){
  #pragma unroll
  for (int j=0;j<NO;++j) stBF(BCb, row0+j, b, y[j]*inv);
}

// ---------------- main kernel -----------------
__global__ __launch_bounds__(512, 6) void dsgsf_main(P p, const char* blob){
  __shared__ __align__(16) char SM[51200];
  char* XP = SM;               // 16KB: spec A-frags [kc*4+mt]
  char* AH = SM + 16384;       //  8KB: h state [feat][batch] bf16 swizzled
  char* AC = SM + 24576;       //  8KB: c state
  char* BC = SM + 32768;       //  8KB: trans-c outputs
  char* TF = SM + 40960;       //  8KB: trans-h outputs as A-frags
  float* PSm = (float*)(SM + 49152);  // 2KB: softmax partial sums [task][batch]

  const int tid = threadIdx.x;
  const int l   = tid & 63;
  const int wu  = __builtin_amdgcn_readfirstlane(tid >> 6);
  const int mtp = wu & 1, z = wu >> 1;
  const long b0 = (long)blockIdx.x * 64;

  // ---- stage spec into A-fragment layout ----
  #pragma unroll
  for (int it=0; it<2; ++it){
    int n = it*512 + tid; int slot = n>>6, lx = n&63;
    int kc = slot>>2, mt = slot&3;
    const float* sp = p.spec + (b0 + mt*16 + (lx&15))*128 + kc*32 + ((lx>>4)<<3);
    float4 v0 = *(const float4*)sp; float4 v1 = *(const float4*)(sp+4);
    unsigned* dst = (unsigned*)(XP + (size_t)slot*1024 + lx*16);
    dst[0]=pack2(v0.x,v0.y); dst[1]=pack2(v0.z,v0.w);
    dst[2]=pack2(v1.x,v1.y); dst[3]=pack2(v1.z,v1.w);
  }
  __syncthreads();

  // ================= F1: lstm0(spec), gates i,g,o =================
  {
    f32x4 acc[2][3];
    int feat = z*16 + (l&15);
    binit<3>(acc, p.fb1, 64, feat, 0,2,3,0);
    auto af = [&](int kt, int mt){ return frag(XP + (size_t)((kt<<2)+mt)*1024 + l*16); };
    gemm_reg<3,4,4>(acc, blob + (size_t)OF1*1024, z, mtp, l, af);
    #pragma unroll
    for (int mtI=0;mtI<2;++mtI)
      #pragma unroll
      for (int r=0;r<4;++r){
        int batch = (mtp*2+mtI)*16 + ((l>>4)<<2) + r;
        float c = sigm(acc[mtI][0][r])*tanh_(acc[mtI][1][r]);
        float h = sigm(acc[mtI][2][r])*tanh_(c);
        stBF(AH, feat, batch, h); stBF(AC, feat, batch, c);
      }
  }
  __syncthreads();

  // ---- T12: chunks of 8, psum over 4 ----
  {
    float y[8], s;
    if (wu<4) convE<64,2,8>(AH, 0, p.ft12h, wu*8, l, y, s);
    else      convE<64,2,8>(AC, 0, p.ft12c, (wu-4)*8, l, y, s);
    PSm[wu*64+l] = s;
    __syncthreads();
    float tot = (wu<4) ? PSm[0*64+l]+PSm[1*64+l]+PSm[2*64+l]+PSm[3*64+l]
                       : PSm[4*64+l]+PSm[5*64+l]+PSm[6*64+l]+PSm[7*64+l];
    float inv = fastrcp(tot);
    if (wu<4) wrTF<1024,8>(TF, 0, wu*8, l, y, inv);
    else      wrBC<8>(BC, (wu-4)*8, l, y, inv);
  }
  __syncthreads();

  // ================= F2 =================
  {
    f32x4 acc[2][4];
    int step = z>>1, nf = z&1;
    int feat = nf*16 + (l&15);
    binit<4>(acc, p.fb2, 32, feat, 0,1,2,3);
    auto af = [&](int kt, int mt){
      return (kt<2) ? frag(XP + (size_t)(((2*step+kt)<<2)+mt)*1024 + l*16)
                    : frag(TF + (size_t)mt*1024 + l*16); };
    gemm_reg<4,2,3>(acc, blob + (size_t)OF2*1024, nf, mtp, l, af);
    pw4(acc, AH, AC, BC, step*32+feat, feat, mtp, l);
  }
  __syncthreads();

  // ---- T23: 2 steps x 2 chunks of 8, psum pairs ----
  {
    float y[8], s; int v=wu&3, st=v>>1, ch=v&1;
    if (wu<4) convE<32,2,8>(AH, st*32, p.ft23h, ch*8, l, y, s);
    else      convE<32,2,8>(AC, st*32, p.ft23c, ch*8, l, y, s);
    PSm[wu*64+l] = s;
    __syncthreads();
    int base = (wu&4) | (st<<1);
    float inv = fastrcp(PSm[base*64+l] + PSm[(base|1)*64+l]);
    if (wu<4) wrTF<512,8>(TF, st, ch*8, l, y, inv);
    else      wrBC<8>(BC, st*16+ch*8, l, y, inv);
  }
  __syncthreads();

  // ================= F3 =================
  {
    f32x4 acc[2][4];
    int s = z, feat = l&15;
    binit<4>(acc, p.fb3, 16, feat, 0,1,2,3);
    auto af = [&](int kt, int mt){
      return (kt==0) ? frag(XP + (size_t)((s<<2)+mt)*1024 + l*16)
                     : frag(TF + (size_t)(((s>>1)<<2)+mt)*512 + (l&31)*16); };
    gemm_reg<4,1,2>(acc, blob + (size_t)OF3*1024, 0, mtp, l, af);
    pw4(acc, AH, AC, BC, s*16+feat, (s>>1)*16+feat, mtp, l);
  }
  __syncthreads();

  // ---- T34: 8 independent rows of 8, local sums ----
  {
    float y[8], s;
    if (wu<4){ convE<16,2,8>(AH, wu*16, p.ft34h, 0, l, y, s);
               wrTF<256,8>(TF, wu, 0, l, y, fastrcp(s)); }
    else     { convE<16,2,8>(AC, (wu-4)*16, p.ft34h, 0, l, y, s);   // ref bug: ft34h for c
               wrBC<8>(BC, (wu-4)*8, l, y, fastrcp(s)); }
  }
  __syncthreads();

  // ================= F4 (parity-packed) =================
  {
    f32x4 a4[2][2][2]; // [parity uu][mtI][tile]
    float bv0 = p.fb4[l&15], bv1 = p.fb4[16+(l&15)];
    #pragma unroll
    for (int uu=0;uu<2;++uu)
      #pragma unroll
      for (int mtI=0;mtI<2;++mtI){ a4[uu][mtI][0]=f32x4{bv0,bv0,bv0,bv0}; a4[uu][mtI][1]=f32x4{bv1,bv1,bv1,bv1}; }
    const char* bs = blob + (size_t)OF4*1024;
    short8 A0 = frag(XP + (size_t)((z<<2)+mtp*2  )*1024 + l*16);
    short8 A1 = frag(XP + (size_t)((z<<2)+mtp*2+1)*1024 + l*16);
    short8 H0 = frag(TF + (size_t)((z<<2)+mtp*2  )*256 + (l&15)*16);
    short8 H1 = frag(TF + (size_t)((z<<2)+mtp*2+1)*256 + (l&15)*16);
    short8 bh0 = gfrag(bs + 4*1024 + l*16);
    short8 bh1 = gfrag(bs + 5*1024 + l*16);
    #pragma unroll
    for (int uu=0;uu<2;++uu){
      short8 bx0 = gfrag(bs + (uu*2+0)*1024 + l*16);
      short8 bx1 = gfrag(bs + (uu*2+1)*1024 + l*16);
      a4[uu][0][0]=MF(A0,bx0,a4[uu][0][0]); a4[uu][0][1]=MF(A0,bx1,a4[uu][0][1]);
      a4[uu][1][0]=MF(A1,bx0,a4[uu][1][0]); a4[uu][1][1]=MF(A1,bx1,a4[uu][1][1]);
      a4[uu][0][0]=MF(H0,bh0,a4[uu][0][0]); a4[uu][0][1]=MF(H0,bh1,a4[uu][0][1]);
      a4[uu][1][0]=MF(H1,bh0,a4[uu][1][0]); a4[uu][1][1]=MF(H1,bh1,a4[uu][1][1]);
    }
    #pragma unroll
    for (int uu=0;uu<2;++uu)
      #pragma unroll
      for (int mtI=0;mtI<2;++mtI)
        #pragma unroll
        for (int r=0;r<4;++r){
          float iv = a4[uu][mtI][0][r], gv = a4[uu][mtI][1][r];
          float xf = __shfl_xor(iv,8), xo = __shfl_xor(gv,8);
          if ((l&15)<8){
            int q = l&15, u = z*2+uu;
            int batch = (mtp*2+mtI)*16 + ((l>>4)<<2) + r;
            float cb = ldBF(BC, (u>>1)*8+q, batch);
            float c = sigm(xf)*cb + sigm(iv)*tanh_(gv);
            float h = sigm(xo)*tanh_(c);
            p.out[(size_t)(b0+batch)*128 + u*8 + q] = h;
          }
        }
  }

  // ================= B4 (parity-packed lstm0) =================
  {
    f32x4 a4[2][2][2];
    float bv0 = ((l&15)<8) ? p.bb4[l&15] : p.bb4[(l&15)+8];   // i | g
    float bv1 = ((l&15)<8) ? p.bb4[24+(l&15)] : 0.f;          // o | pad
    #pragma unroll
    for (int uu=0;uu<2;++uu)
      #pragma unroll
      for (int mtI=0;mtI<2;++mtI){ a4[uu][mtI][0]=f32x4{bv0,bv0,bv0,bv0}; a4[uu][mtI][1]=f32x4{bv1,bv1,bv1,bv1}; }
    const char* bs = blob + (size_t)OB4*1024;
    short8 A0 = frag(XP + (size_t)((z<<2)+mtp*2  )*1024 + l*16);
    short8 A1 = frag(XP + (size_t)((z<<2)+mtp*2+1)*1024 + l*16);
    #pragma unroll
    for (int uu=0;uu<2;++uu){
      short8 bx0 = gfrag(bs + (uu*2+0)*1024 + l*16);
      short8 bx1 = gfrag(bs + (uu*2+1)*1024 + l*16);
      a4[uu][0][0]=MF(A0,bx0,a4[uu][0][0]); a4[uu][0][1]=MF(A0,bx1,a4[uu][0][1]);
      a4[uu][1][0]=MF(A1,bx0,a4[uu][1][0]); a4[uu][1][1]=MF(A1,bx1,a4[uu][1][1]);
    }
    #pragma unroll
    for (int uu=0;uu<2;++uu)
      #pragma unroll
      for (int mtI=0;mtI<2;++mtI)
        #pragma unroll
        for (int r=0;r<4;++r){
          float iv = a4[uu][mtI][0][r], ov = a4[uu][mtI][1][r];
          float gv = __shfl_xor(iv,8);
          if ((l&15)<8){
            int q = l&15, u = z*2+uu;
            int batch = (mtp*2+mtI)*16 + ((l>>4)<<2) + r;
            float c = sigm(iv)*tanh_(gv);
            float h = sigm(ov)*tanh_(c);
            stBF(AH, u*8+q, batch, h); stBF(AC, u*8+q, batch, c);
          }
        }
  }
  __syncthreads();

  // ---- T43: 8 independent rows of 16, local sums ----
  {
    float y[16], s;
    if (wu<4){ convE<16,1,16>(AH, wu*16, p.bt43h, 0, l, y, s);
               wrTF<512,16>(TF, wu, 0, l, y, fastrcp(s)); }
    else     { convE<16,1,16>(AC, (wu-4)*16, p.bt43c, 0, l, y, s);
               wrBC<16>(BC, (wu-4)*16, l, y, fastrcp(s)); }
  }
  __syncthreads();

  // ================= B3 =================
  {
    f32x4 acc[2][4];
    int s = z, feat = l&15;
    binit<4>(acc, p.bb3, 16, feat, 0,1,2,3);
    auto af = [&](int kt, int mt){
      return (kt==0) ? frag(XP + (size_t)((s<<2)+mt)*1024 + l*16)
                     : frag(TF + (size_t)((s<<2)+mt)*512 + (l&31)*16); };
    gemm_reg<4,1,2>(acc, blob + (size_t)OB3*1024, 0, mtp, l, af);
    pw4(acc, AH, AC, BC, s*16+feat, s*16+feat, mtp, l);
  }
  __syncthreads();

  // ---- T32: 2 steps x 2 chunks of 16, psum pairs ----
  {
    float y[16], s; int v=wu&3, st=v>>1, ch=v&1;
    if (wu<4) convE<32,1,16>(AH, st*32, p.bt32h, ch*16, l, y, s);
    else      convE<32,1,16>(AC, st*32, p.bt32c, ch*16, l, y, s);
    PSm[wu*64+l] = s;
    __syncthreads();
    int base = (wu&4) | (st<<1);
    float inv = fastrcp(PSm[base*64+l] + PSm[(base|1)*64+l]);
    if (wu<4) wrTF<1024,16>(TF, st, ch*16, l, y, inv);
    else      wrBC<16>(BC, st*32+ch*16, l, y, inv);
  }
  __syncthreads();

  // ================= B2 =================
  {
    f32x4 acc[2][4];
    int t2 = z>>1, nf = z&1;
    int feat = nf*16 + (l&15);
    binit<4>(acc, p.bb2, 32, feat, 0,1,2,3);
    auto af = [&](int kt, int mt){
      return (kt<2) ? frag(XP + (size_t)(((2*t2+kt)<<2)+mt)*1024 + l*16)
                    : frag(TF + (size_t)((t2<<2)+mt)*1024 + l*16); };
    gemm_reg<4,2,3>(acc, blob + (size_t)OB2*1024, nf, mtp, l, af);
    pw4(acc, AH, AC, BC, t2*32+feat, t2*32+feat, mtp, l);
  }
  __syncthreads();

  // ---- T21: 4 chunks of 16, psum over 4 ----
  {
    float y[16], s;
    if (wu<4) convE<64,1,16>(AH, 0, p.bt21h, wu*16, l, y, s);
    else      convE<64,1,16>(AC, 0, p.bt21c, (wu-4)*16, l, y, s);
    PSm[wu*64+l] = s;
    __syncthreads();
    float tot = (wu<4) ? PSm[0*64+l]+PSm[1*64+l]+PSm[2*64+l]+PSm[3*64+l]
                       : PSm[4*64+l]+PSm[5*64+l]+PSm[6*64+l]+PSm[7*64+l];
    float inv = fastrcp(tot);
    if (wu<4) wrTF<1024,16>(TF, 0, wu*16, l, y, inv);
    else      wrBC<16>(BC, (wu-4)*16, l, y, inv);
  }
  __syncthreads();

  // ================= B1: gates i,f,g -> c only =================
  {
    f32x4 acc[2][3];
    int feat = z*16 + (l&15);
    binit<3>(acc, p.bb1, 64, feat, 0,1,2,0);
    auto af = [&](int kt, int mt){
      return (kt<4) ? frag(XP + (size_t)((kt<<2)+mt)*1024 + l*16)
                    : frag(TF + (size_t)(((kt-4)<<2)+mt)*1024 + l*16); };
    gemm_reg<3,4,6>(acc, blob + (size_t)OB1*1024, z, mtp, l, af);
    #pragma unroll
    for (int mtI=0;mtI<2;++mtI)
      #pragma unroll
      for (int r=0;r<4;++r){
        int batch = (mtp*2+mtI)*16 + ((l>>4)<<2) + r;
        float cb = ldBF(BC, feat, batch);
        float c = sigm(acc[mtI][1][r])*cb + sigm(acc[mtI][0][r])*tanh_(acc[mtI][2][r]);
        p.out[(size_t)(b0+batch)*128 + 64 + feat] = c;
      }
  }
}

extern "C" void kernel_launch(void* const* d_in, const int* in_sizes, int n_in,
                              void* d_out, int out_size, void* d_ws, size_t ws_size,
                              hipStream_t stream) {
  if (ws_size < (size_t)BLOBB) return;
  P p;
  p.spec   = (const float*)d_in[0];
  p.fw_ih1 = (const float*)d_in[1];  p.fw_hh1 = (const float*)d_in[2];  p.fb1 = (const float*)d_in[3];
  p.fw_ih2 = (const float*)d_in[4];  p.fw_hh2 = (const float*)d_in[5];  p.fb2 = (const float*)d_in[6];
  p.fw_ih3 = (const float*)d_in[7];  p.fw_hh3 = (const float*)d_in[8];  p.fb3 = (const float*)d_in[9];
  p.fw_ih4 = (const float*)d_in[10]; p.fw_hh4 = (const float*)d_in[11]; p.fb4 = (const float*)d_in[12];
  p.bw_ih1 = (const float*)d_in[13]; p.bw_hh1 = (const float*)d_in[14]; p.bb1 = (const float*)d_in[15];
  p.bw_ih2 = (const float*)d_in[16]; p.bw_hh2 = (const float*)d_in[17]; p.bb2 = (const float*)d_in[18];
  p.bw_ih3 = (const float*)d_in[19]; p.bw_hh3 = (const float*)d_in[20]; p.bb3 = (const float*)d_in[21];
  p.bw_ih4 = (const float*)d_in[22]; p.bw_hh4 = (const float*)d_in[23]; p.bb4 = (const float*)d_in[24];
  p.ft12h = (const float*)d_in[25]; p.ft12c = (const float*)d_in[26];
  p.ft23h = (const float*)d_in[27]; p.ft23c = (const float*)d_in[28];
  p.ft34h = (const float*)d_in[29];
  p.bt43h = (const float*)d_in[30]; p.bt43c = (const float*)d_in[31];
  p.bt32h = (const float*)d_in[32]; p.bt32c = (const float*)d_in[33];
  p.bt21h = (const float*)d_in[34]; p.bt21c = (const float*)d_in[35];
  p.out = (float*)d_out;

  char* blob = (char*)d_ws;
  hipLaunchKernelGGL(dsgsf_prep, dim3(8), dim3(256), 0, stream, p, blob);
  int Bn = in_sizes[0] / 128;
  hipLaunchKernelGGL(dsgsf_main, dim3(Bn/64), dim3(512), 0, stream, p, (const char*)blob);
}

// Round 4
// 179.074 us; speedup vs baseline: 9.2142x; 1.2069x over previous
//
#include <hip/hip_runtime.h>

typedef __attribute__((ext_vector_type(4))) float f32x4;
typedef __attribute__((ext_vector_type(8))) short short8;

#define DEV __device__ __forceinline__

DEV float fastrcp(float x){ return __builtin_amdgcn_rcpf(x); }
DEV float sigm(float x){ return fastrcp(1.f + __expf(-x)); }
DEV float tanh_(float x){ return 1.f - 2.f*fastrcp(__expf(2.f*x)+1.f); }
DEV unsigned short f2bf(float f){ unsigned u=__float_as_uint(f); u += 0x7fffu + ((u>>16)&1u); return (unsigned short)(u>>16); }
DEV float bf2f(unsigned short h){ return __uint_as_float(((unsigned)h)<<16); }
DEV unsigned pack2(float a, float b){ return (unsigned)f2bf(a) | ((unsigned)f2bf(b)<<16); }

// bank swizzle for [feat][64batch] bf16 arrays (2-way-free on all hot patterns)
DEV int gmask(int f){ return ((f&1)<<5) | (f&2) | ((f&4)<<2); }
DEV void stBF(char* A, int f, int b, float v){ *(unsigned short*)(A + (((f<<6) + (b ^ gmask(f)))<<1)) = f2bf(v); }
DEV float ldBF(const char* A, int f, int b){ return bf2f(*(const unsigned short*)(A + (((f<<6) + (b ^ gmask(f)))<<1))); }

DEV short8 frag(const char* p){ return *(const short8*)p; }
DEV short8 gfrag(const char* p){ return *(const short8*)p; }   // global B-frag -> VGPR (L2-hit)
DEV f32x4 MF(short8 a, short8 b, f32x4 c){ return __builtin_amdgcn_mfma_f32_16x16x32_bf16(a,b,c,0,0,0); }

struct P {
  const float *spec;
  const float *fw_ih1,*fw_hh1,*fb1,*fw_ih2,*fw_hh2,*fb2,*fw_ih3,*fw_hh3,*fb3,*fw_ih4,*fw_hh4,*fb4;
  const float *bw_ih1,*bw_hh1,*bb1,*bw_ih2,*bw_hh2,*bb2,*bw_ih3,*bw_hh3,*bb3,*bw_ih4,*bw_hh4,*bb4;
  const float *ft12h,*ft12c,*ft23h,*ft23c,*ft34h,*bt43h,*bt43c,*bt32h,*bt32c,*bt21h,*bt21c;
  float *out;
};

// blob offsets in KB; slot = 1KB = one 16(row)x32(k) bf16 B-fragment
#define OF1 0
#define OF2 48
#define OF3 72
#define OF4 80
#define OB4 86
#define OB3 90
#define OB2 98
#define OB1 122
#define BLOBB (194*1024)

// ---------------- prep: pack weights into bf16 B-fragments -----------------
__global__ __launch_bounds__(256) void dsgsf_prep(P p, char* blob){
  int s = blockIdx.x;
  if (s == 3 || s == 4){            // F4 / B4: parity-packed (full 32-k spec chunks)
    bool isF = (s == 3);
    const float* wih = isF ? p.fw_ih4 : p.bw_ih4;
    const float* whh = p.fw_hh4;
    int nslot = isF ? 6 : 4;
    int off   = isF ? OF4 : OB4;
    for (int n = threadIdx.x; n < nslot*64; n += 256){
      int st = n>>6, lx = n&63;
      int R = lx&15, half = R>>3, feat = R&7;
      int k0 = ((lx>>4)<<3);
      unsigned dw[4];
      #pragma unroll
      for (int q=0;q<4;++q){
        float a=0.f, bv=0.f;
        int ka=k0+2*q, kb=ka+1;
        if (isF){
          if (st < 4){
            int pp = st>>1, t = st&1;
            int gi = t*2 + half;                 // t0:[i,f] t1:[g,o]
            int src = gi*8 + feat, base = pp*16;
            if (ka>=base && ka<base+16) a  = wih[src*16 + (ka-base)];
            if (kb>=base && kb<base+16) bv = wih[src*16 + (kb-base)];
          } else {
            int t = st-4; int gi = t*2 + half; int src = gi*8 + feat;
            if (ka<8) a  = whh[src*8+ka];
            if (kb<8) bv = whh[src*8+kb];
          }
        } else {
          int pp = st>>1, t = st&1;
          int gi = (t==0) ? (half? 2:0) : (half? -1:3);   // t0:[i,g] t1:[o,pad]
          if (gi >= 0){
            int src = gi*8 + feat, base = pp*16;
            if (ka>=base && ka<base+16) a  = wih[src*16 + (ka-base)];
            if (kb>=base && kb<base+16) bv = wih[src*16 + (kb-base)];
          }
        }
        dw[q] = pack2(a,bv);
      }
      *(uint4*)(blob + (size_t)(off+st)*1024 + lx*16) = make_uint4(dw[0],dw[1],dw[2],dw[3]);
    }
    return;
  }
  const float* wih=nullptr; const float* whh=nullptr;
  int H=0,NG=0,Kx=0,KXT=0,Kh=0,KT=0,NT=0,off=0,o0=0,o1=1,o2=2,o3=3;
  switch(s){
    case 0: wih=p.fw_ih1;               H=64;NG=3;Kx=128;KXT=4;Kh=0; KT=4;NT=12;off=OF1;o1=2;o2=3; break;
    case 1: wih=p.fw_ih2; whh=p.fw_hh2; H=32;NG=4;Kx=64; KXT=2;Kh=32;KT=3;NT=8; off=OF2; break;
    case 2: wih=p.fw_ih3; whh=p.fw_hh3; H=16;NG=4;Kx=32; KXT=1;Kh=16;KT=2;NT=4; off=OF3; break;
    case 5: wih=p.bw_ih3; whh=p.bw_hh3; H=16;NG=4;Kx=32; KXT=1;Kh=16;KT=2;NT=4; off=OB3; break;
    case 6: wih=p.bw_ih2; whh=p.bw_hh2; H=32;NG=4;Kx=64; KXT=2;Kh=32;KT=3;NT=8; off=OB2; break;
    default:wih=p.bw_ih1; whh=p.bw_hh1; H=64;NG=3;Kx=128;KXT=4;Kh=64;KT=6;NT=12;off=OB1; break;
  }
  int total = KT*NT*64;
  for (int n = threadIdx.x; n < total; n += 256){
    int kt = n/(NT*64); int rem = n - kt*NT*64; int nt = rem>>6; int lx = rem&63;
    int R = nt*16 + (lx&15);
    int gi = R / H; int feat = R - gi*H;
    int og = (gi==0)? o0 : (gi==1)? o1 : (gi==2)? o2 : o3;
    int src = og*H + feat;
    int k0 = kt*32 + ((lx>>4)<<3);
    unsigned dw[4];
    #pragma unroll
    for (int q=0;q<4;++q){
      float a=0.f, b=0.f;
      int ka=k0+2*q, kb=ka+1;
      if (gi < NG){
        if (ka < Kx) a = wih[(size_t)src*Kx + ka];
        else { int kh = ka - KXT*32; if (kh>=0 && kh<Kh) a = whh[(size_t)src*Kh + kh]; }
        if (kb < Kx) b = wih[(size_t)src*Kx + kb];
        else { int kh = kb - KXT*32; if (kh>=0 && kh<Kh) b = whh[(size_t)src*Kh + kh]; }
      }
      dw[q] = pack2(a,b);
    }
    *(uint4*)(blob + (size_t)off*1024 + (size_t)(kt*NT + nt)*1024 + lx*16) =
        make_uint4(dw[0],dw[1],dw[2],dw[3]);
  }
}

// ---------------- GEMM: B-fragments direct global->VGPR, no barriers ----------
template<int NG,int NFT,int KT, class AF>
DEV void gemm_reg(f32x4 (&acc)[2][NG], const char* bstage, int nf, int mtp, int l, AF af){
  constexpr int NT = NG*NFT;
  #pragma unroll
  for (int kt=0; kt<KT; ++kt){
    short8 a0 = af(kt, mtp*2);
    short8 a1 = af(kt, mtp*2+1);
    #pragma unroll
    for (int g=0; g<NG; ++g){
      short8 bf = gfrag(bstage + (size_t)(kt*NT + g*NFT + nf)*1024 + l*16);
      acc[0][g] = MF(a0, bf, acc[0][g]);
      acc[1][g] = MF(a1, bf, acc[1][g]);
    }
  }
}

template<int NG>
DEV void binit(f32x4 (&acc)[2][NG], const float* bias, int H, int feat,
               int o0, int o1, int o2, int o3){
  int og[4] = {o0,o1,o2,o3};
  #pragma unroll
  for (int g=0; g<NG; ++g){
    float bv = bias[og[g]*H + feat];
    f32x4 v = {bv,bv,bv,bv};
    acc[0][g]=v; acc[1][g]=v;
  }
}

DEV void pw4(const f32x4 (&acc)[2][4], char* AH, char* AC, const char* BC,
             int arow, int cbrow, int mtp, int l){
  #pragma unroll
  for (int mtI=0;mtI<2;++mtI){
    #pragma unroll
    for (int r=0;r<4;++r){
      int batch = (mtp*2+mtI)*16 + ((l>>4)<<2) + r;
      float cb = ldBF(BC, cbrow, batch);
      float c = sigm(acc[mtI][1][r])*cb + sigm(acc[mtI][0][r])*tanh_(acc[mtI][2][r]);
      float h = sigm(acc[mtI][3][r])*tanh_(c);
      stBF(AH, arow, batch, h);
      stBF(AC, arow, batch, c);
    }
  }
}

// ---- trans: conv(k3,pad1,stride S)+exp for NO outputs, kept in registers ----
template<int L,int S,int NO>
DEV void convE(const char* Ain, int row0, const float* tw, int o0, int b,
               float (&y)[NO], float& s){
  float w0=tw[0], w1=tw[1], w2=tw[2];
  s = 0.f;
  #pragma unroll
  for (int j=0;j<NO;++j){
    int o=o0+j, c=S*o;
    float v = w1*ldBF(Ain,row0+c,b);
    if (c>=1)   v += w0*ldBF(Ain,row0+c-1,b);
    if (c+1<L)  v += w2*ldBF(Ain,row0+c+1,b);
    y[j] = __expf(v); s += y[j];
  }
}
// normalized write, A-fragment layout (one 16B store per 8 outputs)
template<int SZ,int NO>
DEV void wrTF(char* TFb, int subBase, int o0, int b, const float (&y)[NO], float inv){
  #pragma unroll
  for (int g8=0; g8<NO/8; ++g8){
    int oo = o0 + g8*8, fl = oo&31;
    char* base = TFb + (size_t)((subBase+(oo>>5))*4+(b>>4))*SZ + ((b&15)+16*(fl>>3))*16;
    unsigned d0=pack2(y[g8*8+0]*inv,y[g8*8+1]*inv), d1=pack2(y[g8*8+2]*inv,y[g8*8+3]*inv);
    unsigned d2=pack2(y[g8*8+4]*inv,y[g8*8+5]*inv), d3=pack2(y[g8*8+6]*inv,y[g8*8+7]*inv);
    *(uint4*)base = make_uint4(d0,d1,d2,d3);
  }
}
template<int NO>
DEV void wrBC(char* BCb, int row0, int b, const float (&y)[NO], float inv){
  #pragma unroll
  for (int j=0;j<NO;++j) stBF(BCb, row0+j, b, y[j]*inv);
}

// ---------------- main kernel -----------------
// launch_bounds(512,4): VGPR cap 128. (512,6) capped at ~85 and the allocator
// landed at 40 VGPR -> ~400MB scratch spill traffic (R3: WRITE 334MB). The
// gemm_reg + y[16] + acc register demand is ~90-100; 4 waves/EU fits, no spill.
__global__ __launch_bounds__(512, 4) void dsgsf_main(P p, const char* blob){
  __shared__ __align__(16) char SM[51200];
  char* XP = SM;               // 16KB: spec A-frags [kc*4+mt]
  char* AH = SM + 16384;       //  8KB: h state [feat][batch] bf16 swizzled
  char* AC = SM + 24576;       //  8KB: c state
  char* BC = SM + 32768;       //  8KB: trans-c outputs
  char* TF = SM + 40960;       //  8KB: trans-h outputs as A-frags
  float* PSm = (float*)(SM + 49152);  // 2KB: softmax partial sums [task][batch]

  const int tid = threadIdx.x;
  const int l   = tid & 63;
  const int wu  = __builtin_amdgcn_readfirstlane(tid >> 6);
  const int mtp = wu & 1, z = wu >> 1;
  const long b0 = (long)blockIdx.x * 64;

  // ---- stage spec into A-fragment layout ----
  #pragma unroll
  for (int it=0; it<2; ++it){
    int n = it*512 + tid; int slot = n>>6, lx = n&63;
    int kc = slot>>2, mt = slot&3;
    const float* sp = p.spec + (b0 + mt*16 + (lx&15))*128 + kc*32 + ((lx>>4)<<3);
    float4 v0 = *(const float4*)sp; float4 v1 = *(const float4*)(sp+4);
    unsigned* dst = (unsigned*)(XP + (size_t)slot*1024 + lx*16);
    dst[0]=pack2(v0.x,v0.y); dst[1]=pack2(v0.z,v0.w);
    dst[2]=pack2(v1.x,v1.y); dst[3]=pack2(v1.z,v1.w);
  }
  __syncthreads();

  // ================= F1: lstm0(spec), gates i,g,o =================
  {
    f32x4 acc[2][3];
    int feat = z*16 + (l&15);
    binit<3>(acc, p.fb1, 64, feat, 0,2,3,0);
    auto af = [&](int kt, int mt){ return frag(XP + (size_t)((kt<<2)+mt)*1024 + l*16); };
    gemm_reg<3,4,4>(acc, blob + (size_t)OF1*1024, z, mtp, l, af);
    #pragma unroll
    for (int mtI=0;mtI<2;++mtI)
      #pragma unroll
      for (int r=0;r<4;++r){
        int batch = (mtp*2+mtI)*16 + ((l>>4)<<2) + r;
        float c = sigm(acc[mtI][0][r])*tanh_(acc[mtI][1][r]);
        float h = sigm(acc[mtI][2][r])*tanh_(c);
        stBF(AH, feat, batch, h); stBF(AC, feat, batch, c);
      }
  }
  __syncthreads();

  // ---- T12: chunks of 8, psum over 4 ----
  {
    float y[8], s;
    if (wu<4) convE<64,2,8>(AH, 0, p.ft12h, wu*8, l, y, s);
    else      convE<64,2,8>(AC, 0, p.ft12c, (wu-4)*8, l, y, s);
    PSm[wu*64+l] = s;
    __syncthreads();
    float tot = (wu<4) ? PSm[0*64+l]+PSm[1*64+l]+PSm[2*64+l]+PSm[3*64+l]
                       : PSm[4*64+l]+PSm[5*64+l]+PSm[6*64+l]+PSm[7*64+l];
    float inv = fastrcp(tot);
    if (wu<4) wrTF<1024,8>(TF, 0, wu*8, l, y, inv);
    else      wrBC<8>(BC, (wu-4)*8, l, y, inv);
  }
  __syncthreads();

  // ================= F2 =================
  {
    f32x4 acc[2][4];
    int step = z>>1, nf = z&1;
    int feat = nf*16 + (l&15);
    binit<4>(acc, p.fb2, 32, feat, 0,1,2,3);
    auto af = [&](int kt, int mt){
      return (kt<2) ? frag(XP + (size_t)(((2*step+kt)<<2)+mt)*1024 + l*16)
                    : frag(TF + (size_t)mt*1024 + l*16); };
    gemm_reg<4,2,3>(acc, blob + (size_t)OF2*1024, nf, mtp, l, af);
    pw4(acc, AH, AC, BC, step*32+feat, feat, mtp, l);
  }
  __syncthreads();

  // ---- T23: 2 steps x 2 chunks of 8, psum pairs ----
  {
    float y[8], s; int v=wu&3, st=v>>1, ch=v&1;
    if (wu<4) convE<32,2,8>(AH, st*32, p.ft23h, ch*8, l, y, s);
    else      convE<32,2,8>(AC, st*32, p.ft23c, ch*8, l, y, s);
    PSm[wu*64+l] = s;
    __syncthreads();
    int base = (wu&4) | (st<<1);
    float inv = fastrcp(PSm[base*64+l] + PSm[(base|1)*64+l]);
    if (wu<4) wrTF<512,8>(TF, st, ch*8, l, y, inv);
    else      wrBC<8>(BC, st*16+ch*8, l, y, inv);
  }
  __syncthreads();

  // ================= F3 =================
  {
    f32x4 acc[2][4];
    int s = z, feat = l&15;
    binit<4>(acc, p.fb3, 16, feat, 0,1,2,3);
    auto af = [&](int kt, int mt){
      return (kt==0) ? frag(XP + (size_t)((s<<2)+mt)*1024 + l*16)
                     : frag(TF + (size_t)(((s>>1)<<2)+mt)*512 + (l&31)*16); };
    gemm_reg<4,1,2>(acc, blob + (size_t)OF3*1024, 0, mtp, l, af);
    pw4(acc, AH, AC, BC, s*16+feat, (s>>1)*16+feat, mtp, l);
  }
  __syncthreads();

  // ---- T34: 8 independent rows of 8, local sums ----
  {
    float y[8], s;
    if (wu<4){ convE<16,2,8>(AH, wu*16, p.ft34h, 0, l, y, s);
               wrTF<256,8>(TF, wu, 0, l, y, fastrcp(s)); }
    else     { convE<16,2,8>(AC, (wu-4)*16, p.ft34h, 0, l, y, s);   // ref bug: ft34h for c
               wrBC<8>(BC, (wu-4)*8, l, y, fastrcp(s)); }
  }
  __syncthreads();

  // ================= F4 (parity-packed) =================
  {
    f32x4 a4[2][2][2]; // [parity uu][mtI][tile]
    float bv0 = p.fb4[l&15], bv1 = p.fb4[16+(l&15)];
    #pragma unroll
    for (int uu=0;uu<2;++uu)
      #pragma unroll
      for (int mtI=0;mtI<2;++mtI){ a4[uu][mtI][0]=f32x4{bv0,bv0,bv0,bv0}; a4[uu][mtI][1]=f32x4{bv1,bv1,bv1,bv1}; }
    const char* bs = blob + (size_t)OF4*1024;
    short8 A0 = frag(XP + (size_t)((z<<2)+mtp*2  )*1024 + l*16);
    short8 A1 = frag(XP + (size_t)((z<<2)+mtp*2+1)*1024 + l*16);
    short8 H0 = frag(TF + (size_t)((z<<2)+mtp*2  )*256 + (l&15)*16);
    short8 H1 = frag(TF + (size_t)((z<<2)+mtp*2+1)*256 + (l&15)*16);
    short8 bh0 = gfrag(bs + 4*1024 + l*16);
    short8 bh1 = gfrag(bs + 5*1024 + l*16);
    #pragma unroll
    for (int uu=0;uu<2;++uu){
      short8 bx0 = gfrag(bs + (uu*2+0)*1024 + l*16);
      short8 bx1 = gfrag(bs + (uu*2+1)*1024 + l*16);
      a4[uu][0][0]=MF(A0,bx0,a4[uu][0][0]); a4[uu][0][1]=MF(A0,bx1,a4[uu][0][1]);
      a4[uu][1][0]=MF(A1,bx0,a4[uu][1][0]); a4[uu][1][1]=MF(A1,bx1,a4[uu][1][1]);
      a4[uu][0][0]=MF(H0,bh0,a4[uu][0][0]); a4[uu][0][1]=MF(H0,bh1,a4[uu][0][1]);
      a4[uu][1][0]=MF(H1,bh0,a4[uu][1][0]); a4[uu][1][1]=MF(H1,bh1,a4[uu][1][1]);
    }
    #pragma unroll
    for (int uu=0;uu<2;++uu)
      #pragma unroll
      for (int mtI=0;mtI<2;++mtI)
        #pragma unroll
        for (int r=0;r<4;++r){
          float iv = a4[uu][mtI][0][r], gv = a4[uu][mtI][1][r];
          float xf = __shfl_xor(iv,8), xo = __shfl_xor(gv,8);
          if ((l&15)<8){
            int q = l&15, u = z*2+uu;
            int batch = (mtp*2+mtI)*16 + ((l>>4)<<2) + r;
            float cb = ldBF(BC, (u>>1)*8+q, batch);
            float c = sigm(xf)*cb + sigm(iv)*tanh_(gv);
            float h = sigm(xo)*tanh_(c);
            p.out[(size_t)(b0+batch)*128 + u*8 + q] = h;
          }
        }
  }

  // ================= B4 (parity-packed lstm0) =================
  {
    f32x4 a4[2][2][2];
    float bv0 = ((l&15)<8) ? p.bb4[l&15] : p.bb4[(l&15)+8];   // i | g
    float bv1 = ((l&15)<8) ? p.bb4[24+(l&15)] : 0.f;          // o | pad
    #pragma unroll
    for (int uu=0;uu<2;++uu)
      #pragma unroll
      for (int mtI=0;mtI<2;++mtI){ a4[uu][mtI][0]=f32x4{bv0,bv0,bv0,bv0}; a4[uu][mtI][1]=f32x4{bv1,bv1,bv1,bv1}; }
    const char* bs = blob + (size_t)OB4*1024;
    short8 A0 = frag(XP + (size_t)((z<<2)+mtp*2  )*1024 + l*16);
    short8 A1 = frag(XP + (size_t)((z<<2)+mtp*2+1)*1024 + l*16);
    #pragma unroll
    for (int uu=0;uu<2;++uu){
      short8 bx0 = gfrag(bs + (uu*2+0)*1024 + l*16);
      short8 bx1 = gfrag(bs + (uu*2+1)*1024 + l*16);
      a4[uu][0][0]=MF(A0,bx0,a4[uu][0][0]); a4[uu][0][1]=MF(A0,bx1,a4[uu][0][1]);
      a4[uu][1][0]=MF(A1,bx0,a4[uu][1][0]); a4[uu][1][1]=MF(A1,bx1,a4[uu][1][1]);
    }
    #pragma unroll
    for (int uu=0;uu<2;++uu)
      #pragma unroll
      for (int mtI=0;mtI<2;++mtI)
        #pragma unroll
        for (int r=0;r<4;++r){
          float iv = a4[uu][mtI][0][r], ov = a4[uu][mtI][1][r];
          float gv = __shfl_xor(iv,8);
          if ((l&15)<8){
            int q = l&15, u = z*2+uu;
            int batch = (mtp*2+mtI)*16 + ((l>>4)<<2) + r;
            float c = sigm(iv)*tanh_(gv);
            float h = sigm(ov)*tanh_(c);
            stBF(AH, u*8+q, batch, h); stBF(AC, u*8+q, batch, c);
          }
        }
  }
  __syncthreads();

  // ---- T43: 8 independent rows of 16, local sums ----
  {
    float y[16], s;
    if (wu<4){ convE<16,1,16>(AH, wu*16, p.bt43h, 0, l, y, s);
               wrTF<512,16>(TF, wu, 0, l, y, fastrcp(s)); }
    else     { convE<16,1,16>(AC, (wu-4)*16, p.bt43c, 0, l, y, s);
               wrBC<16>(BC, (wu-4)*16, l, y, fastrcp(s)); }
  }
  __syncthreads();

  // ================= B3 =================
  {
    f32x4 acc[2][4];
    int s = z, feat = l&15;
    binit<4>(acc, p.bb3, 16, feat, 0,1,2,3);
    auto af = [&](int kt, int mt){
      return (kt==0) ? frag(XP + (size_t)((s<<2)+mt)*1024 + l*16)
                     : frag(TF + (size_t)((s<<2)+mt)*512 + (l&31)*16); };
    gemm_reg<4,1,2>(acc, blob + (size_t)OB3*1024, 0, mtp, l, af);
    pw4(acc, AH, AC, BC, s*16+feat, s*16+feat, mtp, l);
  }
  __syncthreads();

  // ---- T32: 2 steps x 2 chunks of 16, psum pairs ----
  {
    float y[16], s; int v=wu&3, st=v>>1, ch=v&1;
    if (wu<4) convE<32,1,16>(AH, st*32, p.bt32h, ch*16, l, y, s);
    else      convE<32,1,16>(AC, st*32, p.bt32c, ch*16, l, y, s);
    PSm[wu*64+l] = s;
    __syncthreads();
    int base = (wu&4) | (st<<1);
    float inv = fastrcp(PSm[base*64+l] + PSm[(base|1)*64+l]);
    if (wu<4) wrTF<1024,16>(TF, st, ch*16, l, y, inv);
    else      wrBC<16>(BC, st*32+ch*16, l, y, inv);
  }
  __syncthreads();

  // ================= B2 =================
  {
    f32x4 acc[2][4];
    int t2 = z>>1, nf = z&1;
    int feat = nf*16 + (l&15);
    binit<4>(acc, p.bb2, 32, feat, 0,1,2,3);
    auto af = [&](int kt, int mt){
      return (kt<2) ? frag(XP + (size_t)(((2*t2+kt)<<2)+mt)*1024 + l*16)
                    : frag(TF + (size_t)((t2<<2)+mt)*1024 + l*16); };
    gemm_reg<4,2,3>(acc, blob + (size_t)OB2*1024, nf, mtp, l, af);
    pw4(acc, AH, AC, BC, t2*32+feat, t2*32+feat, mtp, l);
  }
  __syncthreads();

  // ---- T21: 4 chunks of 16, psum over 4 ----
  {
    float y[16], s;
    if (wu<4) convE<64,1,16>(AH, 0, p.bt21h, wu*16, l, y, s);
    else      convE<64,1,16>(AC, 0, p.bt21c, (wu-4)*16, l, y, s);
    PSm[wu*64+l] = s;
    __syncthreads();
    float tot = (wu<4) ? PSm[0*64+l]+PSm[1*64+l]+PSm[2*64+l]+PSm[3*64+l]
                       : PSm[4*64+l]+PSm[5*64+l]+PSm[6*64+l]+PSm[7*64+l];
    float inv = fastrcp(tot);
    if (wu<4) wrTF<1024,16>(TF, 0, wu*16, l, y, inv);
    else      wrBC<16>(BC, (wu-4)*16, l, y, inv);
  }
  __syncthreads();

  // ================= B1: gates i,f,g -> c only =================
  {
    f32x4 acc[2][3];
    int feat = z*16 + (l&15);
    binit<3>(acc, p.bb1, 64, feat, 0,1,2,0);
    auto af = [&](int kt, int mt){
      return (kt<4) ? frag(XP + (size_t)((kt<<2)+mt)*1024 + l*16)
                    : frag(TF + (size_t)(((kt-4)<<2)+mt)*1024 + l*16); };
    gemm_reg<3,4,6>(acc, blob + (size_t)OB1*1024, z, mtp, l, af);
    #pragma unroll
    for (int mtI=0;mtI<2;++mtI)
      #pragma unroll
      for (int r=0;r<4;++r){
        int batch = (mtp*2+mtI)*16 + ((l>>4)<<2) + r;
        float cb = ldBF(BC, feat, batch);
        float c = sigm(acc[mtI][1][r])*cb + sigm(acc[mtI][0][r])*tanh_(acc[mtI][2][r]);
        p.out[(size_t)(b0+batch)*128 + 64 + feat] = c;
      }
  }
}

extern "C" void kernel_launch(void* const* d_in, const int* in_sizes, int n_in,
                              void* d_out, int out_size, void* d_ws, size_t ws_size,
                              hipStream_t stream) {
  if (ws_size < (size_t)BLOBB) return;
  P p;
  p.spec   = (const float*)d_in[0];
  p.fw_ih1 = (const float*)d_in[1];  p.fw_hh1 = (const float*)d_in[2];  p.fb1 = (const float*)d_in[3];
  p.fw_ih2 = (const float*)d_in[4];  p.fw_hh2 = (const float*)d_in[5];  p.fb2 = (const float*)d_in[6];
  p.fw_ih3 = (const float*)d_in[7];  p.fw_hh3 = (const float*)d_in[8];  p.fb3 = (const float*)d_in[9];
  p.fw_ih4 = (const float*)d_in[10]; p.fw_hh4 = (const float*)d_in[11]; p.fb4 = (const float*)d_in[12];
  p.bw_ih1 = (const float*)d_in[13]; p.bw_hh1 = (const float*)d_in[14]; p.bb1 = (const float*)d_in[15];
  p.bw_ih2 = (const float*)d_in[16]; p.bw_hh2 = (const float*)d_in[17]; p.bb2 = (const float*)d_in[18];
  p.bw_ih3 = (const float*)d_in[19]; p.bw_hh3 = (const float*)d_in[20]; p.bb3 = (const float*)d_in[21];
  p.bw_ih4 = (const float*)d_in[22]; p.bw_hh4 = (const float*)d_in[23]; p.bb4 = (const float*)d_in[24];
  p.ft12h = (const float*)d_in[25]; p.ft12c = (const float*)d_in[26];
  p.ft23h = (const float*)d_in[27]; p.ft23c = (const float*)d_in[28];
  p.ft34h = (const float*)d_in[29];
  p.bt43h = (const float*)d_in[30]; p.bt43c = (const float*)d_in[31];
  p.bt32h = (const float*)d_in[32]; p.bt32c = (const float*)d_in[33];
  p.bt21h = (const float*)d_in[34]; p.bt21c = (const float*)d_in[35];
  p.out = (float*)d_out;

  char* blob = (char*)d_ws;
  hipLaunchKernelGGL(dsgsf_prep, dim3(8), dim3(256), 0, stream, p, blob);
  int Bn = in_sizes[0] / 128;
  hipLaunchKernelGGL(dsgsf_main, dim3(Bn/64), dim3(512), 0, stream, p, (const char*)blob);
}

// Round 5
// 162.864 us; speedup vs baseline: 10.1313x; 1.0995x over previous
//
#include <hip/hip_runtime.h>

typedef __attribute__((ext_vector_type(4))) float f32x4;
typedef __attribute__((ext_vector_type(8))) short short8;

#define DEV __device__ __forceinline__

DEV float fastrcp(float x){ return __builtin_amdgcn_rcpf(x); }
DEV float exp2r(float x){ return __builtin_amdgcn_exp2f(x); }
DEV float sigm(float x){ return fastrcp(1.f + exp2r(x*-1.44269504f)); }
DEV float tanh_(float x){ return 1.f - 2.f*fastrcp(exp2r(x*2.88539008f)+1.f); }

// one-instruction bf16 packing (RNE, matches hand-rolled f2bf)
DEV unsigned cvtpk(float lo, float hi){ unsigned r; asm("v_cvt_pk_bf16_f32 %0, %1, %2" : "=v"(r) : "v"(lo), "v"(hi)); return r; }
DEV unsigned short f2bf(float f){ return (unsigned short)cvtpk(f,f); }
DEV float bf2f(unsigned short h){ return __uint_as_float(((unsigned)h)<<16); }
DEV unsigned pack2(float a, float b){ return cvtpk(a,b); }

// bank swizzle for [feat][64batch] bf16 arrays (2-way-free on all hot patterns)
DEV int gmask(int f){ return ((f&1)<<5) | (f&2) | ((f&4)<<2); }
DEV void stBF(char* A, int f, int b, float v){ *(unsigned short*)(A + (((f<<6) + (b ^ gmask(f)))<<1)) = f2bf(v); }
// paired store: batches b (even) and b+1 — adjacent under swizzle (gmask has no bit0)
DEV void stBFpair(char* A, int f, int b, float v0, float v1){
  *(unsigned*)(A + (((f<<6) + (b ^ gmask(f)))<<1)) = cvtpk(v0, v1);
}
DEV float ldBF(const char* A, int f, int b){ return bf2f(*(const unsigned short*)(A + (((f<<6) + (b ^ gmask(f)))<<1))); }

DEV short8 frag(const char* p){ return *(const short8*)p; }
DEV short8 gfrag(const char* p){ return *(const short8*)p; }   // global B-frag -> VGPR (L2-hit)
DEV f32x4 MF(short8 a, short8 b, f32x4 c){ return __builtin_amdgcn_mfma_f32_16x16x32_bf16(a,b,c,0,0,0); }

struct P {
  const float *spec;
  const float *fw_ih1,*fw_hh1,*fb1,*fw_ih2,*fw_hh2,*fb2,*fw_ih3,*fw_hh3,*fb3,*fw_ih4,*fw_hh4,*fb4;
  const float *bw_ih1,*bw_hh1,*bb1,*bw_ih2,*bw_hh2,*bb2,*bw_ih3,*bw_hh3,*bb3,*bw_ih4,*bw_hh4,*bb4;
  const float *ft12h,*ft12c,*ft23h,*ft23c,*ft34h,*bt43h,*bt43c,*bt32h,*bt32c,*bt21h,*bt21c;
  float *out;
};

// blob offsets in KB; slot = 1KB = one 16(row)x32(k) bf16 B-fragment
#define OF1 0
#define OF2 48
#define OF3 72
#define OF4 80
#define OB4 86
#define OB3 90
#define OB2 98
#define OB1 122
#define BLOBB (194*1024)

// ---------------- prep: pack weights into bf16 B-fragments -----------------
__global__ __launch_bounds__(256) void dsgsf_prep(P p, char* blob){
  int s = blockIdx.x;
  if (s == 3 || s == 4){            // F4 / B4: parity-packed (full 32-k spec chunks)
    bool isF = (s == 3);
    const float* wih = isF ? p.fw_ih4 : p.bw_ih4;
    const float* whh = p.fw_hh4;
    int nslot = isF ? 6 : 4;
    int off   = isF ? OF4 : OB4;
    for (int n = threadIdx.x; n < nslot*64; n += 256){
      int st = n>>6, lx = n&63;
      int R = lx&15, half = R>>3, feat = R&7;
      int k0 = ((lx>>4)<<3);
      unsigned dw[4];
      #pragma unroll
      for (int q=0;q<4;++q){
        float a=0.f, bv=0.f;
        int ka=k0+2*q, kb=ka+1;
        if (isF){
          if (st < 4){
            int pp = st>>1, t = st&1;
            int gi = t*2 + half;                 // t0:[i,f] t1:[g,o]
            int src = gi*8 + feat, base = pp*16;
            if (ka>=base && ka<base+16) a  = wih[src*16 + (ka-base)];
            if (kb>=base && kb<base+16) bv = wih[src*16 + (kb-base)];
          } else {
            int t = st-4; int gi = t*2 + half; int src = gi*8 + feat;
            if (ka<8) a  = whh[src*8+ka];
            if (kb<8) bv = whh[src*8+kb];
          }
        } else {
          int pp = st>>1, t = st&1;
          int gi = (t==0) ? (half? 2:0) : (half? -1:3);   // t0:[i,g] t1:[o,pad]
          if (gi >= 0){
            int src = gi*8 + feat, base = pp*16;
            if (ka>=base && ka<base+16) a  = wih[src*16 + (ka-base)];
            if (kb>=base && kb<base+16) bv = wih[src*16 + (kb-base)];
          }
        }
        dw[q] = pack2(a,bv);
      }
      *(uint4*)(blob + (size_t)(off+st)*1024 + lx*16) = make_uint4(dw[0],dw[1],dw[2],dw[3]);
    }
    return;
  }
  const float* wih=nullptr; const float* whh=nullptr;
  int H=0,NG=0,Kx=0,KXT=0,Kh=0,KT=0,NT=0,off=0,o0=0,o1=1,o2=2,o3=3;
  switch(s){
    case 0: wih=p.fw_ih1;               H=64;NG=3;Kx=128;KXT=4;Kh=0; KT=4;NT=12;off=OF1;o1=2;o2=3; break;
    case 1: wih=p.fw_ih2; whh=p.fw_hh2; H=32;NG=4;Kx=64; KXT=2;Kh=32;KT=3;NT=8; off=OF2; break;
    case 2: wih=p.fw_ih3; whh=p.fw_hh3; H=16;NG=4;Kx=32; KXT=1;Kh=16;KT=2;NT=4; off=OF3; break;
    case 5: wih=p.bw_ih3; whh=p.bw_hh3; H=16;NG=4;Kx=32; KXT=1;Kh=16;KT=2;NT=4; off=OB3; break;
    case 6: wih=p.bw_ih2; whh=p.bw_hh2; H=32;NG=4;Kx=64; KXT=2;Kh=32;KT=3;NT=8; off=OB2; break;
    default:wih=p.bw_ih1; whh=p.bw_hh1; H=64;NG=3;Kx=128;KXT=4;Kh=64;KT=6;NT=12;off=OB1; break;
  }
  int total = KT*NT*64;
  for (int n = threadIdx.x; n < total; n += 256){
    int kt = n/(NT*64); int rem = n - kt*NT*64; int nt = rem>>6; int lx = rem&63;
    int R = nt*16 + (lx&15);
    int gi = R / H; int feat = R - gi*H;
    int og = (gi==0)? o0 : (gi==1)? o1 : (gi==2)? o2 : o3;
    int src = og*H + feat;
    int k0 = kt*32 + ((lx>>4)<<3);
    unsigned dw[4];
    #pragma unroll
    for (int q=0;q<4;++q){
      float a=0.f, b=0.f;
      int ka=k0+2*q, kb=ka+1;
      if (gi < NG){
        if (ka < Kx) a = wih[(size_t)src*Kx + ka];
        else { int kh = ka - KXT*32; if (kh>=0 && kh<Kh) a = whh[(size_t)src*Kh + kh]; }
        if (kb < Kx) b = wih[(size_t)src*Kx + kb];
        else { int kh = kb - KXT*32; if (kh>=0 && kh<Kh) b = whh[(size_t)src*Kh + kh]; }
      }
      dw[q] = pack2(a,b);
    }
    *(uint4*)(blob + (size_t)off*1024 + (size_t)(kt*NT + nt)*1024 + lx*16) =
        make_uint4(dw[0],dw[1],dw[2],dw[3]);
  }
}

// ---------------- GEMM: B-fragments direct global->VGPR, no barriers ----------
template<int NG,int NFT,int KT, class AF>
DEV void gemm_reg(f32x4 (&acc)[2][NG], const char* bstage, int nf, int mtp, int l, AF af){
  constexpr int NT = NG*NFT;
  #pragma unroll
  for (int kt=0; kt<KT; ++kt){
    short8 a0 = af(kt, mtp*2);
    short8 a1 = af(kt, mtp*2+1);
    #pragma unroll
    for (int g=0; g<NG; ++g){
      short8 bf = gfrag(bstage + (size_t)(kt*NT + g*NFT + nf)*1024 + l*16);
      acc[0][g] = MF(a0, bf, acc[0][g]);
      acc[1][g] = MF(a1, bf, acc[1][g]);
    }
  }
}

template<int NG>
DEV void binit(f32x4 (&acc)[2][NG], const float* bias, int H, int feat,
               int o0, int o1, int o2, int o3){
  int og[4] = {o0,o1,o2,o3};
  #pragma unroll
  for (int g=0; g<NG; ++g){
    float bv = bias[og[g]*H + feat];
    f32x4 v = {bv,bv,bv,bv};
    acc[0][g]=v; acc[1][g]=v;
  }
}

DEV void pw4(const f32x4 (&acc)[2][4], char* AH, char* AC, const char* BC,
             int arow, int cbrow, int mtp, int l){
  #pragma unroll
  for (int mtI=0;mtI<2;++mtI){
    float hv[4], cv[4];
    int bb = (mtp*2+mtI)*16 + ((l>>4)<<2);
    #pragma unroll
    for (int r=0;r<4;++r){
      float cb = ldBF(BC, cbrow, bb + r);
      cv[r] = sigm(acc[mtI][1][r])*cb + sigm(acc[mtI][0][r])*tanh_(acc[mtI][2][r]);
      hv[r] = sigm(acc[mtI][3][r])*tanh_(cv[r]);
    }
    stBFpair(AH, arow, bb,   hv[0], hv[1]);
    stBFpair(AH, arow, bb+2, hv[2], hv[3]);
    stBFpair(AC, arow, bb,   cv[0], cv[1]);
    stBFpair(AC, arow, bb+2, cv[2], cv[3]);
  }
}

// ---- trans conv(k3,pad1)+exp, register-rotating reads, weights in log2-domain ----
// stride-1: NO+1 loads. Edge conditions are wave-uniform.
template<int L,int NO>
DEV void convE1(const char* Ain, int row0, const float* tw, int o0, int b,
                float (&y)[NO], float& s){
  float w0=tw[0]*1.44269504f, w1=tw[1]*1.44269504f, w2=tw[2]*1.44269504f;
  s = 0.f;
  float prev = (o0 >= 1) ? ldBF(Ain, row0+o0-1, b) : 0.f;
  float cur  = ldBF(Ain, row0+o0, b);
  #pragma unroll
  for (int j=0;j<NO;++j){
    int c = o0 + j;
    float nxt;
    if (j < NO-1) nxt = ldBF(Ain, row0+c+1, b);
    else          nxt = (o0+NO < L) ? ldBF(Ain, row0+c+1, b) : 0.f;
    float v = w0*prev + w1*cur + w2*nxt;
    y[j] = exp2r(v); s += y[j];
    prev = cur; cur = nxt;
  }
}
// stride-2: 2*NO+1 loads (c+1 < L always holds for our shapes; c-1<0 only at o0=0)
template<int L,int NO>
DEV void convE2(const char* Ain, int row0, const float* tw, int o0, int b,
                float (&y)[NO], float& s){
  float w0=tw[0]*1.44269504f, w1=tw[1]*1.44269504f, w2=tw[2]*1.44269504f;
  s = 0.f;
  float left = (o0 >= 1) ? ldBF(Ain, row0+2*o0-1, b) : 0.f;
  #pragma unroll
  for (int j=0;j<NO;++j){
    int c = 2*(o0+j);
    float mid = ldBF(Ain, row0+c,   b);
    float rgt = ldBF(Ain, row0+c+1, b);
    float v = w0*left + w1*mid + w2*rgt;
    y[j] = exp2r(v); s += y[j];
    left = rgt;
  }
}
// normalized write, A-fragment layout (one 16B store per 8 outputs)
template<int SZ,int NO>
DEV void wrTF(char* TFb, int subBase, int o0, int b, const float (&y)[NO], float inv){
  #pragma unroll
  for (int g8=0; g8<NO/8; ++g8){
    int oo = o0 + g8*8, fl = oo&31;
    char* base = TFb + (size_t)((subBase+(oo>>5))*4+(b>>4))*SZ + ((b&15)+16*(fl>>3))*16;
    unsigned d0=cvtpk(y[g8*8+0]*inv,y[g8*8+1]*inv), d1=cvtpk(y[g8*8+2]*inv,y[g8*8+3]*inv);
    unsigned d2=cvtpk(y[g8*8+4]*inv,y[g8*8+5]*inv), d3=cvtpk(y[g8*8+6]*inv,y[g8*8+7]*inv);
    *(uint4*)base = make_uint4(d0,d1,d2,d3);
  }
}
template<int NO>
DEV void wrBC(char* BCb, int row0, int b, const float (&y)[NO], float inv){
  #pragma unroll
  for (int j=0;j<NO;++j) stBF(BCb, row0+j, b, y[j]*inv);
}

// ---------------- main kernel -----------------
// launch_bounds(512,4): VGPR cap 128 (R3 showed (512,6) -> 40 VGPR + massive spill).
__global__ __launch_bounds__(512, 4) void dsgsf_main(P p, const char* blob){
  __shared__ __align__(16) char SM[51200];
  char* XP = SM;               // 16KB: spec A-frags [kc*4+mt]
  char* AH = SM + 16384;       //  8KB: h state [feat][batch] bf16 swizzled
  char* AC = SM + 24576;       //  8KB: c state
  char* BC = SM + 32768;       //  8KB: trans-c outputs
  char* TF = SM + 40960;       //  8KB: trans-h outputs as A-frags
  float* PSm = (float*)(SM + 49152);  // 2KB: softmax partial sums [task][batch]

  const int tid = threadIdx.x;
  const int l   = tid & 63;
  const int wu  = __builtin_amdgcn_readfirstlane(tid >> 6);
  const int mtp = wu & 1, z = wu >> 1;
  const long b0 = (long)blockIdx.x * 64;

  // ---- stage spec into A-fragment layout ----
  #pragma unroll
  for (int it=0; it<2; ++it){
    int n = it*512 + tid; int slot = n>>6, lx = n&63;
    int kc = slot>>2, mt = slot&3;
    const float* sp = p.spec + (b0 + mt*16 + (lx&15))*128 + kc*32 + ((lx>>4)<<3);
    float4 v0 = *(const float4*)sp; float4 v1 = *(const float4*)(sp+4);
    unsigned d0=cvtpk(v0.x,v0.y), d1=cvtpk(v0.z,v0.w);
    unsigned d2=cvtpk(v1.x,v1.y), d3=cvtpk(v1.z,v1.w);
    *(uint4*)(XP + (size_t)slot*1024 + lx*16) = make_uint4(d0,d1,d2,d3);
  }
  __syncthreads();

  // ================= F1: lstm0(spec), gates i,g,o =================
  {
    f32x4 acc[2][3];
    int feat = z*16 + (l&15);
    binit<3>(acc, p.fb1, 64, feat, 0,2,3,0);
    auto af = [&](int kt, int mt){ return frag(XP + (size_t)((kt<<2)+mt)*1024 + l*16); };
    gemm_reg<3,4,4>(acc, blob + (size_t)OF1*1024, z, mtp, l, af);
    #pragma unroll
    for (int mtI=0;mtI<2;++mtI){
      float hv[4], cv[4];
      int bb = (mtp*2+mtI)*16 + ((l>>4)<<2);
      #pragma unroll
      for (int r=0;r<4;++r){
        cv[r] = sigm(acc[mtI][0][r])*tanh_(acc[mtI][1][r]);
        hv[r] = sigm(acc[mtI][2][r])*tanh_(cv[r]);
      }
      stBFpair(AH, feat, bb,   hv[0], hv[1]);
      stBFpair(AH, feat, bb+2, hv[2], hv[3]);
      stBFpair(AC, feat, bb,   cv[0], cv[1]);
      stBFpair(AC, feat, bb+2, cv[2], cv[3]);
    }
  }
  __syncthreads();

  // ---- T12: chunks of 8, psum over 4 ----
  {
    float y[8], s;
    if (wu<4) convE2<64,8>(AH, 0, p.ft12h, wu*8, l, y, s);
    else      convE2<64,8>(AC, 0, p.ft12c, (wu-4)*8, l, y, s);
    PSm[wu*64+l] = s;
    __syncthreads();
    float tot = (wu<4) ? PSm[0*64+l]+PSm[1*64+l]+PSm[2*64+l]+PSm[3*64+l]
                       : PSm[4*64+l]+PSm[5*64+l]+PSm[6*64+l]+PSm[7*64+l];
    float inv = fastrcp(tot);
    if (wu<4) wrTF<1024,8>(TF, 0, wu*8, l, y, inv);
    else      wrBC<8>(BC, (wu-4)*8, l, y, inv);
  }
  __syncthreads();

  // ================= F2 =================
  {
    f32x4 acc[2][4];
    int step = z>>1, nf = z&1;
    int feat = nf*16 + (l&15);
    binit<4>(acc, p.fb2, 32, feat, 0,1,2,3);
    auto af = [&](int kt, int mt){
      return (kt<2) ? frag(XP + (size_t)(((2*step+kt)<<2)+mt)*1024 + l*16)
                    : frag(TF + (size_t)mt*1024 + l*16); };
    gemm_reg<4,2,3>(acc, blob + (size_t)OF2*1024, nf, mtp, l, af);
    pw4(acc, AH, AC, BC, step*32+feat, feat, mtp, l);
  }
  __syncthreads();

  // ---- T23: 2 steps x 2 chunks of 8, psum pairs ----
  {
    float y[8], s; int v=wu&3, st=v>>1, ch=v&1;
    if (wu<4) convE2<32,8>(AH, st*32, p.ft23h, ch*8, l, y, s);
    else      convE2<32,8>(AC, st*32, p.ft23c, ch*8, l, y, s);
    PSm[wu*64+l] = s;
    __syncthreads();
    int base = (wu&4) | (st<<1);
    float inv = fastrcp(PSm[base*64+l] + PSm[(base|1)*64+l]);
    if (wu<4) wrTF<512,8>(TF, st, ch*8, l, y, inv);
    else      wrBC<8>(BC, st*16+ch*8, l, y, inv);
  }
  __syncthreads();

  // ================= F3 =================
  {
    f32x4 acc[2][4];
    int s = z, feat = l&15;
    binit<4>(acc, p.fb3, 16, feat, 0,1,2,3);
    auto af = [&](int kt, int mt){
      return (kt==0) ? frag(XP + (size_t)((s<<2)+mt)*1024 + l*16)
                     : frag(TF + (size_t)(((s>>1)<<2)+mt)*512 + (l&31)*16); };
    gemm_reg<4,1,2>(acc, blob + (size_t)OF3*1024, 0, mtp, l, af);
    pw4(acc, AH, AC, BC, s*16+feat, (s>>1)*16+feat, mtp, l);
  }
  __syncthreads();

  // ---- T34: 8 independent rows of 8, local sums ----
  {
    float y[8], s;
    if (wu<4){ convE2<16,8>(AH, wu*16, p.ft34h, 0, l, y, s);
               wrTF<256,8>(TF, wu, 0, l, y, fastrcp(s)); }
    else     { convE2<16,8>(AC, (wu-4)*16, p.ft34h, 0, l, y, s);   // ref bug: ft34h for c
               wrBC<8>(BC, (wu-4)*8, l, y, fastrcp(s)); }
  }
  __syncthreads();

  // ================= F4 (parity-packed) =================
  {
    f32x4 a4[2][2][2]; // [parity uu][mtI][tile]
    float bv0 = p.fb4[l&15], bv1 = p.fb4[16+(l&15)];
    #pragma unroll
    for (int uu=0;uu<2;++uu)
      #pragma unroll
      for (int mtI=0;mtI<2;++mtI){ a4[uu][mtI][0]=f32x4{bv0,bv0,bv0,bv0}; a4[uu][mtI][1]=f32x4{bv1,bv1,bv1,bv1}; }
    const char* bs = blob + (size_t)OF4*1024;
    short8 A0 = frag(XP + (size_t)((z<<2)+mtp*2  )*1024 + l*16);
    short8 A1 = frag(XP + (size_t)((z<<2)+mtp*2+1)*1024 + l*16);
    short8 H0 = frag(TF + (size_t)((z<<2)+mtp*2  )*256 + (l&15)*16);
    short8 H1 = frag(TF + (size_t)((z<<2)+mtp*2+1)*256 + (l&15)*16);
    short8 bh0 = gfrag(bs + 4*1024 + l*16);
    short8 bh1 = gfrag(bs + 5*1024 + l*16);
    #pragma unroll
    for (int uu=0;uu<2;++uu){
      short8 bx0 = gfrag(bs + (uu*2+0)*1024 + l*16);
      short8 bx1 = gfrag(bs + (uu*2+1)*1024 + l*16);
      a4[uu][0][0]=MF(A0,bx0,a4[uu][0][0]); a4[uu][0][1]=MF(A0,bx1,a4[uu][0][1]);
      a4[uu][1][0]=MF(A1,bx0,a4[uu][1][0]); a4[uu][1][1]=MF(A1,bx1,a4[uu][1][1]);
      a4[uu][0][0]=MF(H0,bh0,a4[uu][0][0]); a4[uu][0][1]=MF(H0,bh1,a4[uu][0][1]);
      a4[uu][1][0]=MF(H1,bh0,a4[uu][1][0]); a4[uu][1][1]=MF(H1,bh1,a4[uu][1][1]);
    }
    #pragma unroll
    for (int uu=0;uu<2;++uu)
      #pragma unroll
      for (int mtI=0;mtI<2;++mtI)
        #pragma unroll
        for (int r=0;r<4;++r){
          float iv = a4[uu][mtI][0][r], gv = a4[uu][mtI][1][r];
          float xf = __shfl_xor(iv,8), xo = __shfl_xor(gv,8);
          if ((l&15)<8){
            int q = l&15, u = z*2+uu;
            int batch = (mtp*2+mtI)*16 + ((l>>4)<<2) + r;
            float cb = ldBF(BC, (u>>1)*8+q, batch);
            float c = sigm(xf)*cb + sigm(iv)*tanh_(gv);
            float h = sigm(xo)*tanh_(c);
            p.out[(size_t)(b0+batch)*128 + u*8 + q] = h;
          }
        }
  }

  // ================= B4 (parity-packed lstm0) =================
  {
    f32x4 a4[2][2][2];
    float bv0 = ((l&15)<8) ? p.bb4[l&15] : p.bb4[(l&15)+8];   // i | g
    float bv1 = ((l&15)<8) ? p.bb4[24+(l&15)] : 0.f;          // o | pad
    #pragma unroll
    for (int uu=0;uu<2;++uu)
      #pragma unroll
      for (int mtI=0;mtI<2;++mtI){ a4[uu][mtI][0]=f32x4{bv0,bv0,bv0,bv0}; a4[uu][mtI][1]=f32x4{bv1,bv1,bv1,bv1}; }
    const char* bs = blob + (size_t)OB4*1024;
    short8 A0 = frag(XP + (size_t)((z<<2)+mtp*2  )*1024 + l*16);
    short8 A1 = frag(XP + (size_t)((z<<2)+mtp*2+1)*1024 + l*16);
    #pragma unroll
    for (int uu=0;uu<2;++uu){
      short8 bx0 = gfrag(bs + (uu*2+0)*1024 + l*16);
      short8 bx1 = gfrag(bs + (uu*2+1)*1024 + l*16);
      a4[uu][0][0]=MF(A0,bx0,a4[uu][0][0]); a4[uu][0][1]=MF(A0,bx1,a4[uu][0][1]);
      a4[uu][1][0]=MF(A1,bx0,a4[uu][1][0]); a4[uu][1][1]=MF(A1,bx1,a4[uu][1][1]);
    }
    #pragma unroll
    for (int uu=0;uu<2;++uu)
      #pragma unroll
      for (int mtI=0;mtI<2;++mtI){
        float hv[4], cv[4];
        #pragma unroll
        for (int r=0;r<4;++r){
          float iv = a4[uu][mtI][0][r], ov = a4[uu][mtI][1][r];
          float gv = __shfl_xor(iv,8);
          cv[r] = sigm(iv)*tanh_(gv);
          hv[r] = sigm(ov)*tanh_(cv[r]);
        }
        if ((l&15)<8){
          int q = l&15, u = z*2+uu, f = u*8+q;
          int bb = (mtp*2+mtI)*16 + ((l>>4)<<2);
          stBFpair(AH, f, bb,   hv[0], hv[1]);
          stBFpair(AH, f, bb+2, hv[2], hv[3]);
          stBFpair(AC, f, bb,   cv[0], cv[1]);
          stBFpair(AC, f, bb+2, cv[2], cv[3]);
        }
      }
  }
  __syncthreads();

  // ---- T43: 8 independent rows of 16, local sums ----
  {
    float y[16], s;
    if (wu<4){ convE1<16,16>(AH, wu*16, p.bt43h, 0, l, y, s);
               wrTF<512,16>(TF, wu, 0, l, y, fastrcp(s)); }
    else     { convE1<16,16>(AC, (wu-4)*16, p.bt43c, 0, l, y, s);
               wrBC<16>(BC, (wu-4)*16, l, y, fastrcp(s)); }
  }
  __syncthreads();

  // ================= B3 =================
  {
    f32x4 acc[2][4];
    int s = z, feat = l&15;
    binit<4>(acc, p.bb3, 16, feat, 0,1,2,3);
    auto af = [&](int kt, int mt){
      return (kt==0) ? frag(XP + (size_t)((s<<2)+mt)*1024 + l*16)
                     : frag(TF + (size_t)((s<<2)+mt)*512 + (l&31)*16); };
    gemm_reg<4,1,2>(acc, blob + (size_t)OB3*1024, 0, mtp, l, af);
    pw4(acc, AH, AC, BC, s*16+feat, s*16+feat, mtp, l);
  }
  __syncthreads();

  // ---- T32: 2 steps x 2 chunks of 16, psum pairs ----
  {
    float y[16], s; int v=wu&3, st=v>>1, ch=v&1;
    if (wu<4) convE1<32,16>(AH, st*32, p.bt32h, ch*16, l, y, s);
    else      convE1<32,16>(AC, st*32, p.bt32c, ch*16, l, y, s);
    PSm[wu*64+l] = s;
    __syncthreads();
    int base = (wu&4) | (st<<1);
    float inv = fastrcp(PSm[base*64+l] + PSm[(base|1)*64+l]);
    if (wu<4) wrTF<1024,16>(TF, st, ch*16, l, y, inv);
    else      wrBC<16>(BC, st*32+ch*16, l, y, inv);
  }
  __syncthreads();

  // ================= B2 =================
  {
    f32x4 acc[2][4];
    int t2 = z>>1, nf = z&1;
    int feat = nf*16 + (l&15);
    binit<4>(acc, p.bb2, 32, feat, 0,1,2,3);
    auto af = [&](int kt, int mt){
      return (kt<2) ? frag(XP + (size_t)(((2*t2+kt)<<2)+mt)*1024 + l*16)
                    : frag(TF + (size_t)((t2<<2)+mt)*1024 + l*16); };
    gemm_reg<4,2,3>(acc, blob + (size_t)OB2*1024, nf, mtp, l, af);
    pw4(acc, AH, AC, BC, t2*32+feat, t2*32+feat, mtp, l);
  }
  __syncthreads();

  // ---- T21: 4 chunks of 16, psum over 4 ----
  {
    float y[16], s;
    if (wu<4) convE1<64,16>(AH, 0, p.bt21h, wu*16, l, y, s);
    else      convE1<64,16>(AC, 0, p.bt21c, (wu-4)*16, l, y, s);
    PSm[wu*64+l] = s;
    __syncthreads();
    float tot = (wu<4) ? PSm[0*64+l]+PSm[1*64+l]+PSm[2*64+l]+PSm[3*64+l]
                       : PSm[4*64+l]+PSm[5*64+l]+PSm[6*64+l]+PSm[7*64+l];
    float inv = fastrcp(tot);
    if (wu<4) wrTF<1024,16>(TF, 0, wu*16, l, y, inv);
    else      wrBC<16>(BC, (wu-4)*16, l, y, inv);
  }
  __syncthreads();

  // ================= B1: gates i,f,g -> c only =================
  {
    f32x4 acc[2][3];
    int feat = z*16 + (l&15);
    binit<3>(acc, p.bb1, 64, feat, 0,1,2,0);
    auto af = [&](int kt, int mt){
      return (kt<4) ? frag(XP + (size_t)((kt<<2)+mt)*1024 + l*16)
                    : frag(TF + (size_t)(((kt-4)<<2)+mt)*1024 + l*16); };
    gemm_reg<3,4,6>(acc, blob + (size_t)OB1*1024, z, mtp, l, af);
    #pragma unroll
    for (int mtI=0;mtI<2;++mtI)
      #pragma unroll
      for (int r=0;r<4;++r){
        int batch = (mtp*2+mtI)*16 + ((l>>4)<<2) + r;
        float cb = ldBF(BC, feat, batch);
        float c = sigm(acc[mtI][1][r])*cb + sigm(acc[mtI][0][r])*tanh_(acc[mtI][2][r]);
        p.out[(size_t)(b0+batch)*128 + 64 + feat] = c;
      }
  }
}

extern "C" void kernel_launch(void* const* d_in, const int* in_sizes, int n_in,
                              void* d_out, int out_size, void* d_ws, size_t ws_size,
                              hipStream_t stream) {
  if (ws_size < (size_t)BLOBB) return;
  P p;
  p.spec   = (const float*)d_in[0];
  p.fw_ih1 = (const float*)d_in[1];  p.fw_hh1 = (const float*)d_in[2];  p.fb1 = (const float*)d_in[3];
  p.fw_ih2 = (const float*)d_in[4];  p.fw_hh2 = (const float*)d_in[5];  p.fb2 = (const float*)d_in[6];
  p.fw_ih3 = (const float*)d_in[7];  p.fw_hh3 = (const float*)d_in[8];  p.fb3 = (const float*)d_in[9];
  p.fw_ih4 = (const float*)d_in[10]; p.fw_hh4 = (const float*)d_in[11]; p.fb4 = (const float*)d_in[12];
  p.bw_ih1 = (const float*)d_in[13]; p.bw_hh1 = (const float*)d_in[14]; p.bb1 = (const float*)d_in[15];
  p.bw_ih2 = (const float*)d_in[16]; p.bw_hh2 = (const float*)d_in[17]; p.bb2 = (const float*)d_in[18];
  p.bw_ih3 = (const float*)d_in[19]; p.bw_hh3 = (const float*)d_in[20]; p.bb3 = (const float*)d_in[21];
  p.bw_ih4 = (const float*)d_in[22]; p.bw_hh4 = (const float*)d_in[23]; p.bb4 = (const float*)d_in[24];
  p.ft12h = (const float*)d_in[25]; p.ft12c = (const float*)d_in[26];
  p.ft23h = (const float*)d_in[27]; p.ft23c = (const float*)d_in[28];
  p.ft34h = (const float*)d_in[29];
  p.bt43h = (const float*)d_in[30]; p.bt43c = (const float*)d_in[31];
  p.bt32h = (const float*)d_in[32]; p.bt32c = (const float*)d_in[33];
  p.bt21h = (const float*)d_in[34]; p.bt21c = (const float*)d_in[35];
  p.out = (float*)d_out;

  char* blob = (char*)d_ws;
  hipLaunchKernelGGL(dsgsf_prep, dim3(8), dim3(256), 0, stream, p, blob);
  int Bn = in_sizes[0] / 128;
  hipLaunchKernelGGL(dsgsf_main, dim3(Bn/64), dim3(512), 0, stream, p, (const char*)blob);
}

// Round 6
// 150.084 us; speedup vs baseline: 10.9940x; 1.0852x over previous
//
#include <hip/hip_runtime.h>

typedef __attribute__((ext_vector_type(4))) float f32x4;
typedef __attribute__((ext_vector_type(8))) short short8;

#define DEV __device__ __forceinline__

DEV float fastrcp(float x){ return __builtin_amdgcn_rcpf(x); }
DEV float exp2r(float x){ return __builtin_amdgcn_exp2f(x); }
DEV float sigm(float x){ return fastrcp(1.f + exp2r(x*-1.44269504f)); }
DEV float tanh_(float x){ return 1.f - 2.f*fastrcp(exp2r(x*2.88539008f)+1.f); }

// one-instruction bf16 packing (RNE)
DEV unsigned cvtpk(float lo, float hi){ unsigned r; asm("v_cvt_pk_bf16_f32 %0, %1, %2" : "=v"(r) : "v"(lo), "v"(hi)); return r; }
DEV unsigned short f2bf(float f){ return (unsigned short)cvtpk(f,f); }
DEV float bf2f(unsigned short h){ return __uint_as_float(((unsigned)h)<<16); }
DEV unsigned pack2(float a, float b){ return cvtpk(a,b); }

// bank swizzle for [feat][64batch] bf16 arrays (2-way-free on all hot patterns)
DEV int gmask(int f){ return ((f&1)<<5) | (f&2) | ((f&4)<<2); }
DEV void stBF(char* A, int f, int b, float v){ *(unsigned short*)(A + (((f<<6) + (b ^ gmask(f)))<<1)) = f2bf(v); }
// paired store: batches b (even) and b+1 — adjacent under swizzle (gmask has no bit0)
DEV void stBFpair(char* A, int f, int b, float v0, float v1){
  *(unsigned*)(A + (((f<<6) + (b ^ gmask(f)))<<1)) = cvtpk(v0, v1);
}
DEV float ldBF(const char* A, int f, int b){ return bf2f(*(const unsigned short*)(A + (((f<<6) + (b ^ gmask(f)))<<1))); }
// paired load: batches b (even), b+1
DEV float2 ldBF2(const char* A, int f, int b){
  unsigned u = *(const unsigned*)(A + (((f<<6) + (b ^ gmask(f)))<<1));
  return make_float2(__uint_as_float(u<<16), __uint_as_float(u & 0xffff0000u));
}

DEV short8 frag(const char* p){ return *(const short8*)p; }
DEV short8 gfrag(const char* p){ return *(const short8*)p; }   // global B-frag -> VGPR (L2-hit)
DEV f32x4 MF(short8 a, short8 b, f32x4 c){ return __builtin_amdgcn_mfma_f32_16x16x32_bf16(a,b,c,0,0,0); }

struct P {
  const float *spec;
  const float *fw_ih1,*fw_hh1,*fb1,*fw_ih2,*fw_hh2,*fb2,*fw_ih3,*fw_hh3,*fb3,*fw_ih4,*fw_hh4,*fb4;
  const float *bw_ih1,*bw_hh1,*bb1,*bw_ih2,*bw_hh2,*bb2,*bw_ih3,*bw_hh3,*bb3,*bw_ih4,*bw_hh4,*bb4;
  const float *ft12h,*ft12c,*ft23h,*ft23c,*ft34h,*bt43h,*bt43c,*bt32h,*bt32c,*bt21h,*bt21c;
  float *out;
};

// blob offsets in KB; slot = 1KB = one 16(row)x32(k) bf16 B-fragment
#define OF1 0
#define OF2 48
#define OF3 72
#define OF4 80
#define OB4 86
#define OB3 90
#define OB2 98
#define OB1 122
#define BLOBB (194*1024)

// ---------------- prep: pack weights into bf16 B-fragments -----------------
__global__ __launch_bounds__(256) void dsgsf_prep(P p, char* blob){
  int s = blockIdx.x;
  if (s == 3 || s == 4){            // F4 / B4: parity-packed (full 32-k spec chunks)
    bool isF = (s == 3);
    const float* wih = isF ? p.fw_ih4 : p.bw_ih4;
    const float* whh = p.fw_hh4;
    int nslot = isF ? 6 : 4;
    int off   = isF ? OF4 : OB4;
    for (int n = threadIdx.x; n < nslot*64; n += 256){
      int st = n>>6, lx = n&63;
      int R = lx&15, half = R>>3, feat = R&7;
      int k0 = ((lx>>4)<<3);
      unsigned dw[4];
      #pragma unroll
      for (int q=0;q<4;++q){
        float a=0.f, bv=0.f;
        int ka=k0+2*q, kb=ka+1;
        if (isF){
          if (st < 4){
            int pp = st>>1, t = st&1;
            int gi = t*2 + half;                 // t0:[i,f] t1:[g,o]
            int src = gi*8 + feat, base = pp*16;
            if (ka>=base && ka<base+16) a  = wih[src*16 + (ka-base)];
            if (kb>=base && kb<base+16) bv = wih[src*16 + (kb-base)];
          } else {
            int t = st-4; int gi = t*2 + half; int src = gi*8 + feat;
            if (ka<8) a  = whh[src*8+ka];
            if (kb<8) bv = whh[src*8+kb];
          }
        } else {
          int pp = st>>1, t = st&1;
          int gi = (t==0) ? (half? 2:0) : (half? -1:3);   // t0:[i,g] t1:[o,pad]
          if (gi >= 0){
            int src = gi*8 + feat, base = pp*16;
            if (ka>=base && ka<base+16) a  = wih[src*16 + (ka-base)];
            if (kb>=base && kb<base+16) bv = wih[src*16 + (kb-base)];
          }
        }
        dw[q] = pack2(a,bv);
      }
      *(uint4*)(blob + (size_t)(off+st)*1024 + lx*16) = make_uint4(dw[0],dw[1],dw[2],dw[3]);
    }
    return;
  }
  const float* wih=nullptr; const float* whh=nullptr;
  int H=0,NG=0,Kx=0,KXT=0,Kh=0,KT=0,NT=0,off=0,o0=0,o1=1,o2=2,o3=3;
  switch(s){
    case 0: wih=p.fw_ih1;               H=64;NG=3;Kx=128;KXT=4;Kh=0; KT=4;NT=12;off=OF1;o1=2;o2=3; break;
    case 1: wih=p.fw_ih2; whh=p.fw_hh2; H=32;NG=4;Kx=64; KXT=2;Kh=32;KT=3;NT=8; off=OF2; break;
    case 2: wih=p.fw_ih3; whh=p.fw_hh3; H=16;NG=4;Kx=32; KXT=1;Kh=16;KT=2;NT=4; off=OF3; break;
    case 5: wih=p.bw_ih3; whh=p.bw_hh3; H=16;NG=4;Kx=32; KXT=1;Kh=16;KT=2;NT=4; off=OB3; break;
    case 6: wih=p.bw_ih2; whh=p.bw_hh2; H=32;NG=4;Kx=64; KXT=2;Kh=32;KT=3;NT=8; off=OB2; break;
    default:wih=p.bw_ih1; whh=p.bw_hh1; H=64;NG=3;Kx=128;KXT=4;Kh=64;KT=6;NT=12;off=OB1; break;
  }
  int total = KT*NT*64;
  for (int n = threadIdx.x; n < total; n += 256){
    int kt = n/(NT*64); int rem = n - kt*NT*64; int nt = rem>>6; int lx = rem&63;
    int R = nt*16 + (lx&15);
    int gi = R / H; int feat = R - gi*H;
    int og = (gi==0)? o0 : (gi==1)? o1 : (gi==2)? o2 : o3;
    int src = og*H + feat;
    int k0 = kt*32 + ((lx>>4)<<3);
    unsigned dw[4];
    #pragma unroll
    for (int q=0;q<4;++q){
      float a=0.f, b=0.f;
      int ka=k0+2*q, kb=ka+1;
      if (gi < NG){
        if (ka < Kx) a = wih[(size_t)src*Kx + ka];
        else { int kh = ka - KXT*32; if (kh>=0 && kh<Kh) a = whh[(size_t)src*Kh + kh]; }
        if (kb < Kx) b = wih[(size_t)src*Kx + kb];
        else { int kh = kb - KXT*32; if (kh>=0 && kh<Kh) b = whh[(size_t)src*Kh + kh]; }
      }
      dw[q] = pack2(a,b);
    }
    *(uint4*)(blob + (size_t)off*1024 + (size_t)(kt*NT + nt)*1024 + lx*16) =
        make_uint4(dw[0],dw[1],dw[2],dw[3]);
  }
}

// ---------------- GEMM: B-fragments direct global->VGPR, no barriers ----------
template<int NG,int NFT,int KT, class AF>
DEV void gemm_reg(f32x4 (&acc)[2][NG], const char* bstage, int nf, int mtp, int l, AF af){
  constexpr int NT = NG*NFT;
  #pragma unroll
  for (int kt=0; kt<KT; ++kt){
    short8 a0 = af(kt, mtp*2);
    short8 a1 = af(kt, mtp*2+1);
    #pragma unroll
    for (int g=0; g<NG; ++g){
      short8 bf = gfrag(bstage + (size_t)(kt*NT + g*NFT + nf)*1024 + l*16);
      acc[0][g] = MF(a0, bf, acc[0][g]);
      acc[1][g] = MF(a1, bf, acc[1][g]);
    }
  }
}

template<int NG>
DEV void binit(f32x4 (&acc)[2][NG], const float* bias, int H, int feat,
               int o0, int o1, int o2, int o3){
  int og[4] = {o0,o1,o2,o3};
  #pragma unroll
  for (int g=0; g<NG; ++g){
    float bv = bias[og[g]*H + feat];
    f32x4 v = {bv,bv,bv,bv};
    acc[0][g]=v; acc[1][g]=v;
  }
}

DEV void pw4(const f32x4 (&acc)[2][4], char* AH, char* AC, const char* BC,
             int arow, int cbrow, int mtp, int l){
  #pragma unroll
  for (int mtI=0;mtI<2;++mtI){
    float hv[4], cv[4];
    int bb = (mtp*2+mtI)*16 + ((l>>4)<<2);
    float2 cb01 = ldBF2(BC, cbrow, bb), cb23 = ldBF2(BC, cbrow, bb+2);
    float cbv[4] = {cb01.x, cb01.y, cb23.x, cb23.y};
    #pragma unroll
    for (int r=0;r<4;++r){
      cv[r] = sigm(acc[mtI][1][r])*cbv[r] + sigm(acc[mtI][0][r])*tanh_(acc[mtI][2][r]);
      hv[r] = sigm(acc[mtI][3][r])*tanh_(cv[r]);
    }
    stBFpair(AH, arow, bb,   hv[0], hv[1]);
    stBFpair(AH, arow, bb+2, hv[2], hv[3]);
    stBFpair(AC, arow, bb,   cv[0], cv[1]);
    stBFpair(AC, arow, bb+2, cv[2], cv[3]);
  }
}

// ---- trans conv(k3,pad1)+exp, register-rotating reads, weights in log2-domain ----
template<int L,int NO>
DEV void convE1(const char* Ain, int row0, const float* tw, int o0, int b,
                float (&y)[NO], float& s){
  float w0=tw[0]*1.44269504f, w1=tw[1]*1.44269504f, w2=tw[2]*1.44269504f;
  s = 0.f;
  float prev = (o0 >= 1) ? ldBF(Ain, row0+o0-1, b) : 0.f;
  float cur  = ldBF(Ain, row0+o0, b);
  #pragma unroll
  for (int j=0;j<NO;++j){
    int c = o0 + j;
    float nxt;
    if (j < NO-1) nxt = ldBF(Ain, row0+c+1, b);
    else          nxt = (o0+NO < L) ? ldBF(Ain, row0+c+1, b) : 0.f;
    float v = w0*prev + w1*cur + w2*nxt;
    y[j] = exp2r(v); s += y[j];
    prev = cur; cur = nxt;
  }
}
template<int L,int NO>
DEV void convE2(const char* Ain, int row0, const float* tw, int o0, int b,
                float (&y)[NO], float& s){
  float w0=tw[0]*1.44269504f, w1=tw[1]*1.44269504f, w2=tw[2]*1.44269504f;
  s = 0.f;
  float left = (o0 >= 1) ? ldBF(Ain, row0+2*o0-1, b) : 0.f;
  #pragma unroll
  for (int j=0;j<NO;++j){
    int c = 2*(o0+j);
    float mid = ldBF(Ain, row0+c,   b);
    float rgt = ldBF(Ain, row0+c+1, b);
    float v = w0*left + w1*mid + w2*rgt;
    y[j] = exp2r(v); s += y[j];
    left = rgt;
  }
}
// normalized write, A-fragment layout (one 16B store per 8 outputs)
template<int SZ,int NO>
DEV void wrTF(char* TFb, int subBase, int o0, int b, const float (&y)[NO], float inv){
  #pragma unroll
  for (int g8=0; g8<NO/8; ++g8){
    int oo = o0 + g8*8, fl = oo&31;
    char* base = TFb + (size_t)((subBase+(oo>>5))*4+(b>>4))*SZ + ((b&15)+16*(fl>>3))*16;
    unsigned d0=cvtpk(y[g8*8+0]*inv,y[g8*8+1]*inv), d1=cvtpk(y[g8*8+2]*inv,y[g8*8+3]*inv);
    unsigned d2=cvtpk(y[g8*8+4]*inv,y[g8*8+5]*inv), d3=cvtpk(y[g8*8+6]*inv,y[g8*8+7]*inv);
    *(uint4*)base = make_uint4(d0,d1,d2,d3);
  }
}
template<int NO>
DEV void wrBC(char* BCb, int row0, int b, const float (&y)[NO], float inv){
  #pragma unroll
  for (int j=0;j<NO;++j) stBF(BCb, row0+j, b, y[j]*inv);
}

// ---------------- main kernel -----------------
// launch_bounds(512,4): VGPR cap 128 (R3 showed (512,6) -> 40 VGPR + massive spill).
__global__ __launch_bounds__(512, 4) void dsgsf_main(P p, const char* blob){
  __shared__ __align__(16) char SM[51200];
  char* XP = SM;               // 16KB: spec A-frags [kc*4+mt]
  char* AH = SM + 16384;       //  8KB: h state [feat][batch] bf16 swizzled
  char* AC = SM + 24576;       //  8KB: c state
  char* BC = SM + 32768;       //  8KB: trans-c outputs
  char* TF = SM + 40960;       //  8KB: trans-h outputs as A-frags
  float* PSm = (float*)(SM + 49152);  // 2KB: softmax partial sums [task][batch]

  const int tid = threadIdx.x;
  const int l   = tid & 63;
  const int wu  = __builtin_amdgcn_readfirstlane(tid >> 6);
  const int mtp = wu & 1, z = wu >> 1;
  const long b0 = (long)blockIdx.x * 64;

  // ---- stage spec into A-fragment layout ----
  #pragma unroll
  for (int it=0; it<2; ++it){
    int n = it*512 + tid; int slot = n>>6, lx = n&63;
    int kc = slot>>2, mt = slot&3;
    const float* sp = p.spec + (b0 + mt*16 + (lx&15))*128 + kc*32 + ((lx>>4)<<3);
    float4 v0 = *(const float4*)sp; float4 v1 = *(const float4*)(sp+4);
    unsigned d0=cvtpk(v0.x,v0.y), d1=cvtpk(v0.z,v0.w);
    unsigned d2=cvtpk(v1.x,v1.y), d3=cvtpk(v1.z,v1.w);
    *(uint4*)(XP + (size_t)slot*1024 + lx*16) = make_uint4(d0,d1,d2,d3);
  }
  __syncthreads();

  // ================= F1: lstm0(spec), gates i,g,o =================
  {
    f32x4 acc[2][3];
    int feat = z*16 + (l&15);
    binit<3>(acc, p.fb1, 64, feat, 0,2,3,0);
    auto af = [&](int kt, int mt){ return frag(XP + (size_t)((kt<<2)+mt)*1024 + l*16); };
    gemm_reg<3,4,4>(acc, blob + (size_t)OF1*1024, z, mtp, l, af);
    #pragma unroll
    for (int mtI=0;mtI<2;++mtI){
      float hv[4], cv[4];
      int bb = (mtp*2+mtI)*16 + ((l>>4)<<2);
      #pragma unroll
      for (int r=0;r<4;++r){
        cv[r] = sigm(acc[mtI][0][r])*tanh_(acc[mtI][1][r]);
        hv[r] = sigm(acc[mtI][2][r])*tanh_(cv[r]);
      }
      stBFpair(AH, feat, bb,   hv[0], hv[1]);
      stBFpair(AH, feat, bb+2, hv[2], hv[3]);
      stBFpair(AC, feat, bb,   cv[0], cv[1]);
      stBFpair(AC, feat, bb+2, cv[2], cv[3]);
    }
  }
  __syncthreads();

  // ---- T12: chunks of 8, psum over 4 ----
  {
    float y[8], s;
    if (wu<4) convE2<64,8>(AH, 0, p.ft12h, wu*8, l, y, s);
    else      convE2<64,8>(AC, 0, p.ft12c, (wu-4)*8, l, y, s);
    PSm[wu*64+l] = s;
    __syncthreads();
    float tot = (wu<4) ? PSm[0*64+l]+PSm[1*64+l]+PSm[2*64+l]+PSm[3*64+l]
                       : PSm[4*64+l]+PSm[5*64+l]+PSm[6*64+l]+PSm[7*64+l];
    float inv = fastrcp(tot);
    if (wu<4) wrTF<1024,8>(TF, 0, wu*8, l, y, inv);
    else      wrBC<8>(BC, (wu-4)*8, l, y, inv);
  }
  __syncthreads();

  // ================= F2 =================
  {
    f32x4 acc[2][4];
    int step = z>>1, nf = z&1;
    int feat = nf*16 + (l&15);
    binit<4>(acc, p.fb2, 32, feat, 0,1,2,3);
    auto af = [&](int kt, int mt){
      return (kt<2) ? frag(XP + (size_t)(((2*step+kt)<<2)+mt)*1024 + l*16)
                    : frag(TF + (size_t)mt*1024 + l*16); };
    gemm_reg<4,2,3>(acc, blob + (size_t)OF2*1024, nf, mtp, l, af);
    pw4(acc, AH, AC, BC, step*32+feat, feat, mtp, l);
  }
  __syncthreads();

  // ---- T23: 2 steps x 2 chunks of 8, psum pairs ----
  {
    float y[8], s; int v=wu&3, st=v>>1, ch=v&1;
    if (wu<4) convE2<32,8>(AH, st*32, p.ft23h, ch*8, l, y, s);
    else      convE2<32,8>(AC, st*32, p.ft23c, ch*8, l, y, s);
    PSm[wu*64+l] = s;
    __syncthreads();
    int base = (wu&4) | (st<<1);
    float inv = fastrcp(PSm[base*64+l] + PSm[(base|1)*64+l]);
    if (wu<4) wrTF<512,8>(TF, st, ch*8, l, y, inv);
    else      wrBC<8>(BC, st*16+ch*8, l, y, inv);
  }
  __syncthreads();

  // ================= F3 =================
  {
    f32x4 acc[2][4];
    int s = z, feat = l&15;
    binit<4>(acc, p.fb3, 16, feat, 0,1,2,3);
    auto af = [&](int kt, int mt){
      return (kt==0) ? frag(XP + (size_t)((s<<2)+mt)*1024 + l*16)
                     : frag(TF + (size_t)(((s>>1)<<2)+mt)*512 + (l&31)*16); };
    gemm_reg<4,1,2>(acc, blob + (size_t)OF3*1024, 0, mtp, l, af);
    pw4(acc, AH, AC, BC, s*16+feat, (s>>1)*16+feat, mtp, l);
  }
  __syncthreads();

  // ---- T34: 8 independent rows of 8, local sums ----
  {
    float y[8], s;
    if (wu<4){ convE2<16,8>(AH, wu*16, p.ft34h, 0, l, y, s);
               wrTF<256,8>(TF, wu, 0, l, y, fastrcp(s)); }
    else     { convE2<16,8>(AC, (wu-4)*16, p.ft34h, 0, l, y, s);   // ref bug: ft34h for c
               wrBC<8>(BC, (wu-4)*8, l, y, fastrcp(s)); }
  }
  __syncthreads();

  // ================= F4 (parity-packed, all-lane epilogue) =================
  {
    f32x4 a4[2][2][2]; // [parity uu][mtI][tile]
    float bv0 = p.fb4[l&15], bv1 = p.fb4[16+(l&15)];
    #pragma unroll
    for (int uu=0;uu<2;++uu)
      #pragma unroll
      for (int mtI=0;mtI<2;++mtI){ a4[uu][mtI][0]=f32x4{bv0,bv0,bv0,bv0}; a4[uu][mtI][1]=f32x4{bv1,bv1,bv1,bv1}; }
    const char* bs = blob + (size_t)OF4*1024;
    short8 A0 = frag(XP + (size_t)((z<<2)+mtp*2  )*1024 + l*16);
    short8 A1 = frag(XP + (size_t)((z<<2)+mtp*2+1)*1024 + l*16);
    short8 H0 = frag(TF + (size_t)((z<<2)+mtp*2  )*256 + (l&15)*16);
    short8 H1 = frag(TF + (size_t)((z<<2)+mtp*2+1)*256 + (l&15)*16);
    short8 bh0 = gfrag(bs + 4*1024 + l*16);
    short8 bh1 = gfrag(bs + 5*1024 + l*16);
    #pragma unroll
    for (int uu=0;uu<2;++uu){
      short8 bx0 = gfrag(bs + (uu*2+0)*1024 + l*16);
      short8 bx1 = gfrag(bs + (uu*2+1)*1024 + l*16);
      a4[uu][0][0]=MF(A0,bx0,a4[uu][0][0]); a4[uu][0][1]=MF(A0,bx1,a4[uu][0][1]);
      a4[uu][1][0]=MF(A1,bx0,a4[uu][1][0]); a4[uu][1][1]=MF(A1,bx1,a4[uu][1][1]);
      a4[uu][0][0]=MF(H0,bh0,a4[uu][0][0]); a4[uu][0][1]=MF(H0,bh1,a4[uu][0][1]);
      a4[uu][1][0]=MF(H1,bh0,a4[uu][1][0]); a4[uu][1][1]=MF(H1,bh1,a4[uu][1][1]);
    }
    // lane-half q<8 -> uu=0, q>=8 -> uu=1; gates redistributed by shfl_xor(8)
    const bool sel = (l&15) < 8;
    const int qe = l&7;
    const int u = z*2 + (sel ? 0 : 1);
    #pragma unroll
    for (int mtI=0;mtI<2;++mtI){
      int bb = (mtp*2+mtI)*16 + ((l>>4)<<2);
      float2 cb01 = ldBF2(BC, z*8+qe, bb), cb23 = ldBF2(BC, z*8+qe, bb+2);
      float cbv[4] = {cb01.x, cb01.y, cb23.x, cb23.y};
      #pragma unroll
      for (int r=0;r<4;++r){
        float s00 = __shfl_xor(a4[0][mtI][0][r],8), s10 = __shfl_xor(a4[1][mtI][0][r],8);
        float s01 = __shfl_xor(a4[0][mtI][1][r],8), s11 = __shfl_xor(a4[1][mtI][1][r],8);
        float iv = sel ? a4[0][mtI][0][r] : s10;
        float fv = sel ? s00 : a4[1][mtI][0][r];
        float gv = sel ? a4[0][mtI][1][r] : s11;
        float ov = sel ? s01 : a4[1][mtI][1][r];
        float c = sigm(fv)*cbv[r] + sigm(iv)*tanh_(gv);
        float h = sigm(ov)*tanh_(c);
        p.out[(size_t)(b0+bb+r)*128 + u*8 + qe] = h;
      }
    }
  }

  // ================= B4 (parity-packed lstm0, all-lane epilogue) =================
  {
    f32x4 a4[2][2][2];
    float bv0 = ((l&15)<8) ? p.bb4[l&15] : p.bb4[(l&15)+8];   // i | g
    float bv1 = ((l&15)<8) ? p.bb4[24+(l&15)] : 0.f;          // o | pad
    #pragma unroll
    for (int uu=0;uu<2;++uu)
      #pragma unroll
      for (int mtI=0;mtI<2;++mtI){ a4[uu][mtI][0]=f32x4{bv0,bv0,bv0,bv0}; a4[uu][mtI][1]=f32x4{bv1,bv1,bv1,bv1}; }
    const char* bs = blob + (size_t)OB4*1024;
    short8 A0 = frag(XP + (size_t)((z<<2)+mtp*2  )*1024 + l*16);
    short8 A1 = frag(XP + (size_t)((z<<2)+mtp*2+1)*1024 + l*16);
    #pragma unroll
    for (int uu=0;uu<2;++uu){
      short8 bx0 = gfrag(bs + (uu*2+0)*1024 + l*16);
      short8 bx1 = gfrag(bs + (uu*2+1)*1024 + l*16);
      a4[uu][0][0]=MF(A0,bx0,a4[uu][0][0]); a4[uu][0][1]=MF(A0,bx1,a4[uu][0][1]);
      a4[uu][1][0]=MF(A1,bx0,a4[uu][1][0]); a4[uu][1][1]=MF(A1,bx1,a4[uu][1][1]);
    }
    const bool sel = (l&15) < 8;
    const int qe = l&7;
    const int u = z*2 + (sel ? 0 : 1);
    const int f = u*8 + qe;
    #pragma unroll
    for (int mtI=0;mtI<2;++mtI){
      float hv[4], cv[4];
      int bb = (mtp*2+mtI)*16 + ((l>>4)<<2);
      #pragma unroll
      for (int r=0;r<4;++r){
        float s0 = __shfl_xor(a4[0][mtI][0][r],8);   // lane<8 gets g(uu0); lane>=8 gets i(uu0) (unused)
        float s1 = __shfl_xor(a4[1][mtI][0][r],8);   // lane>=8 gets i(uu1)
        float s2 = __shfl_xor(a4[1][mtI][1][r],8);   // lane>=8 gets o(uu1)
        float iv = sel ? a4[0][mtI][0][r] : s1;
        float gv = sel ? s0 : a4[1][mtI][0][r];
        float ov = sel ? a4[0][mtI][1][r] : s2;
        cv[r] = sigm(iv)*tanh_(gv);
        hv[r] = sigm(ov)*tanh_(cv[r]);
      }
      stBFpair(AH, f, bb,   hv[0], hv[1]);
      stBFpair(AH, f, bb+2, hv[2], hv[3]);
      stBFpair(AC, f, bb,   cv[0], cv[1]);
      stBFpair(AC, f, bb+2, cv[2], cv[3]);
    }
  }
  __syncthreads();

  // ---- T43: 8 independent rows of 16, local sums ----
  {
    float y[16], s;
    if (wu<4){ convE1<16,16>(AH, wu*16, p.bt43h, 0, l, y, s);
               wrTF<512,16>(TF, wu, 0, l, y, fastrcp(s)); }
    else     { convE1<16,16>(AC, (wu-4)*16, p.bt43c, 0, l, y, s);
               wrBC<16>(BC, (wu-4)*16, l, y, fastrcp(s)); }
  }
  __syncthreads();

  // ================= B3 =================
  {
    f32x4 acc[2][4];
    int s = z, feat = l&15;
    binit<4>(acc, p.bb3, 16, feat, 0,1,2,3);
    auto af = [&](int kt, int mt){
      return (kt==0) ? frag(XP + (size_t)((s<<2)+mt)*1024 + l*16)
                     : frag(TF + (size_t)((s<<2)+mt)*512 + (l&31)*16); };
    gemm_reg<4,1,2>(acc, blob + (size_t)OB3*1024, 0, mtp, l, af);
    pw4(acc, AH, AC, BC, s*16+feat, s*16+feat, mtp, l);
  }
  __syncthreads();

  // ---- T32: 2 steps x 2 chunks of 16, psum pairs ----
  {
    float y[16], s; int v=wu&3, st=v>>1, ch=v&1;
    if (wu<4) convE1<32,16>(AH, st*32, p.bt32h, ch*16, l, y, s);
    else      convE1<32,16>(AC, st*32, p.bt32c, ch*16, l, y, s);
    PSm[wu*64+l] = s;
    __syncthreads();
    int base = (wu&4) | (st<<1);
    float inv = fastrcp(PSm[base*64+l] + PSm[(base|1)*64+l]);
    if (wu<4) wrTF<1024,16>(TF, st, ch*16, l, y, inv);
    else      wrBC<16>(BC, st*32+ch*16, l, y, inv);
  }
  __syncthreads();

  // ================= B2 =================
  {
    f32x4 acc[2][4];
    int t2 = z>>1, nf = z&1;
    int feat = nf*16 + (l&15);
    binit<4>(acc, p.bb2, 32, feat, 0,1,2,3);
    auto af = [&](int kt, int mt){
      return (kt<2) ? frag(XP + (size_t)(((2*t2+kt)<<2)+mt)*1024 + l*16)
                    : frag(TF + (size_t)((t2<<2)+mt)*1024 + l*16); };
    gemm_reg<4,2,3>(acc, blob + (size_t)OB2*1024, nf, mtp, l, af);
    pw4(acc, AH, AC, BC, t2*32+feat, t2*32+feat, mtp, l);
  }
  __syncthreads();

  // ---- T21: 4 chunks of 16, psum over 4 ----
  {
    float y[16], s;
    if (wu<4) convE1<64,16>(AH, 0, p.bt21h, wu*16, l, y, s);
    else      convE1<64,16>(AC, 0, p.bt21c, (wu-4)*16, l, y, s);
    PSm[wu*64+l] = s;
    __syncthreads();
    float tot = (wu<4) ? PSm[0*64+l]+PSm[1*64+l]+PSm[2*64+l]+PSm[3*64+l]
                       : PSm[4*64+l]+PSm[5*64+l]+PSm[6*64+l]+PSm[7*64+l];
    float inv = fastrcp(tot);
    if (wu<4) wrTF<1024,16>(TF, 0, wu*16, l, y, inv);
    else      wrBC<16>(BC, (wu-4)*16, l, y, inv);
  }
  __syncthreads();

  // ================= B1: gates i,f,g -> c only =================
  {
    f32x4 acc[2][3];
    int feat = z*16 + (l&15);
    binit<3>(acc, p.bb1, 64, feat, 0,1,2,0);
    auto af = [&](int kt, int mt){
      return (kt<4) ? frag(XP + (size_t)((kt<<2)+mt)*1024 + l*16)
                    : frag(TF + (size_t)(((kt-4)<<2)+mt)*1024 + l*16); };
    gemm_reg<3,4,6>(acc, blob + (size_t)OB1*1024, z, mtp, l, af);
    #pragma unroll
    for (int mtI=0;mtI<2;++mtI){
      int bb = (mtp*2+mtI)*16 + ((l>>4)<<2);
      float2 cb01 = ldBF2(BC, feat, bb), cb23 = ldBF2(BC, feat, bb+2);
      float cbv[4] = {cb01.x, cb01.y, cb23.x, cb23.y};
      #pragma unroll
      for (int r=0;r<4;++r){
        float c = sigm(acc[mtI][1][r])*cbv[r] + sigm(acc[mtI][0][r])*tanh_(acc[mtI][2][r]);
        p.out[(size_t)(b0+bb+r)*128 + 64 + feat] = c;
      }
    }
  }
}

extern "C" void kernel_launch(void* const* d_in, const int* in_sizes, int n_in,
                              void* d_out, int out_size, void* d_ws, size_t ws_size,
                              hipStream_t stream) {
  if (ws_size < (size_t)BLOBB) return;
  P p;
  p.spec   = (const float*)d_in[0];
  p.fw_ih1 = (const float*)d_in[1];  p.fw_hh1 = (const float*)d_in[2];  p.fb1 = (const float*)d_in[3];
  p.fw_ih2 = (const float*)d_in[4];  p.fw_hh2 = (const float*)d_in[5];  p.fb2 = (const float*)d_in[6];
  p.fw_ih3 = (const float*)d_in[7];  p.fw_hh3 = (const float*)d_in[8];  p.fb3 = (const float*)d_in[9];
  p.fw_ih4 = (const float*)d_in[10]; p.fw_hh4 = (const float*)d_in[11]; p.fb4 = (const float*)d_in[12];
  p.bw_ih1 = (const float*)d_in[13]; p.bw_hh1 = (const float*)d_in[14]; p.bb1 = (const float*)d_in[15];
  p.bw_ih2 = (const float*)d_in[16]; p.bw_hh2 = (const float*)d_in[17]; p.bb2 = (const float*)d_in[18];
  p.bw_ih3 = (const float*)d_in[19]; p.bw_hh3 = (const float*)d_in[20]; p.bb3 = (const float*)d_in[21];
  p.bw_ih4 = (const float*)d_in[22]; p.bw_hh4 = (const float*)d_in[23]; p.bb4 = (const float*)d_in[24];
  p.ft12h = (const float*)d_in[25]; p.ft12c = (const float*)d_in[26];
  p.ft23h = (const float*)d_in[27]; p.ft23c = (const float*)d_in[28];
  p.ft34h = (const float*)d_in[29];
  p.bt43h = (const float*)d_in[30]; p.bt43c = (const float*)d_in[31];
  p.bt32h = (const float*)d_in[32]; p.bt32c = (const float*)d_in[33];
  p.bt21h = (const float*)d_in[34]; p.bt21c = (const float*)d_in[35];
  p.out = (float*)d_out;

  char* blob = (char*)d_ws;
  hipLaunchKernelGGL(dsgsf_prep, dim3(8), dim3(256), 0, stream, p, blob);
  int Bn = in_sizes[0] / 128;
  hipLaunchKernelGGL(dsgsf_main, dim3(Bn/64), dim3(512), 0, stream, p, (const char*)blob);
}

// Round 7
// 145.475 us; speedup vs baseline: 11.3423x; 1.0317x over previous
//
#include <hip/hip_runtime.h>

typedef __attribute__((ext_vector_type(4))) float f32x4;
typedef __attribute__((ext_vector_type(8))) short short8;

#define DEV __device__ __forceinline__

DEV float fastrcp(float x){ return __builtin_amdgcn_rcpf(x); }
DEV float exp2r(float x){ return __builtin_amdgcn_exp2f(x); }

// ---- trans-minimized LSTM pointwise (common-denominator folding) ----
// c = sigm(f)*cb + sigm(i)*tanh(g)  with u=e^-f, v=e^-i, w=e^2g:
//   = [cb(1+v)(1+w) + (w-1)(1+u)] / ((1+u)(1+v)(1+w))   -> 3 exp + 1 rcp
DEV float lstm_c(float gi, float gf, float gg, float cb){
  float v = exp2r(gi*-1.44269504f);
  float u = exp2r(gf*-1.44269504f);
  float w = exp2r(gg*2.88539008f);
  float pv = 1.f+v, pu = 1.f+u, pw = 1.f+w;
  float pvw = pv*pw;
  return (cb*pvw + (w-1.f)*pu) * fastrcp(pu*pvw);
}
// h = sigm(o)*tanh(c) = (y-1)/((1+x)(1+y)), x=e^-o, y=e^2c -> 2 exp + 1 rcp
DEV float lstm_h(float go, float c){
  float x = exp2r(go*-1.44269504f);
  float y = exp2r(c*2.88539008f);
  return (y-1.f)*fastrcp((1.f+x)*(1.f+y));
}
// lstm0: c = sigm(i)*tanh(g) = (w-1)/((1+v)(1+w)) -> 2 exp + 1 rcp
DEV float lstm0_c(float gi, float gg){
  float v = exp2r(gi*-1.44269504f);
  float w = exp2r(gg*2.88539008f);
  return (w-1.f)*fastrcp((1.f+v)*(1.f+w));
}

// one-instruction bf16 packing (RNE)
DEV unsigned cvtpk(float lo, float hi){ unsigned r; asm("v_cvt_pk_bf16_f32 %0, %1, %2" : "=v"(r) : "v"(lo), "v"(hi)); return r; }
DEV unsigned short f2bf(float f){ return (unsigned short)cvtpk(f,f); }
DEV float bf2f(unsigned short h){ return __uint_as_float(((unsigned)h)<<16); }
DEV unsigned pack2(float a, float b){ return cvtpk(a,b); }

// bank swizzle for [feat][64batch] bf16 arrays (2-way-free on all hot patterns)
DEV int gmask(int f){ return ((f&1)<<5) | (f&2) | ((f&4)<<2); }
DEV void stBF(char* A, int f, int b, float v){ *(unsigned short*)(A + (((f<<6) + (b ^ gmask(f)))<<1)) = f2bf(v); }
// paired store: batches b (even) and b+1 — adjacent under swizzle (gmask has no bit0)
DEV void stBFpair(char* A, int f, int b, float v0, float v1){
  *(unsigned*)(A + (((f<<6) + (b ^ gmask(f)))<<1)) = cvtpk(v0, v1);
}
DEV float ldBF(const char* A, int f, int b){ return bf2f(*(const unsigned short*)(A + (((f<<6) + (b ^ gmask(f)))<<1))); }
// paired load: batches b (even), b+1
DEV float2 ldBF2(const char* A, int f, int b){
  unsigned u = *(const unsigned*)(A + (((f<<6) + (b ^ gmask(f)))<<1));
  return make_float2(__uint_as_float(u<<16), __uint_as_float(u & 0xffff0000u));
}

DEV short8 frag(const char* p){ return *(const short8*)p; }
DEV short8 gfrag(const char* p){ return *(const short8*)p; }   // global B-frag -> VGPR (L2-hit)
DEV f32x4 MF(short8 a, short8 b, f32x4 c){ return __builtin_amdgcn_mfma_f32_16x16x32_bf16(a,b,c,0,0,0); }

struct P {
  const float *spec;
  const float *fw_ih1,*fw_hh1,*fb1,*fw_ih2,*fw_hh2,*fb2,*fw_ih3,*fw_hh3,*fb3,*fw_ih4,*fw_hh4,*fb4;
  const float *bw_ih1,*bw_hh1,*bb1,*bw_ih2,*bw_hh2,*bb2,*bw_ih3,*bw_hh3,*bb3,*bw_ih4,*bw_hh4,*bb4;
  const float *ft12h,*ft12c,*ft23h,*ft23c,*ft34h,*bt43h,*bt43c,*bt32h,*bt32c,*bt21h,*bt21c;
  float *out;
};

// blob offsets in KB; slot = 1KB = one 16(row)x32(k) bf16 B-fragment
#define OF1 0
#define OF2 48
#define OF3 72
#define OF4 80
#define OB4 86
#define OB3 90
#define OB2 98
#define OB1 122
#define BLOBB (194*1024)

// ---------------- prep: pack weights into bf16 B-fragments -----------------
__global__ __launch_bounds__(256) void dsgsf_prep(P p, char* blob){
  int s = blockIdx.x;
  if (s == 3 || s == 4){            // F4 / B4: parity-packed (full 32-k spec chunks)
    bool isF = (s == 3);
    const float* wih = isF ? p.fw_ih4 : p.bw_ih4;
    const float* whh = p.fw_hh4;
    int nslot = isF ? 6 : 4;
    int off   = isF ? OF4 : OB4;
    for (int n = threadIdx.x; n < nslot*64; n += 256){
      int st = n>>6, lx = n&63;
      int R = lx&15, half = R>>3, feat = R&7;
      int k0 = ((lx>>4)<<3);
      unsigned dw[4];
      #pragma unroll
      for (int q=0;q<4;++q){
        float a=0.f, bv=0.f;
        int ka=k0+2*q, kb=ka+1;
        if (isF){
          if (st < 4){
            int pp = st>>1, t = st&1;
            int gi = t*2 + half;                 // t0:[i,f] t1:[g,o]
            int src = gi*8 + feat, base = pp*16;
            if (ka>=base && ka<base+16) a  = wih[src*16 + (ka-base)];
            if (kb>=base && kb<base+16) bv = wih[src*16 + (kb-base)];
          } else {
            int t = st-4; int gi = t*2 + half; int src = gi*8 + feat;
            if (ka<8) a  = whh[src*8+ka];
            if (kb<8) bv = whh[src*8+kb];
          }
        } else {
          int pp = st>>1, t = st&1;
          int gi = (t==0) ? (half? 2:0) : (half? -1:3);   // t0:[i,g] t1:[o,pad]
          if (gi >= 0){
            int src = gi*8 + feat, base = pp*16;
            if (ka>=base && ka<base+16) a  = wih[src*16 + (ka-base)];
            if (kb>=base && kb<base+16) bv = wih[src*16 + (kb-base)];
          }
        }
        dw[q] = pack2(a,bv);
      }
      *(uint4*)(blob + (size_t)(off+st)*1024 + lx*16) = make_uint4(dw[0],dw[1],dw[2],dw[3]);
    }
    return;
  }
  const float* wih=nullptr; const float* whh=nullptr;
  int H=0,NG=0,Kx=0,KXT=0,Kh=0,KT=0,NT=0,off=0,o0=0,o1=1,o2=2,o3=3;
  switch(s){
    case 0: wih=p.fw_ih1;               H=64;NG=3;Kx=128;KXT=4;Kh=0; KT=4;NT=12;off=OF1;o1=2;o2=3; break;
    case 1: wih=p.fw_ih2; whh=p.fw_hh2; H=32;NG=4;Kx=64; KXT=2;Kh=32;KT=3;NT=8; off=OF2; break;
    case 2: wih=p.fw_ih3; whh=p.fw_hh3; H=16;NG=4;Kx=32; KXT=1;Kh=16;KT=2;NT=4; off=OF3; break;
    case 5: wih=p.bw_ih3; whh=p.bw_hh3; H=16;NG=4;Kx=32; KXT=1;Kh=16;KT=2;NT=4; off=OB3; break;
    case 6: wih=p.bw_ih2; whh=p.bw_hh2; H=32;NG=4;Kx=64; KXT=2;Kh=32;KT=3;NT=8; off=OB2; break;
    default:wih=p.bw_ih1; whh=p.bw_hh1; H=64;NG=3;Kx=128;KXT=4;Kh=64;KT=6;NT=12;off=OB1; break;
  }
  int total = KT*NT*64;
  for (int n = threadIdx.x; n < total; n += 256){
    int kt = n/(NT*64); int rem = n - kt*NT*64; int nt = rem>>6; int lx = rem&63;
    int R = nt*16 + (lx&15);
    int gi = R / H; int feat = R - gi*H;
    int og = (gi==0)? o0 : (gi==1)? o1 : (gi==2)? o2 : o3;
    int src = og*H + feat;
    int k0 = kt*32 + ((lx>>4)<<3);
    unsigned dw[4];
    #pragma unroll
    for (int q=0;q<4;++q){
      float a=0.f, b=0.f;
      int ka=k0+2*q, kb=ka+1;
      if (gi < NG){
        if (ka < Kx) a = wih[(size_t)src*Kx + ka];
        else { int kh = ka - KXT*32; if (kh>=0 && kh<Kh) a = whh[(size_t)src*Kh + kh]; }
        if (kb < Kx) b = wih[(size_t)src*Kx + kb];
        else { int kh = kb - KXT*32; if (kh>=0 && kh<Kh) b = whh[(size_t)src*Kh + kh]; }
      }
      dw[q] = pack2(a,b);
    }
    *(uint4*)(blob + (size_t)off*1024 + (size_t)(kt*NT + nt)*1024 + lx*16) =
        make_uint4(dw[0],dw[1],dw[2],dw[3]);
  }
}

// ---------------- GEMM: B-fragments direct global->VGPR, no barriers ----------
template<int NG,int NFT,int KT, class AF>
DEV void gemm_reg(f32x4 (&acc)[2][NG], const char* bstage, int nf, int mtp, int l, AF af){
  constexpr int NT = NG*NFT;
  #pragma unroll
  for (int kt=0; kt<KT; ++kt){
    short8 a0 = af(kt, mtp*2);
    short8 a1 = af(kt, mtp*2+1);
    #pragma unroll
    for (int g=0; g<NG; ++g){
      short8 bf = gfrag(bstage + (size_t)(kt*NT + g*NFT + nf)*1024 + l*16);
      acc[0][g] = MF(a0, bf, acc[0][g]);
      acc[1][g] = MF(a1, bf, acc[1][g]);
    }
  }
}

template<int NG>
DEV void binit(f32x4 (&acc)[2][NG], const float* bias, int H, int feat,
               int o0, int o1, int o2, int o3){
  int og[4] = {o0,o1,o2,o3};
  #pragma unroll
  for (int g=0; g<NG; ++g){
    float bv = bias[og[g]*H + feat];
    f32x4 v = {bv,bv,bv,bv};
    acc[0][g]=v; acc[1][g]=v;
  }
}

DEV void pw4(const f32x4 (&acc)[2][4], char* AH, char* AC, const char* BC,
             int arow, int cbrow, int mtp, int l){
  #pragma unroll
  for (int mtI=0;mtI<2;++mtI){
    float hv[4], cv[4];
    int bb = (mtp*2+mtI)*16 + ((l>>4)<<2);
    float2 cb01 = ldBF2(BC, cbrow, bb), cb23 = ldBF2(BC, cbrow, bb+2);
    float cbv[4] = {cb01.x, cb01.y, cb23.x, cb23.y};
    #pragma unroll
    for (int r=0;r<4;++r){
      cv[r] = lstm_c(acc[mtI][0][r], acc[mtI][1][r], acc[mtI][2][r], cbv[r]);
      hv[r] = lstm_h(acc[mtI][3][r], cv[r]);
    }
    stBFpair(AH, arow, bb,   hv[0], hv[1]);
    stBFpair(AH, arow, bb+2, hv[2], hv[3]);
    stBFpair(AC, arow, bb,   cv[0], cv[1]);
    stBFpair(AC, arow, bb+2, cv[2], cv[3]);
  }
}

// ---- trans conv(k3,pad1)+exp, register-rotating reads, weights in log2-domain ----
template<int L,int NO>
DEV void convE1(const char* Ain, int row0, const float* tw, int o0, int b,
                float (&y)[NO], float& s){
  float w0=tw[0]*1.44269504f, w1=tw[1]*1.44269504f, w2=tw[2]*1.44269504f;
  s = 0.f;
  float prev = (o0 >= 1) ? ldBF(Ain, row0+o0-1, b) : 0.f;
  float cur  = ldBF(Ain, row0+o0, b);
  #pragma unroll
  for (int j=0;j<NO;++j){
    int c = o0 + j;
    float nxt;
    if (j < NO-1) nxt = ldBF(Ain, row0+c+1, b);
    else          nxt = (o0+NO < L) ? ldBF(Ain, row0+c+1, b) : 0.f;
    float v = w0*prev + w1*cur + w2*nxt;
    y[j] = exp2r(v); s += y[j];
    prev = cur; cur = nxt;
  }
}
template<int L,int NO>
DEV void convE2(const char* Ain, int row0, const float* tw, int o0, int b,
                float (&y)[NO], float& s){
  float w0=tw[0]*1.44269504f, w1=tw[1]*1.44269504f, w2=tw[2]*1.44269504f;
  s = 0.f;
  float left = (o0 >= 1) ? ldBF(Ain, row0+2*o0-1, b) : 0.f;
  #pragma unroll
  for (int j=0;j<NO;++j){
    int c = 2*(o0+j);
    float mid = ldBF(Ain, row0+c,   b);
    float rgt = ldBF(Ain, row0+c+1, b);
    float v = w0*left + w1*mid + w2*rgt;
    y[j] = exp2r(v); s += y[j];
    left = rgt;
  }
}
// normalized write, A-fragment layout (one 16B store per 8 outputs)
template<int SZ,int NO>
DEV void wrTF(char* TFb, int subBase, int o0, int b, const float (&y)[NO], float inv){
  #pragma unroll
  for (int g8=0; g8<NO/8; ++g8){
    int oo = o0 + g8*8, fl = oo&31;
    char* base = TFb + (size_t)((subBase+(oo>>5))*4+(b>>4))*SZ + ((b&15)+16*(fl>>3))*16;
    unsigned d0=cvtpk(y[g8*8+0]*inv,y[g8*8+1]*inv), d1=cvtpk(y[g8*8+2]*inv,y[g8*8+3]*inv);
    unsigned d2=cvtpk(y[g8*8+4]*inv,y[g8*8+5]*inv), d3=cvtpk(y[g8*8+6]*inv,y[g8*8+7]*inv);
    *(uint4*)base = make_uint4(d0,d1,d2,d3);
  }
}
template<int NO>
DEV void wrBC(char* BCb, int row0, int b, const float (&y)[NO], float inv){
  #pragma unroll
  for (int j=0;j<NO;++j) stBF(BCb, row0+j, b, y[j]*inv);
}

// ---------------- main kernel -----------------
// launch_bounds(512,4): VGPR cap 128 (R3 showed (512,6) -> 40 VGPR + massive spill).
__global__ __launch_bounds__(512, 4) void dsgsf_main(P p, const char* blob){
  __shared__ __align__(16) char SM[51200];
  char* XP = SM;               // 16KB: spec A-frags [kc*4+mt]
  char* AH = SM + 16384;       //  8KB: h state [feat][batch] bf16 swizzled
  char* AC = SM + 24576;       //  8KB: c state
  char* BC = SM + 32768;       //  8KB: trans-c outputs
  char* TF = SM + 40960;       //  8KB: trans-h outputs as A-frags
  float* PSm = (float*)(SM + 49152);  // 2KB: softmax partial sums [task][batch]

  const int tid = threadIdx.x;
  const int l   = tid & 63;
  const int wu  = __builtin_amdgcn_readfirstlane(tid >> 6);
  const int mtp = wu & 1, z = wu >> 1;
  const long b0 = (long)blockIdx.x * 64;

  // ---- stage spec into A-fragment layout ----
  #pragma unroll
  for (int it=0; it<2; ++it){
    int n = it*512 + tid; int slot = n>>6, lx = n&63;
    int kc = slot>>2, mt = slot&3;
    const float* sp = p.spec + (b0 + mt*16 + (lx&15))*128 + kc*32 + ((lx>>4)<<3);
    float4 v0 = *(const float4*)sp; float4 v1 = *(const float4*)(sp+4);
    unsigned d0=cvtpk(v0.x,v0.y), d1=cvtpk(v0.z,v0.w);
    unsigned d2=cvtpk(v1.x,v1.y), d3=cvtpk(v1.z,v1.w);
    *(uint4*)(XP + (size_t)slot*1024 + lx*16) = make_uint4(d0,d1,d2,d3);
  }
  __syncthreads();

  // ================= F1: lstm0(spec), gates i,g,o =================
  {
    f32x4 acc[2][3];
    int feat = z*16 + (l&15);
    binit<3>(acc, p.fb1, 64, feat, 0,2,3,0);
    auto af = [&](int kt, int mt){ return frag(XP + (size_t)((kt<<2)+mt)*1024 + l*16); };
    gemm_reg<3,4,4>(acc, blob + (size_t)OF1*1024, z, mtp, l, af);
    #pragma unroll
    for (int mtI=0;mtI<2;++mtI){
      float hv[4], cv[4];
      int bb = (mtp*2+mtI)*16 + ((l>>4)<<2);
      #pragma unroll
      for (int r=0;r<4;++r){
        cv[r] = lstm0_c(acc[mtI][0][r], acc[mtI][1][r]);
        hv[r] = lstm_h(acc[mtI][2][r], cv[r]);
      }
      stBFpair(AH, feat, bb,   hv[0], hv[1]);
      stBFpair(AH, feat, bb+2, hv[2], hv[3]);
      stBFpair(AC, feat, bb,   cv[0], cv[1]);
      stBFpair(AC, feat, bb+2, cv[2], cv[3]);
    }
  }
  __syncthreads();

  // ---- T12: chunks of 8, psum over 4 ----
  {
    float y[8], s;
    if (wu<4) convE2<64,8>(AH, 0, p.ft12h, wu*8, l, y, s);
    else      convE2<64,8>(AC, 0, p.ft12c, (wu-4)*8, l, y, s);
    PSm[wu*64+l] = s;
    __syncthreads();
    float tot = (wu<4) ? PSm[0*64+l]+PSm[1*64+l]+PSm[2*64+l]+PSm[3*64+l]
                       : PSm[4*64+l]+PSm[5*64+l]+PSm[6*64+l]+PSm[7*64+l];
    float inv = fastrcp(tot);
    if (wu<4) wrTF<1024,8>(TF, 0, wu*8, l, y, inv);
    else      wrBC<8>(BC, (wu-4)*8, l, y, inv);
  }
  __syncthreads();

  // ================= F2 =================
  {
    f32x4 acc[2][4];
    int step = z>>1, nf = z&1;
    int feat = nf*16 + (l&15);
    binit<4>(acc, p.fb2, 32, feat, 0,1,2,3);
    auto af = [&](int kt, int mt){
      return (kt<2) ? frag(XP + (size_t)(((2*step+kt)<<2)+mt)*1024 + l*16)
                    : frag(TF + (size_t)mt*1024 + l*16); };
    gemm_reg<4,2,3>(acc, blob + (size_t)OF2*1024, nf, mtp, l, af);
    pw4(acc, AH, AC, BC, step*32+feat, feat, mtp, l);
  }
  __syncthreads();

  // ---- T23: 2 steps x 2 chunks of 8, psum pairs ----
  {
    float y[8], s; int v=wu&3, st=v>>1, ch=v&1;
    if (wu<4) convE2<32,8>(AH, st*32, p.ft23h, ch*8, l, y, s);
    else      convE2<32,8>(AC, st*32, p.ft23c, ch*8, l, y, s);
    PSm[wu*64+l] = s;
    __syncthreads();
    int base = (wu&4) | (st<<1);
    float inv = fastrcp(PSm[base*64+l] + PSm[(base|1)*64+l]);
    if (wu<4) wrTF<512,8>(TF, st, ch*8, l, y, inv);
    else      wrBC<8>(BC, st*16+ch*8, l, y, inv);
  }
  __syncthreads();

  // ================= F3 =================
  {
    f32x4 acc[2][4];
    int s = z, feat = l&15;
    binit<4>(acc, p.fb3, 16, feat, 0,1,2,3);
    auto af = [&](int kt, int mt){
      return (kt==0) ? frag(XP + (size_t)((s<<2)+mt)*1024 + l*16)
                     : frag(TF + (size_t)(((s>>1)<<2)+mt)*512 + (l&31)*16); };
    gemm_reg<4,1,2>(acc, blob + (size_t)OF3*1024, 0, mtp, l, af);
    pw4(acc, AH, AC, BC, s*16+feat, (s>>1)*16+feat, mtp, l);
  }
  __syncthreads();

  // ---- T34: 8 independent rows of 8, local sums ----
  {
    float y[8], s;
    if (wu<4){ convE2<16,8>(AH, wu*16, p.ft34h, 0, l, y, s);
               wrTF<256,8>(TF, wu, 0, l, y, fastrcp(s)); }
    else     { convE2<16,8>(AC, (wu-4)*16, p.ft34h, 0, l, y, s);   // ref bug: ft34h for c
               wrBC<8>(BC, (wu-4)*8, l, y, fastrcp(s)); }
  }
  __syncthreads();

  // ================= F4 (parity-packed, all-lane epilogue) =================
  {
    f32x4 a4[2][2][2]; // [parity uu][mtI][tile]
    float bv0 = p.fb4[l&15], bv1 = p.fb4[16+(l&15)];
    #pragma unroll
    for (int uu=0;uu<2;++uu)
      #pragma unroll
      for (int mtI=0;mtI<2;++mtI){ a4[uu][mtI][0]=f32x4{bv0,bv0,bv0,bv0}; a4[uu][mtI][1]=f32x4{bv1,bv1,bv1,bv1}; }
    const char* bs = blob + (size_t)OF4*1024;
    short8 A0 = frag(XP + (size_t)((z<<2)+mtp*2  )*1024 + l*16);
    short8 A1 = frag(XP + (size_t)((z<<2)+mtp*2+1)*1024 + l*16);
    short8 H0 = frag(TF + (size_t)((z<<2)+mtp*2  )*256 + (l&15)*16);
    short8 H1 = frag(TF + (size_t)((z<<2)+mtp*2+1)*256 + (l&15)*16);
    short8 bh0 = gfrag(bs + 4*1024 + l*16);
    short8 bh1 = gfrag(bs + 5*1024 + l*16);
    #pragma unroll
    for (int uu=0;uu<2;++uu){
      short8 bx0 = gfrag(bs + (uu*2+0)*1024 + l*16);
      short8 bx1 = gfrag(bs + (uu*2+1)*1024 + l*16);
      a4[uu][0][0]=MF(A0,bx0,a4[uu][0][0]); a4[uu][0][1]=MF(A0,bx1,a4[uu][0][1]);
      a4[uu][1][0]=MF(A1,bx0,a4[uu][1][0]); a4[uu][1][1]=MF(A1,bx1,a4[uu][1][1]);
      a4[uu][0][0]=MF(H0,bh0,a4[uu][0][0]); a4[uu][0][1]=MF(H0,bh1,a4[uu][0][1]);
      a4[uu][1][0]=MF(H1,bh0,a4[uu][1][0]); a4[uu][1][1]=MF(H1,bh1,a4[uu][1][1]);
    }
    // lane-half q<8 -> uu=0, q>=8 -> uu=1; gates redistributed by shfl_xor(8)
    const bool sel = (l&15) < 8;
    const int qe = l&7;
    const int u = z*2 + (sel ? 0 : 1);
    #pragma unroll
    for (int mtI=0;mtI<2;++mtI){
      int bb = (mtp*2+mtI)*16 + ((l>>4)<<2);
      float2 cb01 = ldBF2(BC, z*8+qe, bb), cb23 = ldBF2(BC, z*8+qe, bb+2);
      float cbv[4] = {cb01.x, cb01.y, cb23.x, cb23.y};
      #pragma unroll
      for (int r=0;r<4;++r){
        float s00 = __shfl_xor(a4[0][mtI][0][r],8), s10 = __shfl_xor(a4[1][mtI][0][r],8);
        float s01 = __shfl_xor(a4[0][mtI][1][r],8), s11 = __shfl_xor(a4[1][mtI][1][r],8);
        float iv = sel ? a4[0][mtI][0][r] : s10;
        float fv = sel ? s00 : a4[1][mtI][0][r];
        float gv = sel ? a4[0][mtI][1][r] : s11;
        float ov = sel ? s01 : a4[1][mtI][1][r];
        float c = lstm_c(iv, fv, gv, cbv[r]);
        float h = lstm_h(ov, c);
        p.out[(size_t)(b0+bb+r)*128 + u*8 + qe] = h;
      }
    }
  }

  // ================= B4 (parity-packed lstm0, all-lane epilogue) =================
  {
    f32x4 a4[2][2][2];
    float bv0 = ((l&15)<8) ? p.bb4[l&15] : p.bb4[(l&15)+8];   // i | g
    float bv1 = ((l&15)<8) ? p.bb4[24+(l&15)] : 0.f;          // o | pad
    #pragma unroll
    for (int uu=0;uu<2;++uu)
      #pragma unroll
      for (int mtI=0;mtI<2;++mtI){ a4[uu][mtI][0]=f32x4{bv0,bv0,bv0,bv0}; a4[uu][mtI][1]=f32x4{bv1,bv1,bv1,bv1}; }
    const char* bs = blob + (size_t)OB4*1024;
    short8 A0 = frag(XP + (size_t)((z<<2)+mtp*2  )*1024 + l*16);
    short8 A1 = frag(XP + (size_t)((z<<2)+mtp*2+1)*1024 + l*16);
    #pragma unroll
    for (int uu=0;uu<2;++uu){
      short8 bx0 = gfrag(bs + (uu*2+0)*1024 + l*16);
      short8 bx1 = gfrag(bs + (uu*2+1)*1024 + l*16);
      a4[uu][0][0]=MF(A0,bx0,a4[uu][0][0]); a4[uu][0][1]=MF(A0,bx1,a4[uu][0][1]);
      a4[uu][1][0]=MF(A1,bx0,a4[uu][1][0]); a4[uu][1][1]=MF(A1,bx1,a4[uu][1][1]);
    }
    const bool sel = (l&15) < 8;
    const int qe = l&7;
    const int u = z*2 + (sel ? 0 : 1);
    const int f = u*8 + qe;
    #pragma unroll
    for (int mtI=0;mtI<2;++mtI){
      float hv[4], cv[4];
      int bb = (mtp*2+mtI)*16 + ((l>>4)<<2);
      #pragma unroll
      for (int r=0;r<4;++r){
        float s0 = __shfl_xor(a4[0][mtI][0][r],8);   // lane<8 gets g(uu0); lane>=8 gets i(uu0) (unused)
        float s1 = __shfl_xor(a4[1][mtI][0][r],8);   // lane>=8 gets i(uu1)
        float s2 = __shfl_xor(a4[1][mtI][1][r],8);   // lane>=8 gets o(uu1)
        float iv = sel ? a4[0][mtI][0][r] : s1;
        float gv = sel ? s0 : a4[1][mtI][0][r];
        float ov = sel ? a4[0][mtI][1][r] : s2;
        cv[r] = lstm0_c(iv, gv);
        hv[r] = lstm_h(ov, cv[r]);
      }
      stBFpair(AH, f, bb,   hv[0], hv[1]);
      stBFpair(AH, f, bb+2, hv[2], hv[3]);
      stBFpair(AC, f, bb,   cv[0], cv[1]);
      stBFpair(AC, f, bb+2, cv[2], cv[3]);
    }
  }
  __syncthreads();

  // ---- T43: 8 independent rows of 16, local sums ----
  {
    float y[16], s;
    if (wu<4){ convE1<16,16>(AH, wu*16, p.bt43h, 0, l, y, s);
               wrTF<512,16>(TF, wu, 0, l, y, fastrcp(s)); }
    else     { convE1<16,16>(AC, (wu-4)*16, p.bt43c, 0, l, y, s);
               wrBC<16>(BC, (wu-4)*16, l, y, fastrcp(s)); }
  }
  __syncthreads();

  // ================= B3 =================
  {
    f32x4 acc[2][4];
    int s = z, feat = l&15;
    binit<4>(acc, p.bb3, 16, feat, 0,1,2,3);
    auto af = [&](int kt, int mt){
      return (kt==0) ? frag(XP + (size_t)((s<<2)+mt)*1024 + l*16)
                     : frag(TF + (size_t)((s<<2)+mt)*512 + (l&31)*16); };
    gemm_reg<4,1,2>(acc, blob + (size_t)OB3*1024, 0, mtp, l, af);
    pw4(acc, AH, AC, BC, s*16+feat, s*16+feat, mtp, l);
  }
  __syncthreads();

  // ---- T32: 2 steps x 2 chunks of 16, psum pairs ----
  {
    float y[16], s; int v=wu&3, st=v>>1, ch=v&1;
    if (wu<4) convE1<32,16>(AH, st*32, p.bt32h, ch*16, l, y, s);
    else      convE1<32,16>(AC, st*32, p.bt32c, ch*16, l, y, s);
    PSm[wu*64+l] = s;
    __syncthreads();
    int base = (wu&4) | (st<<1);
    float inv = fastrcp(PSm[base*64+l] + PSm[(base|1)*64+l]);
    if (wu<4) wrTF<1024,16>(TF, st, ch*16, l, y, inv);
    else      wrBC<16>(BC, st*32+ch*16, l, y, inv);
  }
  __syncthreads();

  // ================= B2 =================
  {
    f32x4 acc[2][4];
    int t2 = z>>1, nf = z&1;
    int feat = nf*16 + (l&15);
    binit<4>(acc, p.bb2, 32, feat, 0,1,2,3);
    auto af = [&](int kt, int mt){
      return (kt<2) ? frag(XP + (size_t)(((2*t2+kt)<<2)+mt)*1024 + l*16)
                    : frag(TF + (size_t)((t2<<2)+mt)*1024 + l*16); };
    gemm_reg<4,2,3>(acc, blob + (size_t)OB2*1024, nf, mtp, l, af);
    pw4(acc, AH, AC, BC, t2*32+feat, t2*32+feat, mtp, l);
  }
  __syncthreads();

  // ---- T21: 4 chunks of 16, psum over 4 ----
  {
    float y[16], s;
    if (wu<4) convE1<64,16>(AH, 0, p.bt21h, wu*16, l, y, s);
    else      convE1<64,16>(AC, 0, p.bt21c, (wu-4)*16, l, y, s);
    PSm[wu*64+l] = s;
    __syncthreads();
    float tot = (wu<4) ? PSm[0*64+l]+PSm[1*64+l]+PSm[2*64+l]+PSm[3*64+l]
                       : PSm[4*64+l]+PSm[5*64+l]+PSm[6*64+l]+PSm[7*64+l];
    float inv = fastrcp(tot);
    if (wu<4) wrTF<1024,16>(TF, 0, wu*16, l, y, inv);
    else      wrBC<16>(BC, (wu-4)*16, l, y, inv);
  }
  __syncthreads();

  // ================= B1: gates i,f,g -> c only =================
  {
    f32x4 acc[2][3];
    int feat = z*16 + (l&15);
    binit<3>(acc, p.bb1, 64, feat, 0,1,2,0);
    auto af = [&](int kt, int mt){
      return (kt<4) ? frag(XP + (size_t)((kt<<2)+mt)*1024 + l*16)
                    : frag(TF + (size_t)(((kt-4)<<2)+mt)*1024 + l*16); };
    gemm_reg<3,4,6>(acc, blob + (size_t)OB1*1024, z, mtp, l, af);
    #pragma unroll
    for (int mtI=0;mtI<2;++mtI){
      int bb = (mtp*2+mtI)*16 + ((l>>4)<<2);
      float2 cb01 = ldBF2(BC, feat, bb), cb23 = ldBF2(BC, feat, bb+2);
      float cbv[4] = {cb01.x, cb01.y, cb23.x, cb23.y};
      #pragma unroll
      for (int r=0;r<4;++r){
        float c = lstm_c(acc[mtI][0][r], acc[mtI][1][r], acc[mtI][2][r], cbv[r]);
        p.out[(size_t)(b0+bb+r)*128 + 64 + feat] = c;
      }
    }
  }
}

extern "C" void kernel_launch(void* const* d_in, const int* in_sizes, int n_in,
                              void* d_out, int out_size, void* d_ws, size_t ws_size,
                              hipStream_t stream) {
  if (ws_size < (size_t)BLOBB) return;
  P p;
  p.spec   = (const float*)d_in[0];
  p.fw_ih1 = (const float*)d_in[1];  p.fw_hh1 = (const float*)d_in[2];  p.fb1 = (const float*)d_in[3];
  p.fw_ih2 = (const float*)d_in[4];  p.fw_hh2 = (const float*)d_in[5];  p.fb2 = (const float*)d_in[6];
  p.fw_ih3 = (const float*)d_in[7];  p.fw_hh3 = (const float*)d_in[8];  p.fb3 = (const float*)d_in[9];
  p.fw_ih4 = (const float*)d_in[10]; p.fw_hh4 = (const float*)d_in[11]; p.fb4 = (const float*)d_in[12];
  p.bw_ih1 = (const float*)d_in[13]; p.bw_hh1 = (const float*)d_in[14]; p.bb1 = (const float*)d_in[15];
  p.bw_ih2 = (const float*)d_in[16]; p.bw_hh2 = (const float*)d_in[17]; p.bb2 = (const float*)d_in[18];
  p.bw_ih3 = (const float*)d_in[19]; p.bw_hh3 = (const float*)d_in[20]; p.bb3 = (const float*)d_in[21];
  p.bw_ih4 = (const float*)d_in[22]; p.bw_hh4 = (const float*)d_in[23]; p.bb4 = (const float*)d_in[24];
  p.ft12h = (const float*)d_in[25]; p.ft12c = (const float*)d_in[26];
  p.ft23h = (const float*)d_in[27]; p.ft23c = (const float*)d_in[28];
  p.ft34h = (const float*)d_in[29];
  p.bt43h = (const float*)d_in[30]; p.bt43c = (const float*)d_in[31];
  p.bt32h = (const float*)d_in[32]; p.bt32c = (const float*)d_in[33];
  p.bt21h = (const float*)d_in[34]; p.bt21c = (const float*)d_in[35];
  p.out = (float*)d_out;

  char* blob = (char*)d_ws;
  hipLaunchKernelGGL(dsgsf_prep, dim3(8), dim3(256), 0, stream, p, blob);
  int Bn = in_sizes[0] / 128;
  hipLaunchKernelGGL(dsgsf_main, dim3(Bn/64), dim3(512), 0, stream, p, (const char*)blob);
}